// Round 4
// baseline (2689.491 us; speedup 1.0000x reference)
//
#include <hip/hip_runtime.h>
#include <math.h>

typedef short bf16x8 __attribute__((ext_vector_type(8)));
typedef float f32x4 __attribute__((ext_vector_type(4)));

#define GLL16(g, l) \
  __builtin_amdgcn_global_load_lds((__attribute__((address_space(1))) const unsigned int*)(g), \
                                   (__attribute__((address_space(3))) unsigned int*)(l), 16, 0, 0)

// ---------- helpers ----------
__device__ __forceinline__ float wsum(float v){
  #pragma unroll
  for (int o=32;o;o>>=1) v += __shfl_xor(v,o);
  return v;
}
__device__ __forceinline__ float wmaxr(float v){
  #pragma unroll
  for (int o=32;o;o>>=1) v = fmaxf(v,__shfl_xor(v,o));
  return v;
}
__device__ __forceinline__ float geluf(float x){
  return 0.5f*x*(1.0f+erff(x*0.7071067811865475f));
}
__device__ __forceinline__ short fbf(float f){   // fp32 -> bf16 RNE
  unsigned u = __float_as_uint(f);
  unsigned r = (u + 0x7fffu + ((u>>16)&1u)) >> 16;
  return (short)r;
}
__device__ __forceinline__ float bff(short s){
  return __uint_as_float(((unsigned)(unsigned short)s)<<16);
}
__device__ __forceinline__ unsigned fkey(float f){
  unsigned b=__float_as_uint(f);
  return (b&0x80000000u)? ~b : (b|0x80000000u);
}
__device__ __forceinline__ float fdec(unsigned k){
  unsigned b=(k&0x80000000u)? (k&0x7fffffffu) : ~k;
  return __uint_as_float(b);
}

// ---------- mask dtype detection ----------
__global__ void detect_mask_kernel(const int* __restrict__ m, long long n, int* flag){
  long long i = (long long)blockIdx.x*256 + threadIdx.x;
  bool bad = (i<n) && (m[i]!=0 && m[i]!=1);
  if (__any(bad)) { if ((threadIdx.x&63)==0) atomicOr(flag,1); }
}

// epilogue shared by both GEMMs
__device__ __forceinline__ float epi(float v, const float* bias, int col, int act){
  if (bias) v += bias[col];
  if (act==1) v = geluf(v);
  else if (act==2) v = v*(1.f/(1.f+__expf(-1.702f*v)));
  return v;
}

// ---------- bf16 MFMA GEMM, 128x128 tile (4 waves, 64x64 each) ----------
// out[z] = epilogue( A[z] @ B[z]^T )   A:[M,K] bf16 lda, B:[N,K] bf16 ldb.
// REQUIRES: K % 32 == 0, lda/ldb multiples of 8, bases 16B-aligned.
// KS>1: split-K, atomicAdd fp32 into pre-zeroed out (no epilogue).
// LDS: per 16-row block (1KB): addr = blk*1024B + quad*256B + row*16B == lane-linear.
#define XBM 128
#define XBN 128
#define XBK 32
__global__ __launch_bounds__(256)
void gemm_bf16_big(const short* __restrict__ A, int lda, long long sA,
                   const short* __restrict__ B, int ldb, long long sB,
                   const float* __restrict__ bias,
                   const float* __restrict__ res, int ldr, long long sR,
                   void* __restrict__ out, int ldo, long long sO, int outbf16,
                   int M, int N, int K, int act, int KS)
{
  __shared__ short As[XBM*XBK];   // 8 KB
  __shared__ short Bs[XBN*XBK];   // 8 KB
  int zz = blockIdx.z;
  int z = zz / KS, ks = zz - z*KS;
  A += (long long)z*sA; B += (long long)z*sB;
  if (res) res += (long long)z*sR;
  float* outF = (float*)out + (long long)z*sO;
  short* outH = (short*)out + (long long)z*sO;

  int tid = threadIdx.x;
  int rowBase = blockIdx.y*XBM;
  int colBase = blockIdx.x*XBN;

  int Kc = ((K + KS*XBK - 1)/(KS*XBK))*XBK;
  int kbeg = ks*Kc;
  int kend = min(K, kbeg+Kc);
  if (kbeg >= kend) return;

  int w = tid>>6;
  int lane = tid&63;
  int lm = lane&15, quad = lane>>4;
  int waveM = w>>1, waveN = w&1;

  // wave w stages A rows [w*32, w*32+32) and B rows [w*32, w*32+32)
  int arow0 = min(rowBase + w*32 + lm,      M-1);
  int arow1 = min(rowBase + w*32 + 16 + lm, M-1);
  int brow0 = min(colBase + w*32 + lm,      N-1);
  int brow1 = min(colBase + w*32 + 16 + lm, N-1);
  const short* Ag0 = A + (long long)arow0*lda + quad*8;
  const short* Ag1 = A + (long long)arow1*lda + quad*8;
  const short* Bg0 = B + (long long)brow0*ldb + quad*8;
  const short* Bg1 = B + (long long)brow1*ldb + quad*8;
  short* Al0 = &As[(w*2+0)*512];
  short* Al1 = &As[(w*2+1)*512];
  short* Bl0 = &Bs[(w*2+0)*512];
  short* Bl1 = &Bs[(w*2+1)*512];

  f32x4 acc[4][4] = {};

  for (int k0=kbeg; k0<kend; k0+=XBK){
    GLL16(Ag0 + k0, Al0);
    GLL16(Ag1 + k0, Al1);
    GLL16(Bg0 + k0, Bl0);
    GLL16(Bg1 + k0, Bl1);
    __syncthreads();
    bf16x8 af[4], bfr[4];
    #pragma unroll
    for (int tm=0;tm<4;tm++) af[tm]  = *(bf16x8*)&As[(waveM*4+tm)*512 + quad*128 + lm*8];
    #pragma unroll
    for (int tn=0;tn<4;tn++) bfr[tn] = *(bf16x8*)&Bs[(waveN*4+tn)*512 + quad*128 + lm*8];
    #pragma unroll
    for (int tm=0;tm<4;tm++)
      #pragma unroll
      for (int tn=0;tn<4;tn++)
        acc[tm][tn] = __builtin_amdgcn_mfma_f32_16x16x32_bf16(af[tm], bfr[tn], acc[tm][tn], 0,0,0);
    __syncthreads();
  }

  #pragma unroll
  for (int tm=0;tm<4;tm++){
    #pragma unroll
    for (int tn=0;tn<4;tn++){
      int col = colBase + waveN*64 + tn*16 + lm;
      if (col>=N) continue;
      #pragma unroll
      for (int reg=0;reg<4;reg++){
        int row = rowBase + waveM*64 + tm*16 + quad*4 + reg;
        if (row>=M) continue;
        float v = acc[tm][tn][reg];
        if (KS>1){ atomicAdd(&outF[(long long)row*ldo+col], v); continue; }
        v = epi(v, bias, col, act);
        if (res) v += res[(long long)row*ldr+col];
        if (outbf16) outH[(long long)row*ldo+col] = fbf(v);
        else         outF[(long long)row*ldo+col] = v;
      }
    }
  }
}

// ---------- bf16 MFMA GEMM, 128x64 tile (narrow-N path) ----------
#define TBM 128
#define TBN 64
#define TBK 32
__global__ __launch_bounds__(256)
void gemm_bf16(const short* __restrict__ A, int lda, long long sA,
               const short* __restrict__ B, int ldb, long long sB,
               const float* __restrict__ bias,
               const float* __restrict__ res, int ldr, long long sR,
               void* __restrict__ out, int ldo, long long sO, int outbf16,
               int M, int N, int K, int act, int KS)
{
  __shared__ short As[TBM*TBK];   // 8 KB
  __shared__ short Bs[TBN*TBK];   // 4 KB
  int zz = blockIdx.z;
  int z = zz / KS, ks = zz - z*KS;
  A += (long long)z*sA; B += (long long)z*sB;
  if (res) res += (long long)z*sR;
  float* outF = (float*)out + (long long)z*sO;
  short* outH = (short*)out + (long long)z*sO;

  int tid = threadIdx.x;
  int rowBase = blockIdx.y*TBM;
  int colBase = blockIdx.x*TBN;

  int Kc = ((K + KS*TBK - 1)/(KS*TBK))*TBK;
  int kbeg = ks*Kc;
  int kend = min(K, kbeg+Kc);
  if (kbeg >= kend) return;

  int w = tid>>6;
  int lane = tid&63;
  int lm = lane&15, quad = lane>>4;
  int waveM = w>>1, waveN = w&1;

  int arow0 = min(rowBase + w*32 + lm,      M-1);
  int arow1 = min(rowBase + w*32 + 16 + lm, M-1);
  int brow  = min(colBase + w*16 + lm,      N-1);
  const short* Ag0 = A + (long long)arow0*lda + quad*8;
  const short* Ag1 = A + (long long)arow1*lda + quad*8;
  const short* Bg  = B + (long long)brow*ldb  + quad*8;
  short* Al0 = &As[(w*2+0)*512];
  short* Al1 = &As[(w*2+1)*512];
  short* Bl  = &Bs[w*512];

  f32x4 acc[4][2] = {};

  for (int k0=kbeg; k0<kend; k0+=TBK){
    GLL16(Ag0 + k0, Al0);
    GLL16(Ag1 + k0, Al1);
    GLL16(Bg  + k0, Bl);
    __syncthreads();
    bf16x8 af[4], bfr[2];
    #pragma unroll
    for (int tm=0;tm<4;tm++) af[tm]  = *(bf16x8*)&As[(waveM*4+tm)*512 + quad*128 + lm*8];
    #pragma unroll
    for (int tn=0;tn<2;tn++) bfr[tn] = *(bf16x8*)&Bs[(waveN*2+tn)*512 + quad*128 + lm*8];
    #pragma unroll
    for (int tm=0;tm<4;tm++)
      #pragma unroll
      for (int tn=0;tn<2;tn++)
        acc[tm][tn] = __builtin_amdgcn_mfma_f32_16x16x32_bf16(af[tm], bfr[tn], acc[tm][tn], 0,0,0);
    __syncthreads();
  }

  #pragma unroll
  for (int tm=0;tm<4;tm++){
    #pragma unroll
    for (int tn=0;tn<2;tn++){
      int col = colBase + waveN*32 + tn*16 + lm;
      if (col>=N) continue;
      #pragma unroll
      for (int reg=0;reg<4;reg++){
        int row = rowBase + waveM*64 + tm*16 + quad*4 + reg;
        if (row>=M) continue;
        float v = acc[tm][tn][reg];
        if (KS>1){ atomicAdd(&outF[(long long)row*ldo+col], v); continue; }
        v = epi(v, bias, col, act);
        if (res) v += res[(long long)row*ldr+col];
        if (outbf16) outH[(long long)row*ldo+col] = fbf(v);
        else         outF[(long long)row*ldo+col] = v;
      }
    }
  }
}

// ---------- softmax in-place on bf16 scores ----------
__global__ __launch_bounds__(256)
void softmax_bf16(short* __restrict__ S, int ld, long long sS, int cols, float alpha,
                  const void* __restrict__ mask, long long maskoff, int maskld,
                  const int* __restrict__ modeflag)
{
  __shared__ float buf[2080];
  __shared__ float red[4];
  int row = blockIdx.x, z = blockIdx.y;
  short* p = S + (long long)z*sS + (long long)row*ld;
  int tid = threadIdx.x;
  int mode = 0;
  if (mask && modeflag) mode = *modeflag;
  float mx = -3.4e38f;
  for (int c=tid;c<cols;c+=256){
    float v = bff(p[c])*alpha;
    if (mask){
      long long mi = maskoff + (long long)row*maskld + c;
      bool ok = mode ? (((const unsigned char*)mask)[mi]!=0)
                     : (((const int*)mask)[mi]!=0);
      if (!ok) v = -3.4e38f;
    }
    buf[c] = v;
    mx = fmaxf(mx, v);
  }
  mx = wmaxr(mx);
  int wid = tid>>6, lane = tid&63;
  if (lane==0) red[wid]=mx;
  __syncthreads();
  mx = fmaxf(fmaxf(red[0],red[1]),fmaxf(red[2],red[3]));
  __syncthreads();
  float sum=0.f;
  for (int c=tid;c<cols;c+=256){
    float v = buf[c];
    float e = (v > -1.0e37f) ? __expf(v-mx) : 0.f;
    buf[c]=e; sum += e;
  }
  sum = wsum(sum);
  if (lane==0) red[wid]=sum;
  __syncthreads();
  sum = red[0]+red[1]+red[2]+red[3];
  float inv = 1.f/sum;
  for (int c=tid;c<cols;c+=256) p[c] = fbf(buf[c]*inv);
  for (int c=cols+tid;c<ld;c+=256) p[c] = 0;
}

// ---------- LayerNorm (fp32 in -> bf16 out), C=384 ----------
__global__ __launch_bounds__(128)
void ln_bf16_kernel(const float* __restrict__ in, const float* __restrict__ g,
                    const float* __restrict__ bt, short* __restrict__ out)
{
  long long row = blockIdx.x;
  const float* p = in + row*384;
  int tid = threadIdx.x;
  float v0=p[tid], v1=p[tid+128], v2=p[tid+256];
  float s = v0+v1+v2;
  float ss = v0*v0+v1*v1+v2*v2;
  __shared__ float r1[2], r2[2];
  s = wsum(s); ss = wsum(ss);
  int wid=tid>>6, lane=tid&63;
  if (lane==0){ r1[wid]=s; r2[wid]=ss; }
  __syncthreads();
  float mean=(r1[0]+r1[1])*(1.f/384.f);
  float var =(r2[0]+r2[1])*(1.f/384.f)-mean*mean;
  float rstd=rsqrtf(var+1e-5f);
  short* o = out + row*384;
  o[tid]     = fbf((v0-mean)*rstd*g[tid]+bt[tid]);
  o[tid+128] = fbf((v1-mean)*rstd*g[tid+128]+bt[tid+128]);
  o[tid+256] = fbf((v2-mean)*rstd*g[tid+256]+bt[tid+256]);
}

// ---------- fp32 -> bf16 convert ----------
__global__ void cvt_kernel(const float* __restrict__ in, short* __restrict__ out, long long n4){
  long long i = (long long)blockIdx.x*256 + threadIdx.x;
  if (i<n4){
    float4 f = ((const float4*)in)[i];
    short4 s;
    s.x=fbf(f.x); s.y=fbf(f.y); s.z=fbf(f.z); s.w=fbf(f.w);
    ((short4*)out)[i]=s;
  }
}

// ---------- tiled transpose+convert: fp32 [R,C] -> bf16 [C, ldout] zero-padded ----------
__global__ __launch_bounds__(256)
void tconv_kernel(const float* __restrict__ in, int ldin, long long sIn, long long sIn2, int zmod,
                  int R, int C, short* __restrict__ out, int ldout, long long sOut)
{
  __shared__ float tile[32][33];
  int z = blockIdx.z;
  const float* ip = in + (long long)(z/zmod)*sIn + (long long)(z%zmod)*sIn2;
  short* op = out + (long long)z*sOut;
  int r0 = blockIdx.x*32;
  int c0 = blockIdx.y*32;
  int tx = threadIdx.x&31, ty = threadIdx.x>>5;
  #pragma unroll
  for (int i=0;i<4;i++){
    int r = r0 + ty + i*8, c = c0 + tx;
    tile[ty+i*8][tx] = (r<R && c<C) ? ip[(long long)r*ldin + c] : 0.f;
  }
  __syncthreads();
  #pragma unroll
  for (int i=0;i<4;i++){
    int oc = c0 + ty + i*8;
    int orr = r0 + tx;
    if (oc<C && orr<ldout) op[(long long)oc*ldout + orr] = fbf(tile[tx][ty+i*8]);
  }
}

// ---------- tiled transpose: bf16 [R,C] -> bf16 [C, ldout] zero-padded ----------
__global__ __launch_bounds__(256)
void tconv16_kernel(const short* __restrict__ in, int ldin, long long sIn, long long sIn2, int zmod,
                    int R, int C, short* __restrict__ out, int ldout, long long sOut)
{
  __shared__ short tile[32][34];
  int z = blockIdx.z;
  const short* ip = in + (long long)(z/zmod)*sIn + (long long)(z%zmod)*sIn2;
  short* op = out + (long long)z*sOut;
  int r0 = blockIdx.x*32;
  int c0 = blockIdx.y*32;
  int tx = threadIdx.x&31, ty = threadIdx.x>>5;
  #pragma unroll
  for (int i=0;i<4;i++){
    int r = r0 + ty + i*8, c = c0 + tx;
    tile[ty+i*8][tx] = (r<R && c<C) ? ip[(long long)r*ldin + c] : (short)0;
  }
  __syncthreads();
  #pragma unroll
  for (int i=0;i<4;i++){
    int oc = c0 + ty + i*8;
    int orr = r0 + tx;
    if (oc<C && orr<ldout) op[(long long)oc*ldout + orr] = tile[tx][ty+i*8];
  }
}

// ---------- elementwise ----------
__global__ void ew_x2_kernel(float* x1, const float* ffn, const float* ada, long long n){
  long long i=(long long)blockIdx.x*256+threadIdx.x;
  if (i<n) x1[i] = x1[i] + ffn[i] + 0.5f*ada[i];
}
__global__ void copy_pts_kernel(const float* __restrict__ x2, float* __restrict__ pts){
  long long i=(long long)blockIdx.x*256+threadIdx.x;
  if (i < 8192ll*384){
    long long b = i/(2048ll*384);
    long long rem = i%(2048ll*384);
    pts[i] = x2[(b*2049+1)*384 + rem];
  }
}
__global__ void copy_cls_kernel(const float* __restrict__ x2, float* __restrict__ out){
  int i = blockIdx.x*256+threadIdx.x;
  if (i < 4*384){
    int b=i/384, c=i%384;
    out[(long long)b*2049*384 + c] = x2[(long long)b*2049*384 + c];
  }
}

// ---------- segment scatter (sum + max + count) ----------
__global__ __launch_bounds__(128)
void scatter_seg_kernel(const float* __restrict__ feat, const int* __restrict__ seg,
                        float* __restrict__ fsum, unsigned* __restrict__ fmax,
                        float* __restrict__ cnt)
{
  int n = blockIdx.x;
  int s = seg[n];
  const float* p = feat + (long long)n*384;
  int tid = threadIdx.x;
  #pragma unroll
  for (int k=0;k<3;k++){
    int c = tid + k*128;
    float v = p[c];
    atomicAdd(&fsum[(long long)s*384+c], v);
    atomicMax(&fmax[(long long)s*384+c], fkey(v));
  }
  if (tid==0) atomicAdd(&cnt[s], 1.0f);
}

// ---------- cell = bn_gelu(max + mean) ----------
__global__ __launch_bounds__(128)
void cell_kernel(const float* __restrict__ fsum, const unsigned* __restrict__ fmax,
                 const float* __restrict__ cnt,
                 const float* __restrict__ g, const float* __restrict__ bb,
                 const float* __restrict__ m, const float* __restrict__ v,
                 float* __restrict__ out)
{
  int s = blockIdx.x;
  float cn = cnt[s];
  float denom = fmaxf(cn, 1.f);
  int tid = threadIdx.x;
  #pragma unroll
  for (int k=0;k<3;k++){
    int c = tid + k*128;
    float mx = (cn>0.f) ? fdec(fmax[(long long)s*384+c]) : 0.f;
    float t = mx + fsum[(long long)s*384+c]/denom;
    t = (t - m[c])*rsqrtf(v[c]+1e-5f)*g[c] + bb[c];
    out[(long long)s*384+c] = geluf(t);
  }
}

// ---------- final cosine-sim weighted combine ----------
__global__ __launch_bounds__(128)
void combine_kernel(const float* __restrict__ pts, const float* __restrict__ cell3,
                    const int* __restrict__ cluster, const float* __restrict__ cell2,
                    const int* __restrict__ gidx, float* __restrict__ out)
{
  int n = blockIdx.x;
  int tid = threadIdx.x;
  __shared__ float sdot[6], ssq[6], sw[6];
  __shared__ int soff[6];
  __shared__ float red[2][2];
  __shared__ float sn3;
  const float* x3 = cell3 + (long long)cluster[n]*384;
  int wid=tid>>6, lane=tid&63;
  float sq=0.f;
  for (int c=tid;c<384;c+=128){ float v=x3[c]; sq+=v*v; }
  sq = wsum(sq);
  if (lane==0) red[0][wid]=sq;
  __syncthreads();
  if (tid==0) sn3 = sqrtf(red[0][0]+red[0][1]);
  __syncthreads();
  for (int i=0;i<6;i++){
    int gi = gidx[(long long)i*8192 + n];
    if (tid==0) soff[i]=gi;
    const float* r = cell2 + ((long long)i*4096 + gi)*384;
    float d=0.f, s2=0.f;
    for (int c=tid;c<384;c+=128){ float a=r[c]; d+=a*x3[c]; s2+=a*a; }
    d = wsum(d); s2 = wsum(s2);
    if (lane==0){ red[0][wid]=d; red[1][wid]=s2; }
    __syncthreads();
    if (tid==0){ sdot[i]=red[0][0]+red[0][1]; ssq[i]=red[1][0]+red[1][1]; }
    __syncthreads();
  }
  if (tid==0){
    float ssumv=0.f; float sims[6];
    for (int i=0;i<6;i++){
      float nrm = sqrtf(ssq[i])*sn3;
      float s = (sdot[i]/fmaxf(nrm,1e-8f) + 1.f)*0.5f;
      sims[i]=s; ssumv+=s;
    }
    for (int i=0;i<6;i++) sw[i]=sims[i]/ssumv;
  }
  __syncthreads();
  int b = n>>11, gp = n&2047;
  float* o = out + ((long long)(b*2049 + 1 + gp))*384;
  for (int c=tid;c<384;c+=128){
    float acc=0.f;
    #pragma unroll
    for (int i=0;i<6;i++){
      const float* r = cell2 + ((long long)i*4096 + soff[i])*384;
      acc += sw[i]*r[c];
    }
    o[c] = pts[(long long)n*384+c] + 0.5f*acc;
  }
}

// ---------- host helpers ----------
static inline void launch_gemm16(hipStream_t s, const short* A,int lda,long long sA,
  const short* B,int ldb,long long sB, const float* bias,
  const float* res,int ldr,long long sR, void* out,int ldo,long long sO,int outbf16,
  int M,int N,int K,int act,int nz,int KS)
{
  dim3 g((N+TBN-1)/TBN,(M+TBM-1)/TBM,(unsigned)(nz*KS));
  hipLaunchKernelGGL(gemm_bf16,g,dim3(256),0,s,
    A,lda,sA,B,ldb,sB,bias,res,ldr,sR,out,ldo,sO,outbf16,M,N,K,act,KS);
}
static inline void launch_gemm16b(hipStream_t s, const short* A,int lda,long long sA,
  const short* B,int ldb,long long sB, const float* bias,
  const float* res,int ldr,long long sR, void* out,int ldo,long long sO,int outbf16,
  int M,int N,int K,int act,int nz,int KS)
{
  dim3 g((N+XBN-1)/XBN,(M+XBM-1)/XBM,(unsigned)(nz*KS));
  hipLaunchKernelGGL(gemm_bf16_big,g,dim3(256),0,s,
    A,lda,sA,B,ldb,sB,bias,res,ldr,sR,out,ldo,sO,outbf16,M,N,K,act,KS);
}
static inline void launch_tconv(hipStream_t s, const float* in,int ldin,long long sIn,long long sIn2,int zmod,
  int R,int C, short* out,int ldout,long long sOut,int nz)
{
  dim3 g((ldout+31)/32,(C+31)/32,(unsigned)nz);
  hipLaunchKernelGGL(tconv_kernel,g,dim3(256),0,s, in,ldin,sIn,sIn2,zmod,R,C,out,ldout,sOut);
}
static inline void launch_tconv16(hipStream_t s, const short* in,int ldin,long long sIn,long long sIn2,int zmod,
  int R,int C, short* out,int ldout,long long sOut,int nz)
{
  dim3 g((ldout+31)/32,(C+31)/32,(unsigned)nz);
  hipLaunchKernelGGL(tconv16_kernel,g,dim3(256),0,s, in,ldin,sIn,sIn2,zmod,R,C,out,ldout,sOut);
}
static inline void launch_cvt(hipStream_t s, const float* in, short* out, long long n){
  long long n4 = n/4;
  hipLaunchKernelGGL(cvt_kernel,dim3((unsigned)((n4+255)/256)),dim3(256),0,s,in,out,n4);
}

extern "C" void kernel_launch(void* const* d_in, const int* in_sizes, int n_in,
                              void* d_out, int out_size, void* d_ws, size_t ws_size,
                              hipStream_t stream)
{
  const float* x       = (const float*)d_in[0];
  const float* norm1_g = (const float*)d_in[2];
  const float* norm1_b = (const float*)d_in[3];
  const float* qkv_w   = (const float*)d_in[4];
  const float* proj_w  = (const float*)d_in[5];
  const float* proj_b  = (const float*)d_in[6];
  const float* norm2_g = (const float*)d_in[7];
  const float* norm2_b = (const float*)d_in[8];
  const float* fc1_w   = (const float*)d_in[9];
  const float* fc1_b   = (const float*)d_in[10];
  const float* fc2_w   = (const float*)d_in[11];
  const float* fc2_b   = (const float*)d_in[12];
  const float* ada1_w  = (const float*)d_in[13];
  const float* ada1_b  = (const float*)d_in[14];
  const float* ada2_w  = (const float*)d_in[15];
  const float* ada2_b  = (const float*)d_in[16];
  const float* bn3_g   = (const float*)d_in[17];
  const float* bn3_b   = (const float*)d_in[18];
  const float* bn3_m   = (const float*)d_in[19];
  const float* bn3_v   = (const float*)d_in[20];
  const float* bn2_g   = (const float*)d_in[21];
  const float* bn2_b   = (const float*)d_in[22];
  const float* bn2_m   = (const float*)d_in[23];
  const float* bn2_v   = (const float*)d_in[24];
  const float* norm3_g = (const float*)d_in[25];
  const float* norm3_b = (const float*)d_in[26];
  const float* a1_qkv_w  = (const float*)d_in[27];
  const float* a1_proj_w = (const float*)d_in[28];
  const float* a1_proj_b = (const float*)d_in[29];
  const void*  maskp     = d_in[30];
  const int*   cluster   = (const int*)d_in[33];
  const int*   fgi       = (const int*)d_in[34];
  float* out = (float*)d_out;

  // ---- workspace layout ----
  size_t off = 0;
  char* wsb = (char*)d_ws;
  auto alloc = [&](size_t bytes)->void*{
    void* p = wsb + off;
    off += (bytes + 255) & ~(size_t)255;
    return p;
  };
  short*    bufHh = (short*)alloc(8196ll*384*2);
  short*    bufQh = (short*)alloc(8196ll*1152*2);
  short*    Sb16  = (short*)alloc(6ll*2049*2080*2);
  short*    Vt    = (short*)alloc(24ll*64*2080*2);
  float*    bufO  = (float*)alloc(8196ll*384*4);
  short*    bufOh = (short*)alloc(8196ll*384*2);
  short*    bufAh = (short*)alloc(8196ll*96*2);
  float*    bufX  = (float*)alloc(8196ll*384*4);
  float*    ptsb  = (float*)alloc(8192ll*384*4);
  float*    cnt   = (float*)alloc(1024*4);
  float*    fsum  = (float*)alloc(1024ll*384*4);
  unsigned* fmaxe = (unsigned*)alloc(1024ll*384*4);
  float*    cell3 = (float*)alloc(1024ll*384*4);
  float*    gc    = (float*)alloc(4096*4);
  float*    gsum  = (float*)alloc(4096ll*384*4);
  unsigned* gmaxe = (unsigned*)alloc(4096ll*384*4);
  float*    cell2 = (float*)alloc(6ll*4096*384*4);
  short*    qkvT  = (short*)alloc(1152ll*384*2);
  short*    projT = (short*)alloc(384ll*384*2);
  short*    fc1T  = (short*)alloc(1536ll*384*2);
  short*    fc2T  = (short*)alloc(384ll*1536*2);
  short*    ada1T = (short*)alloc(96ll*384*2);
  short*    ada2T = (short*)alloc(384ll*96*2);
  short*    a1qkvT  = (short*)alloc(6ll*1152*384*2);
  short*    a1projT = (short*)alloc(6ll*384*384*2);
  int*      flag  = (int*)alloc(256);
  // aliases (lifetime-disjoint):
  float* bufT   = (float*)Sb16;                             // a1_proj out, per view
  short* bufTh  = (short*)((char*)Sb16 + 14ll*1024*1024);   // fc1 out (FFN window)
  float* bufAda = (float*)bufQh;                            // ada2 out (FFN window)

  // ---- mask dtype detect ----
  hipMemsetAsync(flag, 0, 4, stream);
  {
    long long nInt = 6ll*2048*2048/4;
    detect_mask_kernel<<<dim3((unsigned)((nInt+255)/256)),dim3(256),0,stream>>>((const int*)maskp, nInt, flag);
  }

  // ---- weight transposes (fp32 [K,N] -> bf16 [N,K]) ----
  launch_tconv(stream, qkv_w, 1152, 0,0,1, 384,1152, qkvT, 384, 0, 1);
  launch_tconv(stream, proj_w, 384, 0,0,1, 384,384,  projT, 384, 0, 1);
  launch_tconv(stream, fc1_w, 1536, 0,0,1, 384,1536, fc1T, 384, 0, 1);
  launch_tconv(stream, fc2_w, 384,  0,0,1, 1536,384, fc2T, 1536, 0, 1);
  launch_tconv(stream, ada1_w, 96,  0,0,1, 384,96,   ada1T, 384, 0, 1);
  launch_tconv(stream, ada2_w, 384, 0,0,1, 96,384,   ada2T, 96, 0, 1);
  launch_tconv(stream, a1_qkv_w, 1152, 384ll*1152,0,1, 384,1152, a1qkvT, 384, 1152ll*384, 6);
  launch_tconv(stream, a1_proj_w, 384, 384ll*384,0,1, 384,384,  a1projT, 384, 384ll*384, 6);

  // ---- phase 1: transformer block ----
  ln_bf16_kernel<<<8196,128,0,stream>>>(x, norm1_g, norm1_b, bufHh);
  launch_gemm16b(stream, bufHh,384,0, qkvT,384,0, nullptr, nullptr,0,0,
                 bufQh,1152,0,1, 8196,1152,384, 0, 1,1);
  // V^T for inner attention: z=(b*6+h), in bf16 [2049x64] slice -> out [64][2080]
  launch_tconv16(stream, bufQh + 768, 1152, 2049ll*1152, 64, 6, 2049, 64, Vt, 2080, 64ll*2080, 24);
  hipMemsetAsync(bufO, 0, 8196ll*384*4, stream);
  for (int b=0;b<4;b++){
    const short* qb = bufQh + (long long)b*2049*1152;
    launch_gemm16b(stream, qb,1152,64, qb+384,1152,64, nullptr, nullptr,0,0,
                   Sb16,2080,2049ll*2080,1, 2049,2049,64, 0, 6,1);
    softmax_bf16<<<dim3(2049,6),256,0,stream>>>(Sb16,2080,2049ll*2080,2049,0.125f,
                                                nullptr,0,0,nullptr);
    launch_gemm16(stream, Sb16,2080,2049ll*2080, Vt + (long long)b*6*64*2080,2080,64ll*2080,
                  nullptr, nullptr,0,0,
                  bufO + (long long)b*2049*384,384,64,0, 2049,64,2080, 0, 6,8);
  }
  launch_cvt(stream, bufO, bufOh, 8196ll*384);
  launch_gemm16b(stream, bufOh,384,0, projT,384,0, proj_b, x,384,0,
                 bufX,384,0,0, 8196,384,384, 0, 1,1);
  ln_bf16_kernel<<<8196,128,0,stream>>>(bufX, norm2_g, norm2_b, bufHh);
  launch_gemm16b(stream, bufHh,384,0, fc1T,384,0, fc1_b, nullptr,0,0,
                 bufTh,1536,0,1, 8196,1536,384, 1, 1,1);
  launch_gemm16b(stream, bufTh,1536,0, fc2T,1536,0, fc2_b, nullptr,0,0,
                 bufO,384,0,0, 8196,384,1536, 0, 1,1);
  launch_cvt(stream, bufO, bufOh, 8196ll*384);
  launch_gemm16(stream, bufOh,384,0, ada1T,384,0, ada1_b, nullptr,0,0,
                bufAh,96,0,1, 8196,96,384, 2, 1,1);
  launch_gemm16b(stream, bufAh,96,0, ada2T,96,0, ada2_b, nullptr,0,0,
                 bufAda,384,0,0, 8196,384,96, 0, 1,1);
  ew_x2_kernel<<<dim3((8196*384+255)/256),256,0,stream>>>(bufX, bufO, bufAda, 8196ll*384);
  copy_cls_kernel<<<6,256,0,stream>>>(bufX, out);
  copy_pts_kernel<<<dim3((8192*384+255)/256),256,0,stream>>>(bufX, ptsb);

  // ---- phase 2: cluster pooling -> cell3 ----
  hipMemsetAsync(cnt, 0, 1024*4, stream);
  hipMemsetAsync(fsum, 0, 1024ll*384*4, stream);
  hipMemsetAsync(fmaxe, 0, 1024ll*384*4, stream);
  scatter_seg_kernel<<<8192,128,0,stream>>>(ptsb, cluster, fsum, fmaxe, cnt);
  cell_kernel<<<1024,128,0,stream>>>(fsum, fmaxe, cnt, bn3_g,bn3_b,bn3_m,bn3_v, cell3);

  // ---- phase 3: views ----
  for (int i=0;i<6;i++){
    ln_bf16_kernel<<<8192,128,0,stream>>>(ptsb, norm3_g + (long long)i*384, norm3_b + (long long)i*384, bufHh);
    launch_gemm16b(stream, bufHh,384,0, a1qkvT + (long long)i*1152*384,384,0,
                   nullptr, nullptr,0,0, bufQh,1152,0,1, 8192,1152,384, 0, 1,1);
    launch_tconv16(stream, bufQh + 768, 1152, 2048ll*1152, 0, 1, 2048, 384, Vt, 2048, 384ll*2048, 4);
    launch_gemm16b(stream, bufQh,1152,2048ll*1152, bufQh+384,1152,2048ll*1152,
                   nullptr, nullptr,0,0, Sb16,2048,2048ll*2048,1, 2048,2048,384, 0, 4,1);
    softmax_bf16<<<dim3(2048,4),256,0,stream>>>(Sb16,2048,2048ll*2048,2048,
                0.05103103630798288f, maskp, (long long)i*2048*2048, 2048, flag);
    hipMemsetAsync(bufO, 0, 8192ll*384*4, stream);
    launch_gemm16b(stream, Sb16,2048,2048ll*2048, Vt,2048,384ll*2048,
                   nullptr, nullptr,0,0, bufO,384,2048ll*384,0, 2048,384,2048, 0, 4,2);
    launch_cvt(stream, bufO, bufOh, 8192ll*384);
    launch_gemm16b(stream, bufOh,384,0, a1projT + (long long)i*384*384,384,0,
                   a1_proj_b + (long long)i*384, ptsb,384,0,
                   bufT,384,0,0, 8192,384,384, 0, 1,1);
    hipMemsetAsync(gc, 0, 4096*4, stream);
    hipMemsetAsync(gsum, 0, 4096ll*384*4, stream);
    hipMemsetAsync(gmaxe, 0, 4096ll*384*4, stream);
    scatter_seg_kernel<<<8192,128,0,stream>>>(bufT, fgi + (long long)i*8192, gsum, gmaxe, gc);
    cell_kernel<<<4096,128,0,stream>>>(gsum, gmaxe, gc,
        bn2_g + (long long)i*384, bn2_b + (long long)i*384,
        bn2_m + (long long)i*384, bn2_v + (long long)i*384,
        cell2 + (long long)i*4096*384);
  }

  // ---- phase 4: combine ----
  combine_kernel<<<8192,128,0,stream>>>(ptsb, cell3, cluster, cell2, fgi, out);
}

// Round 5
// 2159.862 us; speedup vs baseline: 1.2452x; 1.2452x over previous
//
#include <hip/hip_runtime.h>
#include <math.h>

typedef short bf16x8 __attribute__((ext_vector_type(8)));
typedef float f32x4 __attribute__((ext_vector_type(4)));

#define GLL16(g, l) \
  __builtin_amdgcn_global_load_lds((__attribute__((address_space(1))) const unsigned int*)(g), \
                                   (__attribute__((address_space(3))) unsigned int*)(l), 16, 0, 0)

// ---------- helpers ----------
__device__ __forceinline__ float wsum(float v){
  #pragma unroll
  for (int o=32;o;o>>=1) v += __shfl_xor(v,o);
  return v;
}
__device__ __forceinline__ float geluf(float x){
  return 0.5f*x*(1.0f+erff(x*0.7071067811865475f));
}
__device__ __forceinline__ short fbf(float f){   // fp32 -> bf16 RNE
  unsigned u = __float_as_uint(f);
  unsigned r = (u + 0x7fffu + ((u>>16)&1u)) >> 16;
  return (short)r;
}
__device__ __forceinline__ float bff(short s){
  return __uint_as_float(((unsigned)(unsigned short)s)<<16);
}
__device__ __forceinline__ unsigned fkey(float f){
  unsigned b=__float_as_uint(f);
  return (b&0x80000000u)? ~b : (b|0x80000000u);
}
__device__ __forceinline__ float fdec(unsigned k){
  unsigned b=(k&0x80000000u)? (k&0x7fffffffu) : ~k;
  return __uint_as_float(b);
}

// ---------- mask dtype detection + byte conversion ----------
__global__ void detect_mask_kernel(const int* __restrict__ m, long long n, int* flag){
  long long i = (long long)blockIdx.x*256 + threadIdx.x;
  bool bad = (i<n) && (m[i]!=0 && m[i]!=1);
  if (__any(bad)) { if ((threadIdx.x&63)==0) atomicOr(flag,1); }
}
__global__ void mask_byte_kernel(const void* __restrict__ m, unsigned char* __restrict__ mb,
                                 long long n4, const int* __restrict__ flag){
  long long i = (long long)blockIdx.x*256 + threadIdx.x;
  if (i>=n4) return;
  int mode = *flag;
  uchar4 o;
  if (mode){ o = ((const uchar4*)m)[i]; o.x=o.x!=0; o.y=o.y!=0; o.z=o.z!=0; o.w=o.w!=0; }
  else { int4 v = ((const int4*)m)[i];
         o.x=(unsigned char)(v.x!=0); o.y=(unsigned char)(v.y!=0);
         o.z=(unsigned char)(v.z!=0); o.w=(unsigned char)(v.w!=0); }
  ((uchar4*)mb)[i]=o;
}

// epilogue shared by GEMMs
__device__ __forceinline__ float epi(float v, const float* bias, int col, int act){
  if (bias) v += bias[col];
  if (act==1) v = geluf(v);
  else if (act==2) v = v*(1.f/(1.f+__expf(-1.702f*v)));
  return v;
}

// ---------- bf16 MFMA GEMM, 128x128 tile ----------
#define XBM 128
#define XBN 128
#define XBK 32
__global__ __launch_bounds__(256)
void gemm_bf16_big(const short* __restrict__ A, int lda, long long sA,
                   const short* __restrict__ B, int ldb, long long sB,
                   const float* __restrict__ bias,
                   const float* __restrict__ res, int ldr, long long sR,
                   void* __restrict__ out, int ldo, long long sO, int outbf16,
                   int M, int N, int K, int act, int KS)
{
  __shared__ short As[XBM*XBK];
  __shared__ short Bs[XBN*XBK];
  int zz = blockIdx.z;
  int z = zz / KS, ks = zz - z*KS;
  A += (long long)z*sA; B += (long long)z*sB;
  if (res) res += (long long)z*sR;
  float* outF = (float*)out + (long long)z*sO;
  short* outH = (short*)out + (long long)z*sO;

  int tid = threadIdx.x;
  int rowBase = blockIdx.y*XBM;
  int colBase = blockIdx.x*XBN;

  int Kc = ((K + KS*XBK - 1)/(KS*XBK))*XBK;
  int kbeg = ks*Kc;
  int kend = min(K, kbeg+Kc);
  if (kbeg >= kend) return;

  int w = tid>>6;
  int lane = tid&63;
  int lm = lane&15, quad = lane>>4;
  int waveM = w>>1, waveN = w&1;

  int arow0 = min(rowBase + w*32 + lm,      M-1);
  int arow1 = min(rowBase + w*32 + 16 + lm, M-1);
  int brow0 = min(colBase + w*32 + lm,      N-1);
  int brow1 = min(colBase + w*32 + 16 + lm, N-1);
  const short* Ag0 = A + (long long)arow0*lda + quad*8;
  const short* Ag1 = A + (long long)arow1*lda + quad*8;
  const short* Bg0 = B + (long long)brow0*ldb + quad*8;
  const short* Bg1 = B + (long long)brow1*ldb + quad*8;
  short* Al0 = &As[(w*2+0)*512];
  short* Al1 = &As[(w*2+1)*512];
  short* Bl0 = &Bs[(w*2+0)*512];
  short* Bl1 = &Bs[(w*2+1)*512];

  f32x4 acc[4][4] = {};

  for (int k0=kbeg; k0<kend; k0+=XBK){
    GLL16(Ag0 + k0, Al0);
    GLL16(Ag1 + k0, Al1);
    GLL16(Bg0 + k0, Bl0);
    GLL16(Bg1 + k0, Bl1);
    __syncthreads();
    bf16x8 af[4], bfr[4];
    #pragma unroll
    for (int tm=0;tm<4;tm++) af[tm]  = *(bf16x8*)&As[(waveM*4+tm)*512 + quad*128 + lm*8];
    #pragma unroll
    for (int tn=0;tn<4;tn++) bfr[tn] = *(bf16x8*)&Bs[(waveN*4+tn)*512 + quad*128 + lm*8];
    #pragma unroll
    for (int tm=0;tm<4;tm++)
      #pragma unroll
      for (int tn=0;tn<4;tn++)
        acc[tm][tn] = __builtin_amdgcn_mfma_f32_16x16x32_bf16(af[tm], bfr[tn], acc[tm][tn], 0,0,0);
    __syncthreads();
  }

  #pragma unroll
  for (int tm=0;tm<4;tm++){
    #pragma unroll
    for (int tn=0;tn<4;tn++){
      int col = colBase + waveN*64 + tn*16 + lm;
      if (col>=N) continue;
      #pragma unroll
      for (int reg=0;reg<4;reg++){
        int row = rowBase + waveM*64 + tm*16 + quad*4 + reg;
        if (row>=M) continue;
        float v = acc[tm][tn][reg];
        if (KS>1){ atomicAdd(&outF[(long long)row*ldo+col], v); continue; }
        v = epi(v, bias, col, act);
        if (res) v += res[(long long)row*ldr+col];
        if (outbf16) outH[(long long)row*ldo+col] = fbf(v);
        else         outF[(long long)row*ldo+col] = v;
      }
    }
  }
}

// ---------- bf16 MFMA GEMM, 128x64 tile ----------
#define TBM 128
#define TBN 64
#define TBK 32
__global__ __launch_bounds__(256)
void gemm_bf16(const short* __restrict__ A, int lda, long long sA,
               const short* __restrict__ B, int ldb, long long sB,
               const float* __restrict__ bias,
               const float* __restrict__ res, int ldr, long long sR,
               void* __restrict__ out, int ldo, long long sO, int outbf16,
               int M, int N, int K, int act, int KS)
{
  __shared__ short As[TBM*TBK];
  __shared__ short Bs[TBN*TBK];
  int zz = blockIdx.z;
  int z = zz / KS, ks = zz - z*KS;
  A += (long long)z*sA; B += (long long)z*sB;
  if (res) res += (long long)z*sR;
  float* outF = (float*)out + (long long)z*sO;
  short* outH = (short*)out + (long long)z*sO;

  int tid = threadIdx.x;
  int rowBase = blockIdx.y*TBM;
  int colBase = blockIdx.x*TBN;

  int Kc = ((K + KS*TBK - 1)/(KS*TBK))*TBK;
  int kbeg = ks*Kc;
  int kend = min(K, kbeg+Kc);
  if (kbeg >= kend) return;

  int w = tid>>6;
  int lane = tid&63;
  int lm = lane&15, quad = lane>>4;
  int waveM = w>>1, waveN = w&1;

  int arow0 = min(rowBase + w*32 + lm,      M-1);
  int arow1 = min(rowBase + w*32 + 16 + lm, M-1);
  int brow  = min(colBase + w*16 + lm,      N-1);
  const short* Ag0 = A + (long long)arow0*lda + quad*8;
  const short* Ag1 = A + (long long)arow1*lda + quad*8;
  const short* Bg  = B + (long long)brow*ldb  + quad*8;
  short* Al0 = &As[(w*2+0)*512];
  short* Al1 = &As[(w*2+1)*512];
  short* Bl  = &Bs[w*512];

  f32x4 acc[4][2] = {};

  for (int k0=kbeg; k0<kend; k0+=TBK){
    GLL16(Ag0 + k0, Al0);
    GLL16(Ag1 + k0, Al1);
    GLL16(Bg  + k0, Bl);
    __syncthreads();
    bf16x8 af[4], bfr[2];
    #pragma unroll
    for (int tm=0;tm<4;tm++) af[tm]  = *(bf16x8*)&As[(waveM*4+tm)*512 + quad*128 + lm*8];
    #pragma unroll
    for (int tn=0;tn<2;tn++) bfr[tn] = *(bf16x8*)&Bs[(waveN*2+tn)*512 + quad*128 + lm*8];
    #pragma unroll
    for (int tm=0;tm<4;tm++)
      #pragma unroll
      for (int tn=0;tn<2;tn++)
        acc[tm][tn] = __builtin_amdgcn_mfma_f32_16x16x32_bf16(af[tm], bfr[tn], acc[tm][tn], 0,0,0);
    __syncthreads();
  }

  #pragma unroll
  for (int tm=0;tm<4;tm++){
    #pragma unroll
    for (int tn=0;tn<2;tn++){
      int col = colBase + waveN*32 + tn*16 + lm;
      if (col>=N) continue;
      #pragma unroll
      for (int reg=0;reg<4;reg++){
        int row = rowBase + waveM*64 + tm*16 + quad*4 + reg;
        if (row>=M) continue;
        float v = acc[tm][tn][reg];
        if (KS>1){ atomicAdd(&outF[(long long)row*ldo+col], v); continue; }
        v = epi(v, bias, col, act);
        if (res) v += res[(long long)row*ldr+col];
        if (outbf16) outH[(long long)row*ldo+col] = fbf(v);
        else         outF[(long long)row*ldo+col] = v;
      }
    }
  }
}

// ---------- bf16 MFMA GEMM, 64x64 tile (narrow-N, high block count) ----------
__global__ __launch_bounds__(256)
void gemm_bf16_s(const short* __restrict__ A, int lda, long long sA,
                 const short* __restrict__ B, int ldb, long long sB,
                 const float* __restrict__ bias,
                 const float* __restrict__ res, int ldr, long long sR,
                 void* __restrict__ out, int ldo, long long sO, int outbf16,
                 int M, int N, int K, int act)
{
  __shared__ short As[64*32];
  __shared__ short Bs[64*32];
  int z = blockIdx.z;
  A += (long long)z*sA; B += (long long)z*sB;
  if (res) res += (long long)z*sR;
  float* outF = (float*)out + (long long)z*sO;
  short* outH = (short*)out + (long long)z*sO;

  int tid = threadIdx.x;
  int rowBase = blockIdx.y*64;
  int colBase = blockIdx.x*64;

  int w = tid>>6;
  int lane = tid&63;
  int lm = lane&15, quad = lane>>4;
  int wm = w>>1, wn = w&1;

  int arow = min(rowBase + w*16 + lm, M-1);
  int brow = min(colBase + w*16 + lm, N-1);
  const short* Ag = A + (long long)arow*lda + quad*8;
  const short* Bg = B + (long long)brow*ldb + quad*8;
  short* Al = &As[w*512];
  short* Bl = &Bs[w*512];

  f32x4 acc[2][2] = {};

  for (int k0=0; k0<K; k0+=32){
    GLL16(Ag + k0, Al);
    GLL16(Bg + k0, Bl);
    __syncthreads();
    bf16x8 af[2], bfr[2];
    #pragma unroll
    for (int tm=0;tm<2;tm++) af[tm]  = *(bf16x8*)&As[(wm*2+tm)*512 + quad*128 + lm*8];
    #pragma unroll
    for (int tn=0;tn<2;tn++) bfr[tn] = *(bf16x8*)&Bs[(wn*2+tn)*512 + quad*128 + lm*8];
    #pragma unroll
    for (int tm=0;tm<2;tm++)
      #pragma unroll
      for (int tn=0;tn<2;tn++)
        acc[tm][tn] = __builtin_amdgcn_mfma_f32_16x16x32_bf16(af[tm], bfr[tn], acc[tm][tn], 0,0,0);
    __syncthreads();
  }

  #pragma unroll
  for (int tm=0;tm<2;tm++){
    #pragma unroll
    for (int tn=0;tn<2;tn++){
      int col = colBase + wn*32 + tn*16 + lm;
      if (col>=N) continue;
      #pragma unroll
      for (int reg=0;reg<4;reg++){
        int row = rowBase + wm*32 + tm*16 + quad*4 + reg;
        if (row>=M) continue;
        float v = epi(acc[tm][tn][reg], bias, col, act);
        if (res) v += res[(long long)row*ldr+col];
        if (outbf16) outH[(long long)row*ldo+col] = fbf(v);
        else         outF[(long long)row*ldo+col] = v;
      }
    }
  }
}

// ---------- flash-fused view attention ----------
// grid (32 qtiles, 4 b, 6 v), 256 threads. Wave w owns q-rows qt*64+w*16..+16.
// QK6: [6][8192][768] bf16 (Q cols 0..384, K cols 384..768)
// Vt6: [24][384][2048] bf16 (V^T per (v,b))
// maskb: [6][2048][2048] u8;  O6: [6][8192][384] bf16
__global__ __launch_bounds__(256,2)
void flash_view(const short* __restrict__ QK6, const short* __restrict__ Vt6,
                const unsigned char* __restrict__ maskb, short* __restrict__ O6)
{
  __shared__ char lds[58368];
  // layout: Q-stage phase: [0,49152) 12 chunks x 4096
  // main:   K ping-pong [0,16384), VT [16384,40960), P [40960,58368) (4 x 4352)
  const float scale = 0.05103103630798288f;
  int qt=blockIdx.x, b=blockIdx.y, v=blockIdx.z;
  int tid=threadIdx.x, w=tid>>6, lane=tid&63, lm=lane&15, quad=lane>>4;

  const short* Qp = QK6 + ((long long)v*8192 + b*2048 + qt*64)*768;
  const short* Kp = QK6 + ((long long)v*8192 + b*2048)*768 + 384;
  const short* Vp = Vt6 + (long long)(v*4+b)*384*2048;
  const unsigned char* Mp = maskb + (long long)v*2048*2048 + (long long)qt*64*2048;
  short* Op = O6 + ((long long)v*8192 + b*2048 + qt*64)*384;

  // stage Q tile (64x384) then pull this wave's 12 A-frags into regs
  #pragma unroll
  for (int c=0;c<12;c++)
    GLL16(Qp + (w*16+lm)*768 + c*32 + quad*8, (short*)(lds + c*4096 + w*1024));
  __syncthreads();
  bf16x8 af[12];
  #pragma unroll
  for (int c=0;c<12;c++)
    af[c] = *(bf16x8*)(lds + c*4096 + w*1024 + quad*256 + lm*16);
  __syncthreads();

  float m_i[4], l_i[4];
  #pragma unroll
  for (int r=0;r<4;r++){ m_i[r]=-3.0e38f; l_i[r]=0.f; }
  f32x4 Oacc[24] = {};
  short* Pw = (short*)(lds + 40960 + w*4352);   // [16][136] bf16, wave-private

  for (int kt=0; kt<16; kt++){
    // ---- S partial: Q(16x384) @ K-tile(128x384)^T
    f32x4 S[8];
    #pragma unroll
    for (int i=0;i<8;i++) S[i] = (f32x4){0.f,0.f,0.f,0.f};
    {
      int rb=w*2;
      GLL16(Kp + (long long)(kt*128 + rb*16 + lm)*768 + quad*8,       (short*)(lds + rb*1024));
      GLL16(Kp + (long long)(kt*128 + (rb+1)*16 + lm)*768 + quad*8,   (short*)(lds + (rb+1)*1024));
    }
    __syncthreads();
    #pragma unroll
    for (int kc=0;kc<12;kc++){
      if (kc<11){
        int p1=(kc+1)&1; int rb=w*2;
        GLL16(Kp + (long long)(kt*128 + rb*16 + lm)*768 + (kc+1)*32 + quad*8,     (short*)(lds + p1*8192 + rb*1024));
        GLL16(Kp + (long long)(kt*128 + (rb+1)*16 + lm)*768 + (kc+1)*32 + quad*8, (short*)(lds + p1*8192 + (rb+1)*1024));
      }
      int p=kc&1;
      #pragma unroll
      for (int ct=0;ct<8;ct++){
        bf16x8 bf = *(bf16x8*)(lds + p*8192 + ct*1024 + quad*256 + lm*16);
        S[ct] = __builtin_amdgcn_mfma_f32_16x16x32_bf16(af[kc], bf, S[ct], 0,0,0);
      }
      __syncthreads();
    }

    // ---- mask + scale (in place)
    #pragma unroll
    for (int ct=0;ct<8;ct++){
      #pragma unroll
      for (int r=0;r<4;r++){
        unsigned char mb = Mp[(long long)(w*16+quad*4+r)*2048 + kt*128 + ct*16 + lm];
        S[ct][r] = mb ? S[ct][r]*scale : -3.0e38f;
      }
    }
    // ---- online softmax (wave-local; rows live in 16-lane groups)
    float alpha[4], mnew[4];
    #pragma unroll
    for (int r=0;r<4;r++){
      float rm = S[0][r];
      #pragma unroll
      for (int ct=1;ct<8;ct++) rm = fmaxf(rm, S[ct][r]);
      #pragma unroll
      for (int o=1;o<16;o<<=1) rm = fmaxf(rm, __shfl_xor(rm, o));
      mnew[r] = fmaxf(m_i[r], rm);
      alpha[r] = __expf(m_i[r]-mnew[r]);
      m_i[r] = mnew[r];
    }
    float rs[4] = {0.f,0.f,0.f,0.f};
    #pragma unroll
    for (int ct=0;ct<8;ct++){
      #pragma unroll
      for (int r=0;r<4;r++){
        float sv = S[ct][r];
        float p = (sv > -1.0e37f) ? __expf(sv - mnew[r]) : 0.f;
        rs[r] += p;
        Pw[(quad*4+r)*136 + ct*16 + lm] = fbf(p);
      }
    }
    #pragma unroll
    for (int r=0;r<4;r++){
      #pragma unroll
      for (int o=1;o<16;o<<=1) rs[r] += __shfl_xor(rs[r], o);
      l_i[r] = l_i[r]*alpha[r] + rs[r];
    }
    #pragma unroll
    for (int tn=0;tn<24;tn++){
      #pragma unroll
      for (int r=0;r<4;r++) Oacc[tn][r] *= alpha[r];
    }

    // ---- PV: P(16x128) @ V-tile(128x384), V^T staged in shared LDS
    #pragma unroll
    for (int kk=0;kk<4;kk++){
      __syncthreads();
      #pragma unroll
      for (int j=0;j<6;j++){
        int rb = w + j*4;
        GLL16(Vp + (long long)(rb*16+lm)*2048 + kt*128 + kk*32 + quad*8, (short*)(lds + 16384 + rb*1024));
      }
      __syncthreads();
      bf16x8 ap = *(bf16x8*)((char*)Pw + (lm*136 + kk*32 + quad*8)*2);
      #pragma unroll
      for (int tn=0;tn<24;tn++){
        bf16x8 bf = *(bf16x8*)(lds + 16384 + tn*1024 + quad*256 + lm*16);
        Oacc[tn] = __builtin_amdgcn_mfma_f32_16x16x32_bf16(ap, bf, Oacc[tn], 0,0,0);
      }
    }
  }

  // ---- epilogue: O / l, store bf16
  #pragma unroll
  for (int tn=0;tn<24;tn++){
    #pragma unroll
    for (int r=0;r<4;r++){
      float o = Oacc[tn][r] / l_i[r];
      Op[(long long)(w*16+quad*4+r)*384 + tn*16 + lm] = fbf(o);
    }
  }
}

// ---------- softmax in-place on bf16 scores (inner attention, no mask) ----------
__global__ __launch_bounds__(256)
void softmax_bf16(short* __restrict__ S, int ld, long long sS, int cols, float alpha)
{
  __shared__ float buf[2080];
  __shared__ float red[4];
  int row = blockIdx.x, z = blockIdx.y;
  short* p = S + (long long)z*sS + (long long)row*ld;
  int tid = threadIdx.x;
  float mx = -3.4e38f;
  for (int c=tid;c<cols;c+=256){
    float v = bff(p[c])*alpha;
    buf[c] = v;
    mx = fmaxf(mx, v);
  }
  #pragma unroll
  for (int o=32;o;o>>=1) mx = fmaxf(mx,__shfl_xor(mx,o));
  int wid = tid>>6, lane = tid&63;
  if (lane==0) red[wid]=mx;
  __syncthreads();
  mx = fmaxf(fmaxf(red[0],red[1]),fmaxf(red[2],red[3]));
  __syncthreads();
  float sum=0.f;
  for (int c=tid;c<cols;c+=256){
    float e = __expf(buf[c]-mx);
    buf[c]=e; sum += e;
  }
  sum = wsum(sum);
  if (lane==0) red[wid]=sum;
  __syncthreads();
  sum = red[0]+red[1]+red[2]+red[3];
  float inv = 1.f/sum;
  for (int c=tid;c<cols;c+=256) p[c] = fbf(buf[c]*inv);
  for (int c=cols+tid;c<ld;c+=256) p[c] = 0;
}

// ---------- LayerNorm (fp32 in -> bf16 out), C=384 ----------
__global__ __launch_bounds__(128)
void ln_bf16_kernel(const float* __restrict__ in, const float* __restrict__ g,
                    const float* __restrict__ bt, short* __restrict__ out)
{
  long long row = blockIdx.x;
  const float* p = in + row*384;
  int tid = threadIdx.x;
  float v0=p[tid], v1=p[tid+128], v2=p[tid+256];
  float s = v0+v1+v2;
  float ss = v0*v0+v1*v1+v2*v2;
  __shared__ float r1[2], r2[2];
  s = wsum(s); ss = wsum(ss);
  int wid=tid>>6, lane=tid&63;
  if (lane==0){ r1[wid]=s; r2[wid]=ss; }
  __syncthreads();
  float mean=(r1[0]+r1[1])*(1.f/384.f);
  float var =(r2[0]+r2[1])*(1.f/384.f)-mean*mean;
  float rstd=rsqrtf(var+1e-5f);
  short* o = out + row*384;
  o[tid]     = fbf((v0-mean)*rstd*g[tid]+bt[tid]);
  o[tid+128] = fbf((v1-mean)*rstd*g[tid+128]+bt[tid+128]);
  o[tid+256] = fbf((v2-mean)*rstd*g[tid+256]+bt[tid+256]);
}

// ---------- fp32 -> bf16 convert ----------
__global__ void cvt_kernel(const float* __restrict__ in, short* __restrict__ out, long long n4){
  long long i = (long long)blockIdx.x*256 + threadIdx.x;
  if (i<n4){
    float4 f = ((const float4*)in)[i];
    short4 s;
    s.x=fbf(f.x); s.y=fbf(f.y); s.z=fbf(f.z); s.w=fbf(f.w);
    ((short4*)out)[i]=s;
  }
}

// ---------- tiled transpose+convert: fp32 [R,C] -> bf16 [C, ldout] zero-padded ----------
__global__ __launch_bounds__(256)
void tconv_kernel(const float* __restrict__ in, int ldin, long long sIn, long long sIn2, int zmod,
                  int R, int C, short* __restrict__ out, int ldout, long long sOut)
{
  __shared__ float tile[32][33];
  int z = blockIdx.z;
  const float* ip = in + (long long)(z/zmod)*sIn + (long long)(z%zmod)*sIn2;
  short* op = out + (long long)z*sOut;
  int r0 = blockIdx.x*32;
  int c0 = blockIdx.y*32;
  int tx = threadIdx.x&31, ty = threadIdx.x>>5;
  #pragma unroll
  for (int i=0;i<4;i++){
    int r = r0 + ty + i*8, c = c0 + tx;
    tile[ty+i*8][tx] = (r<R && c<C) ? ip[(long long)r*ldin + c] : 0.f;
  }
  __syncthreads();
  #pragma unroll
  for (int i=0;i<4;i++){
    int oc = c0 + ty + i*8;
    int orr = r0 + tx;
    if (oc<C && orr<ldout) op[(long long)oc*ldout + orr] = fbf(tile[tx][ty+i*8]);
  }
}

// ---------- tiled transpose: bf16 [R,C] -> bf16 [C, ldout] zero-padded ----------
__global__ __launch_bounds__(256)
void tconv16_kernel(const short* __restrict__ in, int ldin, long long sIn, long long sIn2, int zmod,
                    int R, int C, short* __restrict__ out, int ldout, long long sOut)
{
  __shared__ short tile[32][34];
  int z = blockIdx.z;
  const short* ip = in + (long long)(z/zmod)*sIn + (long long)(z%zmod)*sIn2;
  short* op = out + (long long)z*sOut;
  int r0 = blockIdx.x*32;
  int c0 = blockIdx.y*32;
  int tx = threadIdx.x&31, ty = threadIdx.x>>5;
  #pragma unroll
  for (int i=0;i<4;i++){
    int r = r0 + ty + i*8, c = c0 + tx;
    tile[ty+i*8][tx] = (r<R && c<C) ? ip[(long long)r*ldin + c] : (short)0;
  }
  __syncthreads();
  #pragma unroll
  for (int i=0;i<4;i++){
    int oc = c0 + ty + i*8;
    int orr = r0 + tx;
    if (oc<C && orr<ldout) op[(long long)oc*ldout + orr] = tile[tx][ty+i*8];
  }
}

// ---------- elementwise ----------
__global__ void ew_x2_kernel(float* x1, const float* ffn, const float* ada, long long n){
  long long i=(long long)blockIdx.x*256+threadIdx.x;
  if (i<n) x1[i] = x1[i] + ffn[i] + 0.5f*ada[i];
}
__global__ void copy_pts_kernel(const float* __restrict__ x2, float* __restrict__ pts){
  long long i=(long long)blockIdx.x*256+threadIdx.x;
  if (i < 8192ll*384){
    long long b = i/(2048ll*384);
    long long rem = i%(2048ll*384);
    pts[i] = x2[(b*2049+1)*384 + rem];
  }
}
__global__ void copy_cls_kernel(const float* __restrict__ x2, float* __restrict__ out){
  int i = blockIdx.x*256+threadIdx.x;
  if (i < 4*384){
    int b=i/384, c=i%384;
    out[(long long)b*2049*384 + c] = x2[(long long)b*2049*384 + c];
  }
}

// ---------- segment scatter (sum + max + count) ----------
__global__ __launch_bounds__(128)
void scatter_seg_kernel(const float* __restrict__ feat, const int* __restrict__ seg,
                        float* __restrict__ fsum, unsigned* __restrict__ fmax,
                        float* __restrict__ cnt)
{
  int n = blockIdx.x;
  int s = seg[n];
  const float* p = feat + (long long)n*384;
  int tid = threadIdx.x;
  #pragma unroll
  for (int k=0;k<3;k++){
    int c = tid + k*128;
    float v = p[c];
    atomicAdd(&fsum[(long long)s*384+c], v);
    atomicMax(&fmax[(long long)s*384+c], fkey(v));
  }
  if (tid==0) atomicAdd(&cnt[s], 1.0f);
}

// ---------- cell = bn_gelu(max + mean) ----------
__global__ __launch_bounds__(128)
void cell_kernel(const float* __restrict__ fsum, const unsigned* __restrict__ fmax,
                 const float* __restrict__ cnt,
                 const float* __restrict__ g, const float* __restrict__ bb,
                 const float* __restrict__ m, const float* __restrict__ v,
                 float* __restrict__ out)
{
  int s = blockIdx.x;
  float cn = cnt[s];
  float denom = fmaxf(cn, 1.f);
  int tid = threadIdx.x;
  #pragma unroll
  for (int k=0;k<3;k++){
    int c = tid + k*128;
    float mx = (cn>0.f) ? fdec(fmax[(long long)s*384+c]) : 0.f;
    float t = mx + fsum[(long long)s*384+c]/denom;
    t = (t - m[c])*rsqrtf(v[c]+1e-5f)*g[c] + bb[c];
    out[(long long)s*384+c] = geluf(t);
  }
}

// ---------- final cosine-sim weighted combine ----------
__global__ __launch_bounds__(128)
void combine_kernel(const float* __restrict__ pts, const float* __restrict__ cell3,
                    const int* __restrict__ cluster, const float* __restrict__ cell2,
                    const int* __restrict__ gidx, float* __restrict__ out)
{
  int n = blockIdx.x;
  int tid = threadIdx.x;
  __shared__ float sdot[6], ssq[6], sw[6];
  __shared__ int soff[6];
  __shared__ float red[2][2];
  __shared__ float sn3;
  const float* x3 = cell3 + (long long)cluster[n]*384;
  int wid=tid>>6, lane=tid&63;
  float sq=0.f;
  for (int c=tid;c<384;c+=128){ float v=x3[c]; sq+=v*v; }
  sq = wsum(sq);
  if (lane==0) red[0][wid]=sq;
  __syncthreads();
  if (tid==0) sn3 = sqrtf(red[0][0]+red[0][1]);
  __syncthreads();
  for (int i=0;i<6;i++){
    int gi = gidx[(long long)i*8192 + n];
    if (tid==0) soff[i]=gi;
    const float* r = cell2 + ((long long)i*4096 + gi)*384;
    float d=0.f, s2=0.f;
    for (int c=tid;c<384;c+=128){ float a=r[c]; d+=a*x3[c]; s2+=a*a; }
    d = wsum(d); s2 = wsum(s2);
    if (lane==0){ red[0][wid]=d; red[1][wid]=s2; }
    __syncthreads();
    if (tid==0){ sdot[i]=red[0][0]+red[0][1]; ssq[i]=red[1][0]+red[1][1]; }
    __syncthreads();
  }
  if (tid==0){
    float ssumv=0.f; float sims[6];
    for (int i=0;i<6;i++){
      float nrm = sqrtf(ssq[i])*sn3;
      float s = (sdot[i]/fmaxf(nrm,1e-8f) + 1.f)*0.5f;
      sims[i]=s; ssumv+=s;
    }
    for (int i=0;i<6;i++) sw[i]=sims[i]/ssumv;
  }
  __syncthreads();
  int b = n>>11, gp = n&2047;
  float* o = out + ((long long)(b*2049 + 1 + gp))*384;
  for (int c=tid;c<384;c+=128){
    float acc=0.f;
    #pragma unroll
    for (int i=0;i<6;i++){
      const float* r = cell2 + ((long long)i*4096 + soff[i])*384;
      acc += sw[i]*r[c];
    }
    o[c] = pts[(long long)n*384+c] + 0.5f*acc;
  }
}

// ---------- host helpers ----------
static inline void launch_gemm16(hipStream_t s, const short* A,int lda,long long sA,
  const short* B,int ldb,long long sB, const float* bias,
  const float* res,int ldr,long long sR, void* out,int ldo,long long sO,int outbf16,
  int M,int N,int K,int act,int nz,int KS)
{
  dim3 g((N+TBN-1)/TBN,(M+TBM-1)/TBM,(unsigned)(nz*KS));
  hipLaunchKernelGGL(gemm_bf16,g,dim3(256),0,s,
    A,lda,sA,B,ldb,sB,bias,res,ldr,sR,out,ldo,sO,outbf16,M,N,K,act,KS);
}
static inline void launch_gemm16b(hipStream_t s, const short* A,int lda,long long sA,
  const short* B,int ldb,long long sB, const float* bias,
  const float* res,int ldr,long long sR, void* out,int ldo,long long sO,int outbf16,
  int M,int N,int K,int act,int nz,int KS)
{
  dim3 g((N+XBN-1)/XBN,(M+XBM-1)/XBM,(unsigned)(nz*KS));
  hipLaunchKernelGGL(gemm_bf16_big,g,dim3(256),0,s,
    A,lda,sA,B,ldb,sB,bias,res,ldr,sR,out,ldo,sO,outbf16,M,N,K,act,KS);
}
static inline void launch_gemm16s(hipStream_t s, const short* A,int lda,long long sA,
  const short* B,int ldb,long long sB, const float* bias,
  const float* res,int ldr,long long sR, void* out,int ldo,long long sO,int outbf16,
  int M,int N,int K,int act,int nz)
{
  dim3 g((N+63)/64,(M+63)/64,(unsigned)nz);
  hipLaunchKernelGGL(gemm_bf16_s,g,dim3(256),0,s,
    A,lda,sA,B,ldb,sB,bias,res,ldr,sR,out,ldo,sO,outbf16,M,N,K,act);
}
static inline void launch_tconv(hipStream_t s, const float* in,int ldin,long long sIn,long long sIn2,int zmod,
  int R,int C, short* out,int ldout,long long sOut,int nz)
{
  dim3 g((ldout+31)/32,(C+31)/32,(unsigned)nz);
  hipLaunchKernelGGL(tconv_kernel,g,dim3(256),0,s, in,ldin,sIn,sIn2,zmod,R,C,out,ldout,sOut);
}
static inline void launch_tconv16(hipStream_t s, const short* in,int ldin,long long sIn,long long sIn2,int zmod,
  int R,int C, short* out,int ldout,long long sOut,int nz)
{
  dim3 g((ldout+31)/32,(C+31)/32,(unsigned)nz);
  hipLaunchKernelGGL(tconv16_kernel,g,dim3(256),0,s, in,ldin,sIn,sIn2,zmod,R,C,out,ldout,sOut);
}
static inline void launch_cvt(hipStream_t s, const float* in, short* out, long long n){
  long long n4 = n/4;
  hipLaunchKernelGGL(cvt_kernel,dim3((unsigned)((n4+255)/256)),dim3(256),0,s,in,out,n4);
}

extern "C" void kernel_launch(void* const* d_in, const int* in_sizes, int n_in,
                              void* d_out, int out_size, void* d_ws, size_t ws_size,
                              hipStream_t stream)
{
  const float* x       = (const float*)d_in[0];
  const float* norm1_g = (const float*)d_in[2];
  const float* norm1_b = (const float*)d_in[3];
  const float* qkv_w   = (const float*)d_in[4];
  const float* proj_w  = (const float*)d_in[5];
  const float* proj_b  = (const float*)d_in[6];
  const float* norm2_g = (const float*)d_in[7];
  const float* norm2_b = (const float*)d_in[8];
  const float* fc1_w   = (const float*)d_in[9];
  const float* fc1_b   = (const float*)d_in[10];
  const float* fc2_w   = (const float*)d_in[11];
  const float* fc2_b   = (const float*)d_in[12];
  const float* ada1_w  = (const float*)d_in[13];
  const float* ada1_b  = (const float*)d_in[14];
  const float* ada2_w  = (const float*)d_in[15];
  const float* ada2_b  = (const float*)d_in[16];
  const float* bn3_g   = (const float*)d_in[17];
  const float* bn3_b   = (const float*)d_in[18];
  const float* bn3_m   = (const float*)d_in[19];
  const float* bn3_v   = (const float*)d_in[20];
  const float* bn2_g   = (const float*)d_in[21];
  const float* bn2_b   = (const float*)d_in[22];
  const float* bn2_m   = (const float*)d_in[23];
  const float* bn2_v   = (const float*)d_in[24];
  const float* norm3_g = (const float*)d_in[25];
  const float* norm3_b = (const float*)d_in[26];
  const float* a1_qkv_w  = (const float*)d_in[27];
  const float* a1_proj_w = (const float*)d_in[28];
  const float* a1_proj_b = (const float*)d_in[29];
  const void*  maskp     = d_in[30];
  const int*   cluster   = (const int*)d_in[33];
  const int*   fgi       = (const int*)d_in[34];
  float* out = (float*)d_out;

  // ---- workspace ----
  size_t off = 0;
  char* wsb = (char*)d_ws;
  auto alloc = [&](size_t bytes)->void*{
    void* p = wsb + off;
    off += (bytes + 255) & ~(size_t)255;
    return p;
  };
  // persistent
  short*    bufHh = (short*)alloc(8196ll*384*2);
  float*    ptsb  = (float*)alloc(8192ll*384*4);
  float*    cnt   = (float*)alloc(1024*4);
  float*    fsum  = (float*)alloc(1024ll*384*4);
  unsigned* fmaxe = (unsigned*)alloc(1024ll*384*4);
  float*    cell3 = (float*)alloc(1024ll*384*4);
  unsigned char* maskb = (unsigned char*)alloc(6ll*2048*2048);
  short*    qkvT  = (short*)alloc(1152ll*384*2);
  short*    projT = (short*)alloc(384ll*384*2);
  short*    fc1T  = (short*)alloc(1536ll*384*2);
  short*    fc2T  = (short*)alloc(384ll*1536*2);
  short*    ada1T = (short*)alloc(96ll*384*2);
  short*    ada2T = (short*)alloc(384ll*96*2);
  short*    a1qkvT  = (short*)alloc(6ll*1152*384*2);
  short*    a1projT = (short*)alloc(6ll*384*384*2);
  int*      flag  = (int*)alloc(256);
  // arena (phase-overlapped)
  char* arena = (char*)alloc(157286400);
  // phase-1 layout
  short* bufQh = (short*)(arena + 0);                    // 8196x1152 bf16
  short* Sb16  = (short*)(arena + 18883584);             // 6x2049x2080 bf16
  short* Vt_i  = (short*)(arena + 70026752);             // 24x64x2080 bf16
  float* bufO  = (float*)(arena + 76416512);             // 8196x384 f32
  short* bufOh = (short*)(arena + 89005568);             // 8196x384 bf16
  short* bufAh = (short*)(arena + 95300096);             // 8196x96 bf16
  float* bufX  = (float*)(arena + 96873728);             // 8196x384 f32
  short* bufTh = (short*)(arena + 18883584);             // fc1 out 8196x1536 bf16 (after inner attn; reuses Sb16)
  float* bufAda= (float*)(arena + 0);                    // ada2 out f32 (reuses bufQh)
  // view-phase layout
  short* QK6   = (short*)(arena + 0);                    // 6x8192x768 bf16
  short* Vt6   = (short*)(arena + 75497472);             // 24x384x2048 bf16
  short* O6    = (short*)(arena + 113246208);            // 6x8192x384 bf16
  short* Vtmp  = (short*)(arena + 150994944);            // 8192x384 bf16
  // post-flash layout (QK6/Vt6 dead)
  float* bufT  = (float*)(arena + 0);                    // 8192x384 f32
  float* cell2 = (float*)(arena + 13631488);             // 6x4096x384 f32 (persists to combine)
  float* gc    = (float*)(arena + 51380224);
  float* gsum  = (float*)(arena + 51396608);
  unsigned* gmaxe = (unsigned*)(arena + 57688064);

  // ---- mask detect + byte conversion ----
  hipMemsetAsync(flag, 0, 4, stream);
  {
    long long nInt = 6ll*2048*2048/4;
    detect_mask_kernel<<<dim3((unsigned)((nInt+255)/256)),dim3(256),0,stream>>>((const int*)maskp, nInt, flag);
    long long n4 = 6ll*2048*2048/4;
    mask_byte_kernel<<<dim3((unsigned)((n4+255)/256)),dim3(256),0,stream>>>(maskp, maskb, n4, flag);
  }

  // ---- weight transposes (fp32 [K,N] -> bf16 [N,K]) ----
  launch_tconv(stream, qkv_w, 1152, 0,0,1, 384,1152, qkvT, 384, 0, 1);
  launch_tconv(stream, proj_w, 384, 0,0,1, 384,384,  projT, 384, 0, 1);
  launch_tconv(stream, fc1_w, 1536, 0,0,1, 384,1536, fc1T, 384, 0, 1);
  launch_tconv(stream, fc2_w, 384,  0,0,1, 1536,384, fc2T, 1536, 0, 1);
  launch_tconv(stream, ada1_w, 96,  0,0,1, 384,96,   ada1T, 384, 0, 1);
  launch_tconv(stream, ada2_w, 384, 0,0,1, 96,384,   ada2T, 96, 0, 1);
  launch_tconv(stream, a1_qkv_w, 1152, 384ll*1152,0,1, 384,1152, a1qkvT, 384, 1152ll*384, 6);
  launch_tconv(stream, a1_proj_w, 384, 384ll*384,0,1, 384,384,  a1projT, 384, 384ll*384, 6);

  // ---- phase 1: transformer block ----
  ln_bf16_kernel<<<8196,128,0,stream>>>(x, norm1_g, norm1_b, bufHh);
  launch_gemm16b(stream, bufHh,384,0, qkvT,384,0, nullptr, nullptr,0,0,
                 bufQh,1152,0,1, 8196,1152,384, 0, 1,1);
  launch_tconv16(stream, bufQh + 768, 1152, 2049ll*1152, 64, 6, 2049, 64, Vt_i, 2080, 64ll*2080, 24);
  hipMemsetAsync(bufO, 0, 8196ll*384*4, stream);
  for (int b=0;b<4;b++){
    const short* qb = bufQh + (long long)b*2049*1152;
    launch_gemm16b(stream, qb,1152,64, qb+384,1152,64, nullptr, nullptr,0,0,
                   Sb16,2080,2049ll*2080,1, 2049,2049,64, 0, 6,1);
    softmax_bf16<<<dim3(2049,6),256,0,stream>>>(Sb16,2080,2049ll*2080,2049,0.125f);
    launch_gemm16(stream, Sb16,2080,2049ll*2080, Vt_i + (long long)b*6*64*2080,2080,64ll*2080,
                  nullptr, nullptr,0,0,
                  bufO + (long long)b*2049*384,384,64,0, 2049,64,2080, 0, 6,8);
  }
  launch_cvt(stream, bufO, bufOh, 8196ll*384);
  launch_gemm16s(stream, bufOh,384,0, projT,384,0, proj_b, x,384,0,
                 bufX,384,0,0, 8196,384,384, 0, 1);
  ln_bf16_kernel<<<8196,128,0,stream>>>(bufX, norm2_g, norm2_b, bufHh);
  launch_gemm16b(stream, bufHh,384,0, fc1T,384,0, fc1_b, nullptr,0,0,
                 bufTh,1536,0,1, 8196,1536,384, 1, 1,1);
  launch_gemm16s(stream, bufTh,1536,0, fc2T,1536,0, fc2_b, nullptr,0,0,
                 bufO,384,0,0, 8196,384,1536, 0, 1);
  launch_cvt(stream, bufO, bufOh, 8196ll*384);
  launch_gemm16s(stream, bufOh,384,0, ada1T,384,0, ada1_b, nullptr,0,0,
                 bufAh,96,0,1, 8196,96,384, 2, 1);
  launch_gemm16s(stream, bufAh,96,0, ada2T,96,0, ada2_b, nullptr,0,0,
                 bufAda,384,0,0, 8196,384,96, 0, 1);
  ew_x2_kernel<<<dim3((8196*384+255)/256),256,0,stream>>>(bufX, bufO, bufAda, 8196ll*384);
  copy_cls_kernel<<<6,256,0,stream>>>(bufX, out);
  copy_pts_kernel<<<dim3((8192*384+255)/256),256,0,stream>>>(bufX, ptsb);

  // ---- phase 2: cluster pooling -> cell3 ----
  hipMemsetAsync(cnt, 0, 1024*4, stream);
  hipMemsetAsync(fsum, 0, 1024ll*384*4, stream);
  hipMemsetAsync(fmaxe, 0, 1024ll*384*4, stream);
  scatter_seg_kernel<<<8192,128,0,stream>>>(ptsb, cluster, fsum, fmaxe, cnt);
  cell_kernel<<<1024,128,0,stream>>>(fsum, fmaxe, cnt, bn3_g,bn3_b,bn3_m,bn3_v, cell3);

  // ---- phase 3a: all view qkv projections ----
  for (int i=0;i<6;i++){
    ln_bf16_kernel<<<8192,128,0,stream>>>(ptsb, norm3_g + (long long)i*384, norm3_b + (long long)i*384, bufHh);
    // Q,K -> QK6[i]  (N=768)
    launch_gemm16b(stream, bufHh,384,0, a1qkvT + (long long)i*1152*384,384,0,
                   nullptr, nullptr,0,0, QK6 + (long long)i*8192*768,768,0,1, 8192,768,384, 0, 1,1);
    // V -> Vtmp (N=384), then transpose to Vt6[i]
    launch_gemm16s(stream, bufHh,384,0, a1qkvT + (long long)i*1152*384 + 768ll*384,384,0,
                   nullptr, nullptr,0,0, Vtmp,384,0,1, 8192,384,384, 0, 1);
    launch_tconv16(stream, Vtmp, 384, 2048ll*384, 0, 1, 2048, 384,
                   Vt6 + (long long)i*4*384*2048, 2048, 384ll*2048, 4);
  }

  // ---- phase 3b: fused flash attention for all 24 (v,b) ----
  flash_view<<<dim3(32,4,6),256,0,stream>>>(QK6, Vt6, maskb, O6);

  // ---- phase 3c: per-view proj + grid pooling ----
  for (int i=0;i<6;i++){
    launch_gemm16s(stream, O6 + (long long)i*8192*384,384,0, a1projT + (long long)i*384*384,384,0,
                   a1_proj_b + (long long)i*384, ptsb,384,0,
                   bufT,384,0,0, 8192,384,384, 0, 1);
    hipMemsetAsync(gc, 0, 4096*4, stream);
    hipMemsetAsync(gsum, 0, 4096ll*384*4, stream);
    hipMemsetAsync(gmaxe, 0, 4096ll*384*4, stream);
    scatter_seg_kernel<<<8192,128,0,stream>>>(bufT, fgi + (long long)i*8192, gsum, gmaxe, gc);
    cell_kernel<<<4096,128,0,stream>>>(gsum, gmaxe, gc,
        bn2_g + (long long)i*384, bn2_b + (long long)i*384,
        bn2_m + (long long)i*384, bn2_v + (long long)i*384,
        cell2 + (long long)i*4096*384);
  }

  // ---- phase 4: combine ----
  combine_kernel<<<8192,128,0,stream>>>(ptsb, cell3, cluster, cell2, fgi, out);
}

// Round 6
// 1980.858 us; speedup vs baseline: 1.3577x; 1.0904x over previous
//
#include <hip/hip_runtime.h>
#include <math.h>

typedef short bf16x8 __attribute__((ext_vector_type(8)));
typedef float f32x4 __attribute__((ext_vector_type(4)));

#define GLL16(g, l) \
  __builtin_amdgcn_global_load_lds((__attribute__((address_space(1))) const unsigned int*)(g), \
                                   (__attribute__((address_space(3))) unsigned int*)(l), 16, 0, 0)

// ---------- helpers ----------
__device__ __forceinline__ float wsum(float v){
  #pragma unroll
  for (int o=32;o;o>>=1) v += __shfl_xor(v,o);
  return v;
}
__device__ __forceinline__ float geluf(float x){
  return 0.5f*x*(1.0f+erff(x*0.7071067811865475f));
}
__device__ __forceinline__ short fbf(float f){
  unsigned u = __float_as_uint(f);
  unsigned r = (u + 0x7fffu + ((u>>16)&1u)) >> 16;
  return (short)r;
}
__device__ __forceinline__ float bff(short s){
  return __uint_as_float(((unsigned)(unsigned short)s)<<16);
}
__device__ __forceinline__ unsigned fkey(float f){
  unsigned b=__float_as_uint(f);
  return (b&0x80000000u)? ~b : (b|0x80000000u);
}
__device__ __forceinline__ float fdec(unsigned k){
  unsigned b=(k&0x80000000u)? (k&0x7fffffffu) : ~k;
  return __uint_as_float(b);
}

// ---------- mask dtype detection + byte conversion ----------
__global__ void detect_mask_kernel(const int* __restrict__ m, long long n, int* flag){
  long long i = (long long)blockIdx.x*256 + threadIdx.x;
  bool bad = (i<n) && (m[i]!=0 && m[i]!=1);
  if (__any(bad)) { if ((threadIdx.x&63)==0) atomicOr(flag,1); }
}
__global__ void mask_byte_kernel(const void* __restrict__ m, unsigned char* __restrict__ mb,
                                 long long n4, const int* __restrict__ flag){
  long long i = (long long)blockIdx.x*256 + threadIdx.x;
  if (i>=n4) return;
  int mode = *flag;
  uchar4 o;
  if (mode){ o = ((const uchar4*)m)[i]; o.x=o.x!=0; o.y=o.y!=0; o.z=o.z!=0; o.w=o.w!=0; }
  else { int4 v = ((const int4*)m)[i];
         o.x=(unsigned char)(v.x!=0); o.y=(unsigned char)(v.y!=0);
         o.z=(unsigned char)(v.z!=0); o.w=(unsigned char)(v.w!=0); }
  ((uchar4*)mb)[i]=o;
}

__device__ __forceinline__ float epi(float v, const float* bias, int col, int act){
  if (bias) v += bias[col];
  if (act==1) v = geluf(v);
  else if (act==2) v = v*(1.f/(1.f+__expf(-1.702f*v)));
  return v;
}

// ---------- bf16 MFMA GEMM, 128x128 tile ----------
#define XBM 128
#define XBN 128
#define XBK 32
__global__ __launch_bounds__(256)
void gemm_bf16_big(const short* __restrict__ A, int lda, long long sA,
                   const short* __restrict__ B, int ldb, long long sB,
                   const float* __restrict__ bias, long long sBias,
                   const float* __restrict__ res, int ldr, long long sR,
                   void* __restrict__ out, int ldo, long long sO, int outbf16,
                   int M, int N, int K, int act, int KS)
{
  __shared__ short As[XBM*XBK];
  __shared__ short Bs[XBN*XBK];
  int zz = blockIdx.z;
  int z = zz / KS, ks = zz - z*KS;
  A += (long long)z*sA; B += (long long)z*sB;
  if (res) res += (long long)z*sR;
  if (bias) bias += (long long)z*sBias;
  float* outF = (float*)out + (long long)z*sO;
  short* outH = (short*)out + (long long)z*sO;

  int tid = threadIdx.x;
  int rowBase = blockIdx.y*XBM;
  int colBase = blockIdx.x*XBN;

  int Kc = ((K + KS*XBK - 1)/(KS*XBK))*XBK;
  int kbeg = ks*Kc;
  int kend = min(K, kbeg+Kc);
  if (kbeg >= kend) return;

  int w = tid>>6;
  int lane = tid&63;
  int lm = lane&15, quad = lane>>4;
  int waveM = w>>1, waveN = w&1;

  int arow0 = min(rowBase + w*32 + lm,      M-1);
  int arow1 = min(rowBase + w*32 + 16 + lm, M-1);
  int brow0 = min(colBase + w*32 + lm,      N-1);
  int brow1 = min(colBase + w*32 + 16 + lm, N-1);
  const short* Ag0 = A + (long long)arow0*lda + quad*8;
  const short* Ag1 = A + (long long)arow1*lda + quad*8;
  const short* Bg0 = B + (long long)brow0*ldb + quad*8;
  const short* Bg1 = B + (long long)brow1*ldb + quad*8;
  short* Al0 = &As[(w*2+0)*512];
  short* Al1 = &As[(w*2+1)*512];
  short* Bl0 = &Bs[(w*2+0)*512];
  short* Bl1 = &Bs[(w*2+1)*512];

  f32x4 acc[4][4] = {};

  for (int k0=kbeg; k0<kend; k0+=XBK){
    GLL16(Ag0 + k0, Al0);
    GLL16(Ag1 + k0, Al1);
    GLL16(Bg0 + k0, Bl0);
    GLL16(Bg1 + k0, Bl1);
    __syncthreads();
    bf16x8 af[4], bfr[4];
    #pragma unroll
    for (int tm=0;tm<4;tm++) af[tm]  = *(bf16x8*)&As[(waveM*4+tm)*512 + quad*128 + lm*8];
    #pragma unroll
    for (int tn=0;tn<4;tn++) bfr[tn] = *(bf16x8*)&Bs[(waveN*4+tn)*512 + quad*128 + lm*8];
    #pragma unroll
    for (int tm=0;tm<4;tm++)
      #pragma unroll
      for (int tn=0;tn<4;tn++)
        acc[tm][tn] = __builtin_amdgcn_mfma_f32_16x16x32_bf16(af[tm], bfr[tn], acc[tm][tn], 0,0,0);
    __syncthreads();
  }

  #pragma unroll
  for (int tm=0;tm<4;tm++){
    #pragma unroll
    for (int tn=0;tn<4;tn++){
      int col = colBase + waveN*64 + tn*16 + lm;
      if (col>=N) continue;
      #pragma unroll
      for (int reg=0;reg<4;reg++){
        int row = rowBase + waveM*64 + tm*16 + quad*4 + reg;
        if (row>=M) continue;
        float v = acc[tm][tn][reg];
        if (KS>1){ atomicAdd(&outF[(long long)row*ldo+col], v); continue; }
        v = epi(v, bias, col, act);
        if (res) v += res[(long long)row*ldr+col];
        if (outbf16) outH[(long long)row*ldo+col] = fbf(v);
        else         outF[(long long)row*ldo+col] = v;
      }
    }
  }
}

// ---------- bf16 MFMA GEMM, 128x64 tile ----------
#define TBM 128
#define TBN 64
#define TBK 32
__global__ __launch_bounds__(256)
void gemm_bf16(const short* __restrict__ A, int lda, long long sA,
               const short* __restrict__ B, int ldb, long long sB,
               const float* __restrict__ bias, long long sBias,
               const float* __restrict__ res, int ldr, long long sR,
               void* __restrict__ out, int ldo, long long sO, int outbf16,
               int M, int N, int K, int act, int KS)
{
  __shared__ short As[TBM*TBK];
  __shared__ short Bs[TBN*TBK];
  int zz = blockIdx.z;
  int z = zz / KS, ks = zz - z*KS;
  A += (long long)z*sA; B += (long long)z*sB;
  if (res) res += (long long)z*sR;
  if (bias) bias += (long long)z*sBias;
  float* outF = (float*)out + (long long)z*sO;
  short* outH = (short*)out + (long long)z*sO;

  int tid = threadIdx.x;
  int rowBase = blockIdx.y*TBM;
  int colBase = blockIdx.x*TBN;

  int Kc = ((K + KS*TBK - 1)/(KS*TBK))*TBK;
  int kbeg = ks*Kc;
  int kend = min(K, kbeg+Kc);
  if (kbeg >= kend) return;

  int w = tid>>6;
  int lane = tid&63;
  int lm = lane&15, quad = lane>>4;
  int waveM = w>>1, waveN = w&1;

  int arow0 = min(rowBase + w*32 + lm,      M-1);
  int arow1 = min(rowBase + w*32 + 16 + lm, M-1);
  int brow  = min(colBase + w*16 + lm,      N-1);
  const short* Ag0 = A + (long long)arow0*lda + quad*8;
  const short* Ag1 = A + (long long)arow1*lda + quad*8;
  const short* Bg  = B + (long long)brow*ldb  + quad*8;
  short* Al0 = &As[(w*2+0)*512];
  short* Al1 = &As[(w*2+1)*512];
  short* Bl  = &Bs[w*512];

  f32x4 acc[4][2] = {};

  for (int k0=kbeg; k0<kend; k0+=TBK){
    GLL16(Ag0 + k0, Al0);
    GLL16(Ag1 + k0, Al1);
    GLL16(Bg  + k0, Bl);
    __syncthreads();
    bf16x8 af[4], bfr[2];
    #pragma unroll
    for (int tm=0;tm<4;tm++) af[tm]  = *(bf16x8*)&As[(waveM*4+tm)*512 + quad*128 + lm*8];
    #pragma unroll
    for (int tn=0;tn<2;tn++) bfr[tn] = *(bf16x8*)&Bs[(waveN*2+tn)*512 + quad*128 + lm*8];
    #pragma unroll
    for (int tm=0;tm<4;tm++)
      #pragma unroll
      for (int tn=0;tn<2;tn++)
        acc[tm][tn] = __builtin_amdgcn_mfma_f32_16x16x32_bf16(af[tm], bfr[tn], acc[tm][tn], 0,0,0);
    __syncthreads();
  }

  #pragma unroll
  for (int tm=0;tm<4;tm++){
    #pragma unroll
    for (int tn=0;tn<2;tn++){
      int col = colBase + waveN*32 + tn*16 + lm;
      if (col>=N) continue;
      #pragma unroll
      for (int reg=0;reg<4;reg++){
        int row = rowBase + waveM*64 + tm*16 + quad*4 + reg;
        if (row>=M) continue;
        float v = acc[tm][tn][reg];
        if (KS>1){ atomicAdd(&outF[(long long)row*ldo+col], v); continue; }
        v = epi(v, bias, col, act);
        if (res) v += res[(long long)row*ldr+col];
        if (outbf16) outH[(long long)row*ldo+col] = fbf(v);
        else         outF[(long long)row*ldo+col] = v;
      }
    }
  }
}

// ---------- bf16 MFMA GEMM, 64x64 tile ----------
// outbf16==2: transposed V store: out + (b*384+col)*2048 + (row&2047), b=row>>11
__global__ __launch_bounds__(256)
void gemm_bf16_s(const short* __restrict__ A, int lda, long long sA,
                 const short* __restrict__ B, int ldb, long long sB,
                 const float* __restrict__ bias, long long sBias,
                 const float* __restrict__ res, int ldr, long long sR,
                 void* __restrict__ out, int ldo, long long sO, int outbf16,
                 int M, int N, int K, int act)
{
  __shared__ short As[64*32];
  __shared__ short Bs[64*32];
  int z = blockIdx.z;
  A += (long long)z*sA; B += (long long)z*sB;
  if (res) res += (long long)z*sR;
  if (bias) bias += (long long)z*sBias;
  float* outF = (float*)out + (long long)z*sO;
  short* outH = (short*)out + (long long)z*sO;

  int tid = threadIdx.x;
  int rowBase = blockIdx.y*64;
  int colBase = blockIdx.x*64;

  int w = tid>>6;
  int lane = tid&63;
  int lm = lane&15, quad = lane>>4;
  int wm = w>>1, wn = w&1;

  int arow = min(rowBase + w*16 + lm, M-1);
  int brow = min(colBase + w*16 + lm, N-1);
  const short* Ag = A + (long long)arow*lda + quad*8;
  const short* Bg = B + (long long)brow*ldb + quad*8;
  short* Al = &As[w*512];
  short* Bl = &Bs[w*512];

  f32x4 acc[2][2] = {};

  for (int k0=0; k0<K; k0+=32){
    GLL16(Ag + k0, Al);
    GLL16(Bg + k0, Bl);
    __syncthreads();
    bf16x8 af[2], bfr[2];
    #pragma unroll
    for (int tm=0;tm<2;tm++) af[tm]  = *(bf16x8*)&As[(wm*2+tm)*512 + quad*128 + lm*8];
    #pragma unroll
    for (int tn=0;tn<2;tn++) bfr[tn] = *(bf16x8*)&Bs[(wn*2+tn)*512 + quad*128 + lm*8];
    #pragma unroll
    for (int tm=0;tm<2;tm++)
      #pragma unroll
      for (int tn=0;tn<2;tn++)
        acc[tm][tn] = __builtin_amdgcn_mfma_f32_16x16x32_bf16(af[tm], bfr[tn], acc[tm][tn], 0,0,0);
    __syncthreads();
  }

  #pragma unroll
  for (int tm=0;tm<2;tm++){
    #pragma unroll
    for (int tn=0;tn<2;tn++){
      int col = colBase + wn*32 + tn*16 + lm;
      if (col>=N) continue;
      #pragma unroll
      for (int reg=0;reg<4;reg++){
        int row = rowBase + wm*32 + tm*16 + quad*4 + reg;
        if (row>=M) continue;
        float v = epi(acc[tm][tn][reg], bias, col, act);
        if (res) v += res[(long long)row*ldr+col];
        if (outbf16==2){
          int bb = row>>11;
          outH[((long long)bb*384 + col)*2048 + (row&2047)] = fbf(v);
        }
        else if (outbf16) outH[(long long)row*ldo+col] = fbf(v);
        else              outF[(long long)row*ldo+col] = v;
      }
    }
  }
}

// ---------- flash-fused view attention v2: 64-row K/V tiles, 4 barriers/kt ----------
// QK6: [6][8192][768] bf16 (Q 0..384, K 384..768); Vt6: [24][384][2048] bf16
// maskb: [6][2048][2048] u8; O6: [6][8192][384] bf16
__global__ __launch_bounds__(256,2)
void flash_view(const short* __restrict__ QK6, const short* __restrict__ Vt6,
                const unsigned char* __restrict__ maskb, short* __restrict__ O6)
{
  __shared__ char lds[58368];  // KV 48KB [0,49152) + P 4x2304 [49152,58368)
  const float scale = 0.05103103630798288f;
  int qt=blockIdx.x, b=blockIdx.y, v=blockIdx.z;
  int tid=threadIdx.x, w=tid>>6, lane=tid&63, lm=lane&15, quad=lane>>4;

  const short* Qp = QK6 + ((long long)v*8192 + b*2048 + qt*64)*768;
  const short* Kp = QK6 + ((long long)v*8192 + b*2048)*768 + 384;
  const short* Vp = Vt6 + (long long)(v*4+b)*384*2048;
  const unsigned char* Mp = maskb + (long long)v*2048*2048 + (long long)qt*64*2048;
  short* Op = O6 + ((long long)v*8192 + b*2048 + qt*64)*384;

  // stage Q (64x384) into KV region, pull this wave's 12 A-frags
  #pragma unroll
  for (int c=0;c<12;c++)
    GLL16(Qp + (w*16+lm)*768 + c*32 + quad*8, (short*)(lds + (w*12+c)*1024));
  __syncthreads();
  bf16x8 af[12];
  #pragma unroll
  for (int c=0;c<12;c++)
    af[c] = *(bf16x8*)(lds + (w*12+c)*1024 + quad*256 + lm*16);
  __syncthreads();

  float m_i[4], l_i[4];
  #pragma unroll
  for (int r=0;r<4;r++){ m_i[r]=-3.0e38f; l_i[r]=0.f; }
  f32x4 Oacc[24] = {};
  short* Pw = (short*)(lds + 49152 + w*2304);   // [16][72] bf16, wave-private

  for (int kt=0; kt<32; kt++){
    // ---- stage K tile (64x384): wave w loads its 16 rows x 12 chunks
    #pragma unroll
    for (int c=0;c<12;c++)
      GLL16(Kp + (long long)(kt*64 + w*16 + lm)*768 + c*32 + quad*8, (short*)(lds + (w*12+c)*1024));
    __syncthreads();
    // ---- S: Q(16x384) @ K(64x384)^T, 48 MFMA back-to-back
    f32x4 S[4];
    #pragma unroll
    for (int i=0;i<4;i++) S[i] = (f32x4){0.f,0.f,0.f,0.f};
    #pragma unroll
    for (int kc=0;kc<12;kc++){
      #pragma unroll
      for (int ct=0;ct<4;ct++){
        bf16x8 bf = *(bf16x8*)(lds + (ct*12+kc)*1024 + quad*256 + lm*16);
        S[ct] = __builtin_amdgcn_mfma_f32_16x16x32_bf16(af[kc], bf, S[ct], 0,0,0);
      }
    }
    // ---- mask + scale
    #pragma unroll
    for (int ct=0;ct<4;ct++){
      #pragma unroll
      for (int r=0;r<4;r++){
        unsigned char mb = Mp[(long long)(w*16+quad*4+r)*2048 + kt*64 + ct*16 + lm];
        S[ct][r] = mb ? S[ct][r]*scale : -3.0e38f;
      }
    }
    // ---- online softmax (rows in 16-lane groups)
    float alpha[4], mnew[4];
    #pragma unroll
    for (int r=0;r<4;r++){
      float rm = S[0][r];
      #pragma unroll
      for (int ct=1;ct<4;ct++) rm = fmaxf(rm, S[ct][r]);
      #pragma unroll
      for (int o=1;o<16;o<<=1) rm = fmaxf(rm, __shfl_xor(rm, o));
      mnew[r] = fmaxf(m_i[r], rm);
      alpha[r] = __expf(m_i[r]-mnew[r]);
      m_i[r] = mnew[r];
    }
    float rs[4] = {0.f,0.f,0.f,0.f};
    #pragma unroll
    for (int ct=0;ct<4;ct++){
      #pragma unroll
      for (int r=0;r<4;r++){
        float sv = S[ct][r];
        float p = (sv > -1.0e37f) ? __expf(sv - mnew[r]) : 0.f;
        rs[r] += p;
        Pw[(quad*4+r)*72 + ct*16 + lm] = fbf(p);
      }
    }
    #pragma unroll
    for (int r=0;r<4;r++){
      #pragma unroll
      for (int o=1;o<16;o<<=1) rs[r] += __shfl_xor(rs[r], o);
      l_i[r] = l_i[r]*alpha[r] + rs[r];
    }
    #pragma unroll
    for (int tn=0;tn<24;tn++){
      #pragma unroll
      for (int r=0;r<4;r++) Oacc[tn][r] *= alpha[r];
    }
    __syncthreads();   // all waves done reading K before V overwrites
    // ---- stage V tile (V^T 384 x 64): wave w loads tn=w*6..w*6+6, kk 0..2
    #pragma unroll
    for (int j=0;j<6;j++){
      int tn = w*6+j;
      #pragma unroll
      for (int kk=0;kk<2;kk++)
        GLL16(Vp + (long long)(tn*16+lm)*2048 + kt*64 + kk*32 + quad*8, (short*)(lds + (tn*2+kk)*1024));
    }
    __syncthreads();
    // ---- PV: P(16x64) @ V(64x384), 48 MFMA back-to-back
    #pragma unroll
    for (int kk=0;kk<2;kk++){
      bf16x8 ap = *(bf16x8*)((char*)Pw + (lm*72 + kk*32 + quad*8)*2);
      #pragma unroll
      for (int tn=0;tn<24;tn++){
        bf16x8 bf = *(bf16x8*)(lds + (tn*2+kk)*1024 + quad*256 + lm*16);
        Oacc[tn] = __builtin_amdgcn_mfma_f32_16x16x32_bf16(ap, bf, Oacc[tn], 0,0,0);
      }
    }
    __syncthreads();   // before next kt K loads overwrite V
  }

  #pragma unroll
  for (int tn=0;tn<24;tn++){
    #pragma unroll
    for (int r=0;r<4;r++){
      float o = Oacc[tn][r] / l_i[r];
      Op[(long long)(w*16+quad*4+r)*384 + tn*16 + lm] = fbf(o);
    }
  }
}

// ---------- softmax in-place on bf16 scores (inner attention) ----------
__global__ __launch_bounds__(256)
void softmax_bf16(short* __restrict__ S, int ld, long long sS, int cols, float alpha)
{
  __shared__ float buf[2080];
  __shared__ float red[4];
  int row = blockIdx.x, z = blockIdx.y;
  short* p = S + (long long)z*sS + (long long)row*ld;
  int tid = threadIdx.x;
  float mx = -3.4e38f;
  for (int c=tid;c<cols;c+=256){
    float v = bff(p[c])*alpha;
    buf[c] = v;
    mx = fmaxf(mx, v);
  }
  #pragma unroll
  for (int o=32;o;o>>=1) mx = fmaxf(mx,__shfl_xor(mx,o));
  int wid = tid>>6, lane = tid&63;
  if (lane==0) red[wid]=mx;
  __syncthreads();
  mx = fmaxf(fmaxf(red[0],red[1]),fmaxf(red[2],red[3]));
  __syncthreads();
  float sum=0.f;
  for (int c=tid;c<cols;c+=256){
    float e = __expf(buf[c]-mx);
    buf[c]=e; sum += e;
  }
  sum = wsum(sum);
  if (lane==0) red[wid]=sum;
  __syncthreads();
  sum = red[0]+red[1]+red[2]+red[3];
  float inv = 1.f/sum;
  for (int c=tid;c<cols;c+=256) p[c] = fbf(buf[c]*inv);
  for (int c=cols+tid;c<ld;c+=256) p[c] = 0;
}

// ---------- LayerNorm (fp32 in -> bf16 out), C=384 ----------
__global__ __launch_bounds__(128)
void ln_bf16_kernel(const float* __restrict__ in, const float* __restrict__ g,
                    const float* __restrict__ bt, short* __restrict__ out)
{
  long long row = blockIdx.x;
  const float* p = in + row*384;
  int tid = threadIdx.x;
  float v0=p[tid], v1=p[tid+128], v2=p[tid+256];
  float s = v0+v1+v2;
  float ss = v0*v0+v1*v1+v2*v2;
  __shared__ float r1[2], r2[2];
  s = wsum(s); ss = wsum(ss);
  int wid=tid>>6, lane=tid&63;
  if (lane==0){ r1[wid]=s; r2[wid]=ss; }
  __syncthreads();
  float mean=(r1[0]+r1[1])*(1.f/384.f);
  float var =(r2[0]+r2[1])*(1.f/384.f)-mean*mean;
  float rstd=rsqrtf(var+1e-5f);
  short* o = out + row*384;
  o[tid]     = fbf((v0-mean)*rstd*g[tid]+bt[tid]);
  o[tid+128] = fbf((v1-mean)*rstd*g[tid+128]+bt[tid+128]);
  o[tid+256] = fbf((v2-mean)*rstd*g[tid+256]+bt[tid+256]);
}

// ---------- LN once, write 6 per-view normed copies ----------
__global__ __launch_bounds__(128)
void ln6_kernel(const float* __restrict__ in, const float* __restrict__ g6,
                const float* __restrict__ b6, short* __restrict__ out6)
{
  long long row = blockIdx.x;
  const float* p = in + row*384;
  int tid = threadIdx.x;
  float v0=p[tid], v1=p[tid+128], v2=p[tid+256];
  float s = v0+v1+v2;
  float ss = v0*v0+v1*v1+v2*v2;
  __shared__ float r1[2], r2[2];
  s = wsum(s); ss = wsum(ss);
  int wid=tid>>6, lane=tid&63;
  if (lane==0){ r1[wid]=s; r2[wid]=ss; }
  __syncthreads();
  float mean=(r1[0]+r1[1])*(1.f/384.f);
  float var =(r2[0]+r2[1])*(1.f/384.f)-mean*mean;
  float rstd=rsqrtf(var+1e-5f);
  float n0=(v0-mean)*rstd, n1=(v1-mean)*rstd, n2=(v2-mean)*rstd;
  #pragma unroll
  for (int i=0;i<6;i++){
    const float* g = g6 + i*384;
    const float* bt = b6 + i*384;
    short* o = out6 + (long long)i*8192*384 + row*384;
    o[tid]     = fbf(n0*g[tid]+bt[tid]);
    o[tid+128] = fbf(n1*g[tid+128]+bt[tid+128]);
    o[tid+256] = fbf(n2*g[tid+256]+bt[tid+256]);
  }
}

// ---------- fp32 -> bf16 convert ----------
__global__ void cvt_kernel(const float* __restrict__ in, short* __restrict__ out, long long n4){
  long long i = (long long)blockIdx.x*256 + threadIdx.x;
  if (i<n4){
    float4 f = ((const float4*)in)[i];
    short4 s;
    s.x=fbf(f.x); s.y=fbf(f.y); s.z=fbf(f.z); s.w=fbf(f.w);
    ((short4*)out)[i]=s;
  }
}

// ---------- tiled transpose+convert: fp32 [R,C] -> bf16 [C, ldout] ----------
__global__ __launch_bounds__(256)
void tconv_kernel(const float* __restrict__ in, int ldin, long long sIn, long long sIn2, int zmod,
                  int R, int C, short* __restrict__ out, int ldout, long long sOut)
{
  __shared__ float tile[32][33];
  int z = blockIdx.z;
  const float* ip = in + (long long)(z/zmod)*sIn + (long long)(z%zmod)*sIn2;
  short* op = out + (long long)z*sOut;
  int r0 = blockIdx.x*32;
  int c0 = blockIdx.y*32;
  int tx = threadIdx.x&31, ty = threadIdx.x>>5;
  #pragma unroll
  for (int i=0;i<4;i++){
    int r = r0 + ty + i*8, c = c0 + tx;
    tile[ty+i*8][tx] = (r<R && c<C) ? ip[(long long)r*ldin + c] : 0.f;
  }
  __syncthreads();
  #pragma unroll
  for (int i=0;i<4;i++){
    int oc = c0 + ty + i*8;
    int orr = r0 + tx;
    if (oc<C && orr<ldout) op[(long long)oc*ldout + orr] = fbf(tile[tx][ty+i*8]);
  }
}

// ---------- tiled transpose: bf16 [R,C] -> bf16 [C, ldout] ----------
__global__ __launch_bounds__(256)
void tconv16_kernel(const short* __restrict__ in, int ldin, long long sIn, long long sIn2, int zmod,
                    int R, int C, short* __restrict__ out, int ldout, long long sOut)
{
  __shared__ short tile[32][34];
  int z = blockIdx.z;
  const short* ip = in + (long long)(z/zmod)*sIn + (long long)(z%zmod)*sIn2;
  short* op = out + (long long)z*sOut;
  int r0 = blockIdx.x*32;
  int c0 = blockIdx.y*32;
  int tx = threadIdx.x&31, ty = threadIdx.x>>5;
  #pragma unroll
  for (int i=0;i<4;i++){
    int r = r0 + ty + i*8, c = c0 + tx;
    tile[ty+i*8][tx] = (r<R && c<C) ? ip[(long long)r*ldin + c] : (short)0;
  }
  __syncthreads();
  #pragma unroll
  for (int i=0;i<4;i++){
    int oc = c0 + ty + i*8;
    int orr = r0 + tx;
    if (oc<C && orr<ldout) op[(long long)oc*ldout + orr] = tile[tx][ty+i*8];
  }
}

// ---------- elementwise ----------
__global__ void ew_x2_kernel(float* x1, const float* ffn, const float* ada, long long n){
  long long i=(long long)blockIdx.x*256+threadIdx.x;
  if (i<n) x1[i] = x1[i] + ffn[i] + 0.5f*ada[i];
}
__global__ void copy_pts_kernel(const float* __restrict__ x2, float* __restrict__ pts){
  long long i=(long long)blockIdx.x*256+threadIdx.x;
  if (i < 8192ll*384){
    long long b = i/(2048ll*384);
    long long rem = i%(2048ll*384);
    pts[i] = x2[(b*2049+1)*384 + rem];
  }
}
__global__ void copy_cls_kernel(const float* __restrict__ x2, float* __restrict__ out){
  int i = blockIdx.x*256+threadIdx.x;
  if (i < 4*384){
    int b=i/384, c=i%384;
    out[(long long)b*2049*384 + c] = x2[(long long)b*2049*384 + c];
  }
}

// ---------- segment scatter (z-batched) ----------
__global__ __launch_bounds__(128)
void scatter_seg_kernel(const float* __restrict__ feat, const int* __restrict__ seg,
                        float* __restrict__ fsum, unsigned* __restrict__ fmax,
                        float* __restrict__ cnt,
                        long long zFeat, long long zSeg, long long zSum, long long zCnt)
{
  int n = blockIdx.x, z = blockIdx.y;
  feat += (long long)z*zFeat; seg += (long long)z*zSeg;
  fsum += (long long)z*zSum; fmax += (long long)z*zSum; cnt += (long long)z*zCnt;
  int s = seg[n];
  const float* p = feat + (long long)n*384;
  int tid = threadIdx.x;
  #pragma unroll
  for (int k=0;k<3;k++){
    int c = tid + k*128;
    float v = p[c];
    atomicAdd(&fsum[(long long)s*384+c], v);
    atomicMax(&fmax[(long long)s*384+c], fkey(v));
  }
  if (tid==0) atomicAdd(&cnt[s], 1.0f);
}

// ---------- cell = bn_gelu(max + mean), z-batched ----------
__global__ __launch_bounds__(128)
void cell_kernel(const float* __restrict__ fsum, const unsigned* __restrict__ fmax,
                 const float* __restrict__ cnt,
                 const float* __restrict__ g, const float* __restrict__ bb,
                 const float* __restrict__ m, const float* __restrict__ v,
                 float* __restrict__ out, long long zSum, long long zCnt, long long zP)
{
  int s = blockIdx.x, z = blockIdx.y;
  fsum += (long long)z*zSum; fmax += (long long)z*zSum; cnt += (long long)z*zCnt;
  g += (long long)z*zP; bb += (long long)z*zP; m += (long long)z*zP; v += (long long)z*zP;
  out += (long long)z*zSum;
  float cn = cnt[s];
  float denom = fmaxf(cn, 1.f);
  int tid = threadIdx.x;
  #pragma unroll
  for (int k=0;k<3;k++){
    int c = tid + k*128;
    float mx = (cn>0.f) ? fdec(fmax[(long long)s*384+c]) : 0.f;
    float t = mx + fsum[(long long)s*384+c]/denom;
    t = (t - m[c])*rsqrtf(v[c]+1e-5f)*g[c] + bb[c];
    out[(long long)s*384+c] = geluf(t);
  }
}

// ---------- final cosine-sim weighted combine ----------
__global__ __launch_bounds__(128)
void combine_kernel(const float* __restrict__ pts, const float* __restrict__ cell3,
                    const int* __restrict__ cluster, const float* __restrict__ cell2,
                    const int* __restrict__ gidx, float* __restrict__ out)
{
  int n = blockIdx.x;
  int tid = threadIdx.x;
  __shared__ float sdot[6], ssq[6], sw[6];
  __shared__ int soff[6];
  __shared__ float red[2][2];
  __shared__ float sn3;
  const float* x3 = cell3 + (long long)cluster[n]*384;
  int wid=tid>>6, lane=tid&63;
  float sq=0.f;
  for (int c=tid;c<384;c+=128){ float v=x3[c]; sq+=v*v; }
  sq = wsum(sq);
  if (lane==0) red[0][wid]=sq;
  __syncthreads();
  if (tid==0) sn3 = sqrtf(red[0][0]+red[0][1]);
  __syncthreads();
  for (int i=0;i<6;i++){
    int gi = gidx[(long long)i*8192 + n];
    if (tid==0) soff[i]=gi;
    const float* r = cell2 + ((long long)i*4096 + gi)*384;
    float d=0.f, s2=0.f;
    for (int c=tid;c<384;c+=128){ float a=r[c]; d+=a*x3[c]; s2+=a*a; }
    d = wsum(d); s2 = wsum(s2);
    if (lane==0){ red[0][wid]=d; red[1][wid]=s2; }
    __syncthreads();
    if (tid==0){ sdot[i]=red[0][0]+red[0][1]; ssq[i]=red[1][0]+red[1][1]; }
    __syncthreads();
  }
  if (tid==0){
    float ssumv=0.f; float sims[6];
    for (int i=0;i<6;i++){
      float nrm = sqrtf(ssq[i])*sn3;
      float s = (sdot[i]/fmaxf(nrm,1e-8f) + 1.f)*0.5f;
      sims[i]=s; ssumv+=s;
    }
    for (int i=0;i<6;i++) sw[i]=sims[i]/ssumv;
  }
  __syncthreads();
  int b = n>>11, gp = n&2047;
  float* o = out + ((long long)(b*2049 + 1 + gp))*384;
  for (int c=tid;c<384;c+=128){
    float acc=0.f;
    #pragma unroll
    for (int i=0;i<6;i++){
      const float* r = cell2 + ((long long)i*4096 + soff[i])*384;
      acc += sw[i]*r[c];
    }
    o[c] = pts[(long long)n*384+c] + 0.5f*acc;
  }
}

// ---------- host helpers ----------
static inline void launch_gemm16(hipStream_t s, const short* A,int lda,long long sA,
  const short* B,int ldb,long long sB, const float* bias, long long sBias,
  const float* res,int ldr,long long sR, void* out,int ldo,long long sO,int outbf16,
  int M,int N,int K,int act,int nz,int KS)
{
  dim3 g((N+TBN-1)/TBN,(M+TBM-1)/TBM,(unsigned)(nz*KS));
  hipLaunchKernelGGL(gemm_bf16,g,dim3(256),0,s,
    A,lda,sA,B,ldb,sB,bias,sBias,res,ldr,sR,out,ldo,sO,outbf16,M,N,K,act,KS);
}
static inline void launch_gemm16b(hipStream_t s, const short* A,int lda,long long sA,
  const short* B,int ldb,long long sB, const float* bias, long long sBias,
  const float* res,int ldr,long long sR, void* out,int ldo,long long sO,int outbf16,
  int M,int N,int K,int act,int nz,int KS)
{
  dim3 g((N+XBN-1)/XBN,(M+XBM-1)/XBM,(unsigned)(nz*KS));
  hipLaunchKernelGGL(gemm_bf16_big,g,dim3(256),0,s,
    A,lda,sA,B,ldb,sB,bias,sBias,res,ldr,sR,out,ldo,sO,outbf16,M,N,K,act,KS);
}
static inline void launch_gemm16s(hipStream_t s, const short* A,int lda,long long sA,
  const short* B,int ldb,long long sB, const float* bias, long long sBias,
  const float* res,int ldr,long long sR, void* out,int ldo,long long sO,int outbf16,
  int M,int N,int K,int act,int nz)
{
  dim3 g((N+63)/64,(M+63)/64,(unsigned)nz);
  hipLaunchKernelGGL(gemm_bf16_s,g,dim3(256),0,s,
    A,lda,sA,B,ldb,sB,bias,sBias,res,ldr,sR,out,ldo,sO,outbf16,M,N,K,act);
}
static inline void launch_tconv(hipStream_t s, const float* in,int ldin,long long sIn,long long sIn2,int zmod,
  int R,int C, short* out,int ldout,long long sOut,int nz)
{
  dim3 g((ldout+31)/32,(C+31)/32,(unsigned)nz);
  hipLaunchKernelGGL(tconv_kernel,g,dim3(256),0,s, in,ldin,sIn,sIn2,zmod,R,C,out,ldout,sOut);
}
static inline void launch_tconv16(hipStream_t s, const short* in,int ldin,long long sIn,long long sIn2,int zmod,
  int R,int C, short* out,int ldout,long long sOut,int nz)
{
  dim3 g((ldout+31)/32,(C+31)/32,(unsigned)nz);
  hipLaunchKernelGGL(tconv16_kernel,g,dim3(256),0,s, in,ldin,sIn,sIn2,zmod,R,C,out,ldout,sOut);
}
static inline void launch_cvt(hipStream_t s, const float* in, short* out, long long n){
  long long n4 = n/4;
  hipLaunchKernelGGL(cvt_kernel,dim3((unsigned)((n4+255)/256)),dim3(256),0,s,in,out,n4);
}

extern "C" void kernel_launch(void* const* d_in, const int* in_sizes, int n_in,
                              void* d_out, int out_size, void* d_ws, size_t ws_size,
                              hipStream_t stream)
{
  const float* x       = (const float*)d_in[0];
  const float* norm1_g = (const float*)d_in[2];
  const float* norm1_b = (const float*)d_in[3];
  const float* qkv_w   = (const float*)d_in[4];
  const float* proj_w  = (const float*)d_in[5];
  const float* proj_b  = (const float*)d_in[6];
  const float* norm2_g = (const float*)d_in[7];
  const float* norm2_b = (const float*)d_in[8];
  const float* fc1_w   = (const float*)d_in[9];
  const float* fc1_b   = (const float*)d_in[10];
  const float* fc2_w   = (const float*)d_in[11];
  const float* fc2_b   = (const float*)d_in[12];
  const float* ada1_w  = (const float*)d_in[13];
  const float* ada1_b  = (const float*)d_in[14];
  const float* ada2_w  = (const float*)d_in[15];
  const float* ada2_b  = (const float*)d_in[16];
  const float* bn3_g   = (const float*)d_in[17];
  const float* bn3_b   = (const float*)d_in[18];
  const float* bn3_m   = (const float*)d_in[19];
  const float* bn3_v   = (const float*)d_in[20];
  const float* bn2_g   = (const float*)d_in[21];
  const float* bn2_b   = (const float*)d_in[22];
  const float* bn2_m   = (const float*)d_in[23];
  const float* bn2_v   = (const float*)d_in[24];
  const float* norm3_g = (const float*)d_in[25];
  const float* norm3_b = (const float*)d_in[26];
  const float* a1_qkv_w  = (const float*)d_in[27];
  const float* a1_proj_w = (const float*)d_in[28];
  const float* a1_proj_b = (const float*)d_in[29];
  const void*  maskp     = d_in[30];
  const int*   cluster   = (const int*)d_in[33];
  const int*   fgi       = (const int*)d_in[34];
  float* out = (float*)d_out;

  // ---- workspace ----
  size_t off = 0;
  char* wsb = (char*)d_ws;
  auto alloc = [&](size_t bytes)->void*{
    void* p = wsb + off;
    off += (bytes + 255) & ~(size_t)255;
    return p;
  };
  // persistent
  short*    bufHh = (short*)alloc(8196ll*384*2);
  float*    ptsb  = (float*)alloc(8192ll*384*4);
  float*    cnt   = (float*)alloc(1024*4);
  float*    fsum  = (float*)alloc(1024ll*384*4);
  unsigned* fmaxe = (unsigned*)alloc(1024ll*384*4);
  float*    cell3 = (float*)alloc(1024ll*384*4);
  unsigned char* maskb = (unsigned char*)alloc(6ll*2048*2048);
  float*    gc6   = (float*)alloc(6ll*4096*4);
  short*    qkvT  = (short*)alloc(1152ll*384*2);
  short*    projT = (short*)alloc(384ll*384*2);
  short*    fc1T  = (short*)alloc(1536ll*384*2);
  short*    fc2T  = (short*)alloc(384ll*1536*2);
  short*    ada1T = (short*)alloc(96ll*384*2);
  short*    ada2T = (short*)alloc(384ll*96*2);
  short*    a1qkvT  = (short*)alloc(6ll*1152*384*2);
  short*    a1projT = (short*)alloc(6ll*384*384*2);
  int*      flag  = (int*)alloc(256);
  // arena: A0 [0,75.5M) + A1 [75.5M,151M) + A2 [151M,188.75M)
  char* arena = (char*)alloc(188743680);
  char* A0 = arena;
  char* A1 = arena + 75497472;
  char* A2 = arena + 150994944;
  // phase-1 overlay
  short* bufQh = (short*)(A0 + 0);            // 8196x1152 bf16 (18.9M)
  float* bufO  = (float*)(A0 + 20971520);     // 8196x384 f32 (12.6M)
  short* bufOh = (short*)(A0 + 35651584);     // 8196x384 bf16 (6.3M)
  short* bufAh = (short*)(A0 + 44040192);     // 8196x96 bf16
  float* bufX  = (float*)(A0 + 46137344);     // 8196x384 f32
  float* bufAda= (float*)(A0 + 0);            // ada2 out (aliases bufQh after qkv dead)
  short* Sb16  = (short*)(A1 + 0);            // 6x2049x2080 bf16 (51.1M)
  short* Vt_i  = (short*)(A1 + 53477376);     // 24x64x2080 bf16 (6.4M)
  short* bufTh = (short*)(A1 + 0);            // fc1 out (aliases Sb16 after inner attn)
  // view-phase overlay
  short* QK6   = (short*)(A0 + 0);            // 6x8192x768 bf16 (75.5M)
  short* Vt6   = (short*)(A1 + 0);            // 24x384x2048 bf16 (37.7M)
  short* O6    = (short*)(A2 + 0);            // 6x8192x384 bf16 (37.7M)
  short* bufHh6= (short*)(A2 + 0);            // ln6 out (aliases O6; dead before flash)
  // post-flash overlay
  float* bufT6 = (float*)(A0 + 0);            // 6x8192x384 f32 (75.5M, aliases QK6)
  float* gsum6 = (float*)(A1 + 0);            // 6x4096x384 f32 (37.7M)
  unsigned* gmaxe6 = (unsigned*)(A1 + 37748736); // 6x4096x384 u32 (37.7M)
  float* cell2 = (float*)(A0 + 0);            // 6x4096x384 f32 (written after bufT6 dead)

  // ---- mask detect + byte conversion ----
  hipMemsetAsync(flag, 0, 4, stream);
  {
    long long nInt = 6ll*2048*2048/4;
    detect_mask_kernel<<<dim3((unsigned)((nInt+255)/256)),dim3(256),0,stream>>>((const int*)maskp, nInt, flag);
    mask_byte_kernel<<<dim3((unsigned)((nInt+255)/256)),dim3(256),0,stream>>>(maskp, maskb, nInt, flag);
  }

  // ---- weight transposes (fp32 [K,N] -> bf16 [N,K]) ----
  launch_tconv(stream, qkv_w, 1152, 0,0,1, 384,1152, qkvT, 384, 0, 1);
  launch_tconv(stream, proj_w, 384, 0,0,1, 384,384,  projT, 384, 0, 1);
  launch_tconv(stream, fc1_w, 1536, 0,0,1, 384,1536, fc1T, 384, 0, 1);
  launch_tconv(stream, fc2_w, 384,  0,0,1, 1536,384, fc2T, 1536, 0, 1);
  launch_tconv(stream, ada1_w, 96,  0,0,1, 384,96,   ada1T, 384, 0, 1);
  launch_tconv(stream, ada2_w, 384, 0,0,1, 96,384,   ada2T, 96, 0, 1);
  launch_tconv(stream, a1_qkv_w, 1152, 384ll*1152,0,1, 384,1152, a1qkvT, 384, 1152ll*384, 6);
  launch_tconv(stream, a1_proj_w, 384, 384ll*384,0,1, 384,384,  a1projT, 384, 384ll*384, 6);

  // ---- phase 1: transformer block ----
  ln_bf16_kernel<<<8196,128,0,stream>>>(x, norm1_g, norm1_b, bufHh);
  launch_gemm16b(stream, bufHh,384,0, qkvT,384,0, nullptr,0, nullptr,0,0,
                 bufQh,1152,0,1, 8196,1152,384, 0, 1,1);
  launch_tconv16(stream, bufQh + 768, 1152, 2049ll*1152, 64, 6, 2049, 64, Vt_i, 2080, 64ll*2080, 24);
  hipMemsetAsync(bufO, 0, 8196ll*384*4, stream);
  for (int b=0;b<4;b++){
    const short* qb = bufQh + (long long)b*2049*1152;
    launch_gemm16b(stream, qb,1152,64, qb+384,1152,64, nullptr,0, nullptr,0,0,
                   Sb16,2080,2049ll*2080,1, 2049,2049,64, 0, 6,1);
    softmax_bf16<<<dim3(2049,6),256,0,stream>>>(Sb16,2080,2049ll*2080,2049,0.125f);
    launch_gemm16(stream, Sb16,2080,2049ll*2080, Vt_i + (long long)b*6*64*2080,2080,64ll*2080,
                  nullptr,0, nullptr,0,0,
                  bufO + (long long)b*2049*384,384,64,0, 2049,64,2080, 0, 6,8);
  }
  launch_cvt(stream, bufO, bufOh, 8196ll*384);
  launch_gemm16s(stream, bufOh,384,0, projT,384,0, proj_b,0, x,384,0,
                 bufX,384,0,0, 8196,384,384, 0, 1);
  ln_bf16_kernel<<<8196,128,0,stream>>>(bufX, norm2_g, norm2_b, bufHh);
  launch_gemm16b(stream, bufHh,384,0, fc1T,384,0, fc1_b,0, nullptr,0,0,
                 bufTh,1536,0,1, 8196,1536,384, 1, 1,1);
  launch_gemm16s(stream, bufTh,1536,0, fc2T,1536,0, fc2_b,0, nullptr,0,0,
                 bufO,384,0,0, 8196,384,1536, 0, 1);
  launch_cvt(stream, bufO, bufOh, 8196ll*384);
  launch_gemm16s(stream, bufOh,384,0, ada1T,384,0, ada1_b,0, nullptr,0,0,
                 bufAh,96,0,1, 8196,96,384, 2, 1);
  launch_gemm16s(stream, bufAh,96,0, ada2T,96,0, ada2_b,0, nullptr,0,0,
                 bufAda,384,0,0, 8196,384,96, 0, 1);
  ew_x2_kernel<<<dim3((8196*384+255)/256),256,0,stream>>>(bufX, bufO, bufAda, 8196ll*384);
  copy_cls_kernel<<<6,256,0,stream>>>(bufX, out);
  copy_pts_kernel<<<dim3((8192*384+255)/256),256,0,stream>>>(bufX, ptsb);

  // ---- phase 2: cluster pooling -> cell3 ----
  hipMemsetAsync(cnt, 0, 1024*4, stream);
  hipMemsetAsync(fsum, 0, 1024ll*384*4, stream);
  hipMemsetAsync(fmaxe, 0, 1024ll*384*4, stream);
  scatter_seg_kernel<<<dim3(8192,1),128,0,stream>>>(ptsb, cluster, fsum, fmaxe, cnt, 0,0,0,0);
  cell_kernel<<<dim3(1024,1),128,0,stream>>>(fsum, fmaxe, cnt, bn3_g,bn3_b,bn3_m,bn3_v, cell3, 0,0,0);

  // ---- phase 3a: batched view projections ----
  ln6_kernel<<<8192,128,0,stream>>>(ptsb, norm3_g, norm3_b, bufHh6);
  launch_gemm16b(stream, bufHh6,384,8192ll*384, a1qkvT,384,1152ll*384,
                 nullptr,0, nullptr,0,0, QK6,768,8192ll*768,1, 8192,768,384, 0, 6,1);
  launch_gemm16s(stream, bufHh6,384,8192ll*384, a1qkvT + 768ll*384,384,1152ll*384,
                 nullptr,0, nullptr,0,0, Vt6,2048,4ll*384*2048,2, 8192,384,384, 0, 6);

  // ---- phase 3b: fused flash attention for all 24 (v,b) ----
  flash_view<<<dim3(32,4,6),256,0,stream>>>(QK6, Vt6, maskb, O6);

  // ---- phase 3c: batched proj + grid pooling ----
  launch_gemm16s(stream, O6,384,8192ll*384, a1projT,384,384ll*384,
                 a1_proj_b,384, ptsb,384,0,
                 bufT6,384,8192ll*384,0, 8192,384,384, 0, 6);
  hipMemsetAsync(gc6, 0, 6ll*4096*4, stream);
  hipMemsetAsync(gsum6, 0, 6ll*4096*384*4, stream);
  hipMemsetAsync(gmaxe6, 0, 6ll*4096*384*4, stream);
  scatter_seg_kernel<<<dim3(8192,6),128,0,stream>>>(bufT6, fgi, gsum6, gmaxe6, gc6,
      8192ll*384, 8192, 4096ll*384, 4096);
  cell_kernel<<<dim3(4096,6),128,0,stream>>>(gsum6, gmaxe6, gc6,
      bn2_g, bn2_b, bn2_m, bn2_v, cell2, 4096ll*384, 4096, 384);

  // ---- phase 4: combine ----
  combine_kernel<<<8192,128,0,stream>>>(ptsb, cell3, cluster, cell2, fgi, out);
}

// Round 7
// 1648.515 us; speedup vs baseline: 1.6315x; 1.2016x over previous
//
#include <hip/hip_runtime.h>
#include <math.h>

typedef short bf16x8 __attribute__((ext_vector_type(8)));
typedef float f32x4 __attribute__((ext_vector_type(4)));

#define GLL16(g, l) \
  __builtin_amdgcn_global_load_lds((__attribute__((address_space(1))) const unsigned int*)(g), \
                                   (__attribute__((address_space(3))) unsigned int*)(l), 16, 0, 0)

// ---------- helpers ----------
__device__ __forceinline__ float wsum(float v){
  #pragma unroll
  for (int o=32;o;o>>=1) v += __shfl_xor(v,o);
  return v;
}
__device__ __forceinline__ float geluf(float x){
  return 0.5f*x*(1.0f+erff(x*0.7071067811865475f));
}
__device__ __forceinline__ short fbf(float f){
  unsigned u = __float_as_uint(f);
  unsigned r = (u + 0x7fffu + ((u>>16)&1u)) >> 16;
  return (short)r;
}
__device__ __forceinline__ float bff(short s){
  return __uint_as_float(((unsigned)(unsigned short)s)<<16);
}
__device__ __forceinline__ unsigned fkey(float f){
  unsigned b=__float_as_uint(f);
  return (b&0x80000000u)? ~b : (b|0x80000000u);
}
__device__ __forceinline__ float fdec(unsigned k){
  unsigned b=(k&0x80000000u)? (k&0x7fffffffu) : ~k;
  return __uint_as_float(b);
}

// ---------- mask dtype detection + byte conversion ----------
__global__ void detect_mask_kernel(const int* __restrict__ m, long long n, int* flag){
  long long i = (long long)blockIdx.x*256 + threadIdx.x;
  bool bad = (i<n) && (m[i]!=0 && m[i]!=1);
  if (__any(bad)) { if ((threadIdx.x&63)==0) atomicOr(flag,1); }
}
__global__ void mask_byte_kernel(const void* __restrict__ m, unsigned char* __restrict__ mb,
                                 long long n4, const int* __restrict__ flag){
  long long i = (long long)blockIdx.x*256 + threadIdx.x;
  if (i>=n4) return;
  int mode = *flag;
  uchar4 o;
  if (mode){ o = ((const uchar4*)m)[i]; o.x=o.x!=0; o.y=o.y!=0; o.z=o.z!=0; o.w=o.w!=0; }
  else { int4 v = ((const int4*)m)[i];
         o.x=(unsigned char)(v.x!=0); o.y=(unsigned char)(v.y!=0);
         o.z=(unsigned char)(v.z!=0); o.w=(unsigned char)(v.w!=0); }
  ((uchar4*)mb)[i]=o;
}

__device__ __forceinline__ float epi(float v, const float* bias, int col, int act){
  if (bias) v += bias[col];
  if (act==1) v = geluf(v);
  else if (act==2) v = v*(1.f/(1.f+__expf(-1.702f*v)));
  return v;
}

// ---------- bf16 MFMA GEMM, 128x128 tile ----------
#define XBM 128
#define XBN 128
#define XBK 32
__global__ __launch_bounds__(256)
void gemm_bf16_big(const short* __restrict__ A, int lda, long long sA,
                   const short* __restrict__ B, int ldb, long long sB,
                   const float* __restrict__ bias, long long sBias,
                   const float* __restrict__ res, int ldr, long long sR,
                   void* __restrict__ out, int ldo, long long sO, int outbf16,
                   int M, int N, int K, int act, int KS)
{
  __shared__ short As[XBM*XBK];
  __shared__ short Bs[XBN*XBK];
  int zz = blockIdx.z;
  int z = zz / KS, ks = zz - z*KS;
  A += (long long)z*sA; B += (long long)z*sB;
  if (res) res += (long long)z*sR;
  if (bias) bias += (long long)z*sBias;
  float* outF = (float*)out + (long long)z*sO;
  short* outH = (short*)out + (long long)z*sO;

  int tid = threadIdx.x;
  int rowBase = blockIdx.y*XBM;
  int colBase = blockIdx.x*XBN;

  int Kc = ((K + KS*XBK - 1)/(KS*XBK))*XBK;
  int kbeg = ks*Kc;
  int kend = min(K, kbeg+Kc);
  if (kbeg >= kend) return;

  int w = tid>>6;
  int lane = tid&63;
  int lm = lane&15, quad = lane>>4;
  int waveM = w>>1, waveN = w&1;

  int arow0 = min(rowBase + w*32 + lm,      M-1);
  int arow1 = min(rowBase + w*32 + 16 + lm, M-1);
  int brow0 = min(colBase + w*32 + lm,      N-1);
  int brow1 = min(colBase + w*32 + 16 + lm, N-1);
  const short* Ag0 = A + (long long)arow0*lda + quad*8;
  const short* Ag1 = A + (long long)arow1*lda + quad*8;
  const short* Bg0 = B + (long long)brow0*ldb + quad*8;
  const short* Bg1 = B + (long long)brow1*ldb + quad*8;
  short* Al0 = &As[(w*2+0)*512];
  short* Al1 = &As[(w*2+1)*512];
  short* Bl0 = &Bs[(w*2+0)*512];
  short* Bl1 = &Bs[(w*2+1)*512];

  f32x4 acc[4][4] = {};

  for (int k0=kbeg; k0<kend; k0+=XBK){
    GLL16(Ag0 + k0, Al0);
    GLL16(Ag1 + k0, Al1);
    GLL16(Bg0 + k0, Bl0);
    GLL16(Bg1 + k0, Bl1);
    __syncthreads();
    bf16x8 af[4], bfr[4];
    #pragma unroll
    for (int tm=0;tm<4;tm++) af[tm]  = *(bf16x8*)&As[(waveM*4+tm)*512 + quad*128 + lm*8];
    #pragma unroll
    for (int tn=0;tn<4;tn++) bfr[tn] = *(bf16x8*)&Bs[(waveN*4+tn)*512 + quad*128 + lm*8];
    #pragma unroll
    for (int tm=0;tm<4;tm++)
      #pragma unroll
      for (int tn=0;tn<4;tn++)
        acc[tm][tn] = __builtin_amdgcn_mfma_f32_16x16x32_bf16(af[tm], bfr[tn], acc[tm][tn], 0,0,0);
    __syncthreads();
  }

  #pragma unroll
  for (int tm=0;tm<4;tm++){
    #pragma unroll
    for (int tn=0;tn<4;tn++){
      int col = colBase + waveN*64 + tn*16 + lm;
      if (col>=N) continue;
      #pragma unroll
      for (int reg=0;reg<4;reg++){
        int row = rowBase + waveM*64 + tm*16 + quad*4 + reg;
        if (row>=M) continue;
        float v = acc[tm][tn][reg];
        if (KS>1){ atomicAdd(&outF[(long long)row*ldo+col], v); continue; }
        v = epi(v, bias, col, act);
        if (res) v += res[(long long)row*ldr+col];
        if (outbf16) outH[(long long)row*ldo+col] = fbf(v);
        else         outF[(long long)row*ldo+col] = v;
      }
    }
  }
}

// ---------- bf16 MFMA GEMM, 64x64 tile ----------
// outbf16==2: transposed V store: out + (b*384+col)*2048 + (row&2047), b=row>>11
__global__ __launch_bounds__(256)
void gemm_bf16_s(const short* __restrict__ A, int lda, long long sA,
                 const short* __restrict__ B, int ldb, long long sB,
                 const float* __restrict__ bias, long long sBias,
                 const float* __restrict__ res, int ldr, long long sR,
                 void* __restrict__ out, int ldo, long long sO, int outbf16,
                 int M, int N, int K, int act)
{
  __shared__ short As[64*32];
  __shared__ short Bs[64*32];
  int z = blockIdx.z;
  A += (long long)z*sA; B += (long long)z*sB;
  if (res) res += (long long)z*sR;
  if (bias) bias += (long long)z*sBias;
  float* outF = (float*)out + (long long)z*sO;
  short* outH = (short*)out + (long long)z*sO;

  int tid = threadIdx.x;
  int rowBase = blockIdx.y*64;
  int colBase = blockIdx.x*64;

  int w = tid>>6;
  int lane = tid&63;
  int lm = lane&15, quad = lane>>4;
  int wm = w>>1, wn = w&1;

  int arow = min(rowBase + w*16 + lm, M-1);
  int brow = min(colBase + w*16 + lm, N-1);
  const short* Ag = A + (long long)arow*lda + quad*8;
  const short* Bg = B + (long long)brow*ldb + quad*8;
  short* Al = &As[w*512];
  short* Bl = &Bs[w*512];

  f32x4 acc[2][2] = {};

  for (int k0=0; k0<K; k0+=32){
    GLL16(Ag + k0, Al);
    GLL16(Bg + k0, Bl);
    __syncthreads();
    bf16x8 af[2], bfr[2];
    #pragma unroll
    for (int tm=0;tm<2;tm++) af[tm]  = *(bf16x8*)&As[(wm*2+tm)*512 + quad*128 + lm*8];
    #pragma unroll
    for (int tn=0;tn<2;tn++) bfr[tn] = *(bf16x8*)&Bs[(wn*2+tn)*512 + quad*128 + lm*8];
    #pragma unroll
    for (int tm=0;tm<2;tm++)
      #pragma unroll
      for (int tn=0;tn<2;tn++)
        acc[tm][tn] = __builtin_amdgcn_mfma_f32_16x16x32_bf16(af[tm], bfr[tn], acc[tm][tn], 0,0,0);
    __syncthreads();
  }

  #pragma unroll
  for (int tm=0;tm<2;tm++){
    #pragma unroll
    for (int tn=0;tn<2;tn++){
      int col = colBase + wn*32 + tn*16 + lm;
      if (col>=N) continue;
      #pragma unroll
      for (int reg=0;reg<4;reg++){
        int row = rowBase + wm*32 + tm*16 + quad*4 + reg;
        if (row>=M) continue;
        float v = epi(acc[tm][tn][reg], bias, col, act);
        if (res) v += res[(long long)row*ldr+col];
        if (outbf16==2){
          int bb = row>>11;
          outH[((long long)bb*384 + col)*2048 + (row&2047)] = fbf(v);
        }
        else if (outbf16) outH[(long long)row*ldo+col] = fbf(v);
        else              outF[(long long)row*ldo+col] = v;
      }
    }
  }
}

// ---------- flash-fused view attention v3: shared-P, PV split by tn ----------
// QK6: [6][8192][768] bf16 (Q 0..384, K 384..768); Vt6: [24][384][2048] bf16
// maskb: [6][2048][2048] u8; O6: [6][8192][384] bf16
// LDS: KV region 48KB [0,49152) + P [64][72]bf16 [49152,58368) + alpha f32[64]
__global__ __launch_bounds__(256,2)
void flash_view(const short* __restrict__ QK6, const short* __restrict__ Vt6,
                const unsigned char* __restrict__ maskb, short* __restrict__ O6)
{
  __shared__ char lds[58624];
  const float scale = 0.05103103630798288f;
  int qt=blockIdx.x, b=blockIdx.y, v=blockIdx.z;
  int tid=threadIdx.x, w=tid>>6, lane=tid&63, lm=lane&15, quad=lane>>4;

  const short* Qp = QK6 + ((long long)v*8192 + b*2048 + qt*64)*768;
  const short* Kp = QK6 + ((long long)v*8192 + b*2048)*768 + 384;
  const short* Vp = Vt6 + (long long)(v*4+b)*384*2048;
  const unsigned char* Mp = maskb + (long long)v*2048*2048 + (long long)qt*64*2048;
  short* Op = O6 + ((long long)v*8192 + b*2048 + qt*64)*384;

  short* P = (short*)(lds + 49152);
  float* alphaL = (float*)(lds + 58368);

  // Q A-frags: direct global->reg (wave w owns q-rows w*16..w*16+16)
  bf16x8 af[12];
  #pragma unroll
  for (int c=0;c<12;c++)
    af[c] = *(const bf16x8*)(Qp + (long long)(w*16+lm)*768 + c*32 + quad*8);

  float m_i[4], l_i[4];
  #pragma unroll
  for (int r=0;r<4;r++){ m_i[r]=-3.0e38f; l_i[r]=0.f; }
  f32x4 Oacc[4][6] = {};

  for (int kt=0; kt<32; kt++){
    // ---- stage K (64x384): wave w stages rows w*16..+16 -> [w*12KB + kc*1KB)
    #pragma unroll
    for (int c=0;c<12;c++)
      GLL16(Kp + (long long)(kt*64 + w*16 + lm)*768 + c*32 + quad*8, (short*)(lds + w*12288 + c*1024));
    __syncthreads();  // K ready
    // ---- S: Q(16x384) @ K(64x384)^T
    f32x4 S[4];
    #pragma unroll
    for (int i=0;i<4;i++) S[i] = (f32x4){0.f,0.f,0.f,0.f};
    #pragma unroll
    for (int kc=0;kc<12;kc++){
      #pragma unroll
      for (int ct=0;ct<4;ct++){
        bf16x8 bf = *(bf16x8*)(lds + ct*12288 + kc*1024 + quad*256 + lm*16);
        S[ct] = __builtin_amdgcn_mfma_f32_16x16x32_bf16(af[kc], bf, S[ct], 0,0,0);
      }
    }
    // ---- mask + scale
    #pragma unroll
    for (int ct=0;ct<4;ct++){
      #pragma unroll
      for (int r=0;r<4;r++){
        unsigned char mb = Mp[(long long)(w*16+quad*4+r)*2048 + kt*64 + ct*16 + lm];
        S[ct][r] = mb ? S[ct][r]*scale : -3.0e38f;
      }
    }
    // ---- online softmax for wave's 16 q-rows
    float alpha[4], mnew[4];
    #pragma unroll
    for (int r=0;r<4;r++){
      float rm = S[0][r];
      #pragma unroll
      for (int ct=1;ct<4;ct++) rm = fmaxf(rm, S[ct][r]);
      #pragma unroll
      for (int o=1;o<16;o<<=1) rm = fmaxf(rm, __shfl_xor(rm, o));
      mnew[r] = fmaxf(m_i[r], rm);
      alpha[r] = __expf(m_i[r]-mnew[r]);
      m_i[r] = mnew[r];
    }
    float rs[4] = {0.f,0.f,0.f,0.f};
    #pragma unroll
    for (int ct=0;ct<4;ct++){
      #pragma unroll
      for (int r=0;r<4;r++){
        float sv = S[ct][r];
        float p = (sv > -1.0e37f) ? __expf(sv - mnew[r]) : 0.f;
        rs[r] += p;
        P[(w*16+quad*4+r)*72 + ct*16 + lm] = fbf(p);
      }
    }
    #pragma unroll
    for (int r=0;r<4;r++){
      #pragma unroll
      for (int o=1;o<16;o<<=1) rs[r] += __shfl_xor(rs[r], o);
      l_i[r] = l_i[r]*alpha[r] + rs[r];
    }
    if (lm==0){
      #pragma unroll
      for (int r=0;r<4;r++) alphaL[w*16+quad*4+r] = alpha[r];
    }
    __syncthreads();  // K reads done; P+alpha visible
    // ---- stage V^T rows (w*6+j)*16.. (wave's own tn slice) over K region
    #pragma unroll
    for (int j=0;j<6;j++){
      #pragma unroll
      for (int kk=0;kk<2;kk++)
        GLL16(Vp + (long long)((w*6+j)*16+lm)*2048 + kt*64 + kk*32 + quad*8,
              (short*)(lds + ((w*6+j)*2+kk)*1024));
    }
    // ---- rescale Oacc (all 64 rows' alphas) while V loads fly
    f32x4 am[4];
    #pragma unroll
    for (int m=0;m<4;m++) am[m] = *(f32x4*)&alphaL[m*16 + quad*4];
    #pragma unroll
    for (int m=0;m<4;m++)
      #pragma unroll
      for (int tn=0;tn<6;tn++)
        Oacc[m][tn] *= am[m];
    __syncthreads();  // V ready
    // ---- PV: P(64x64) @ V(64x384), wave computes its 6 tn for all rows
    #pragma unroll
    for (int kk=0;kk<2;kk++){
      bf16x8 ap[4];
      #pragma unroll
      for (int m=0;m<4;m++) ap[m] = *(bf16x8*)&P[(m*16+lm)*72 + kk*32 + quad*8];
      #pragma unroll
      for (int tn=0;tn<6;tn++){
        bf16x8 bf = *(bf16x8*)(lds + ((w*6+tn)*2+kk)*1024 + quad*256 + lm*16);
        #pragma unroll
        for (int m=0;m<4;m++)
          Oacc[m][tn] = __builtin_amdgcn_mfma_f32_16x16x32_bf16(ap[m], bf, Oacc[m][tn], 0,0,0);
      }
    }
    __syncthreads();  // P/V consumed before next kt overwrites
  }

  if (lm==0){
    #pragma unroll
    for (int r=0;r<4;r++) alphaL[w*16+quad*4+r] = l_i[r];
  }
  __syncthreads();
  f32x4 lv[4];
  #pragma unroll
  for (int m=0;m<4;m++) lv[m] = *(f32x4*)&alphaL[m*16 + quad*4];
  #pragma unroll
  for (int m=0;m<4;m++){
    #pragma unroll
    for (int tn=0;tn<6;tn++){
      #pragma unroll
      for (int reg=0;reg<4;reg++){
        Op[(long long)(m*16+quad*4+reg)*384 + (w*6+tn)*16 + lm] = fbf(Oacc[m][tn][reg] / lv[m][reg]);
      }
    }
  }
}

// ---------- flash-fused inner attention: d=64, S=2049, 24 (b,h) pairs ----------
// QKV = bufQh [4][2049][1152]; Vt = Vt_i [24][64][2112] (V^T, zero-padded)
// O = bufOh [4*2049][384]  (bf16)
// LDS: KV 8KB [0,8192) + P [64][72] [8192,17408) + alpha f32[64]
__global__ __launch_bounds__(256,4)
void flash_inner(const short* __restrict__ QKV, const short* __restrict__ Vt,
                 short* __restrict__ O)
{
  __shared__ char lds[17664];
  int qt=blockIdx.x;            // 0..32
  int bh=blockIdx.y;            // 0..23
  int b=bh/6, h=bh-b*6;
  int tid=threadIdx.x, w=tid>>6, lane=tid&63, lm=lane&15, quad=lane>>4;

  const short* Qb = QKV + (long long)b*2049*1152 + h*64;
  const short* Kb = Qb + 384;
  const short* Vtp = Vt + (long long)bh*64*2112;
  short* Op = O + ((long long)b*2049 + qt*64)*384 + h*64;

  short* P = (short*)(lds + 8192);
  float* alphaL = (float*)(lds + 17408);

  int qr = min(qt*64 + w*16 + lm, 2048);
  bf16x8 af[2];
  #pragma unroll
  for (int c=0;c<2;c++)
    af[c] = *(const bf16x8*)(Qb + (long long)qr*1152 + c*32 + quad*8);

  float m_i[4], l_i[4];
  #pragma unroll
  for (int r=0;r<4;r++){ m_i[r]=-3.0e38f; l_i[r]=0.f; }
  f32x4 Oacc[4] = {};

  for (int kt=0; kt<33; kt++){
    int kr = min(kt*64 + w*16 + lm, 2048);
    #pragma unroll
    for (int c=0;c<2;c++)
      GLL16(Kb + (long long)kr*1152 + c*32 + quad*8, (short*)(lds + w*2048 + c*1024));
    __syncthreads();
    f32x4 S[4];
    #pragma unroll
    for (int i=0;i<4;i++) S[i] = (f32x4){0.f,0.f,0.f,0.f};
    #pragma unroll
    for (int kc=0;kc<2;kc++){
      #pragma unroll
      for (int ct=0;ct<4;ct++){
        bf16x8 bf = *(bf16x8*)(lds + ct*2048 + kc*1024 + quad*256 + lm*16);
        S[ct] = __builtin_amdgcn_mfma_f32_16x16x32_bf16(af[kc], bf, S[ct], 0,0,0);
      }
    }
    #pragma unroll
    for (int ct=0;ct<4;ct++){
      int scol = kt*64 + ct*16 + lm;
      bool ok = scol <= 2048;
      #pragma unroll
      for (int r=0;r<4;r++) S[ct][r] = ok ? S[ct][r]*0.125f : -3.0e38f;
    }
    float alpha[4], mnew[4];
    #pragma unroll
    for (int r=0;r<4;r++){
      float rm = S[0][r];
      #pragma unroll
      for (int ct=1;ct<4;ct++) rm = fmaxf(rm, S[ct][r]);
      #pragma unroll
      for (int o=1;o<16;o<<=1) rm = fmaxf(rm, __shfl_xor(rm, o));
      mnew[r] = fmaxf(m_i[r], rm);
      alpha[r] = __expf(m_i[r]-mnew[r]);
      m_i[r] = mnew[r];
    }
    float rs[4] = {0.f,0.f,0.f,0.f};
    #pragma unroll
    for (int ct=0;ct<4;ct++){
      #pragma unroll
      for (int r=0;r<4;r++){
        float sv = S[ct][r];
        float p = (sv > -1.0e37f) ? __expf(sv - mnew[r]) : 0.f;
        rs[r] += p;
        P[(w*16+quad*4+r)*72 + ct*16 + lm] = fbf(p);
      }
    }
    #pragma unroll
    for (int r=0;r<4;r++){
      #pragma unroll
      for (int o=1;o<16;o<<=1) rs[r] += __shfl_xor(rs[r], o);
      l_i[r] = l_i[r]*alpha[r] + rs[r];
    }
    if (lm==0){
      #pragma unroll
      for (int r=0;r<4;r++) alphaL[w*16+quad*4+r] = alpha[r];
    }
    __syncthreads();
    // stage V^T rows w*16..+16 (wave's own tn=w), cols kt*64..
    #pragma unroll
    for (int kk=0;kk<2;kk++)
      GLL16(Vtp + (long long)(w*16+lm)*2112 + kt*64 + kk*32 + quad*8,
            (short*)(lds + w*2048 + kk*1024));
    f32x4 am[4];
    #pragma unroll
    for (int m=0;m<4;m++) am[m] = *(f32x4*)&alphaL[m*16 + quad*4];
    #pragma unroll
    for (int m=0;m<4;m++) Oacc[m] *= am[m];
    __syncthreads();
    #pragma unroll
    for (int kk=0;kk<2;kk++){
      bf16x8 ap[4];
      #pragma unroll
      for (int m=0;m<4;m++) ap[m] = *(bf16x8*)&P[(m*16+lm)*72 + kk*32 + quad*8];
      bf16x8 bf = *(bf16x8*)(lds + w*2048 + kk*1024 + quad*256 + lm*16);
      #pragma unroll
      for (int m=0;m<4;m++)
        Oacc[m] = __builtin_amdgcn_mfma_f32_16x16x32_bf16(ap[m], bf, Oacc[m], 0,0,0);
    }
    __syncthreads();
  }

  if (lm==0){
    #pragma unroll
    for (int r=0;r<4;r++) alphaL[w*16+quad*4+r] = l_i[r];
  }
  __syncthreads();
  f32x4 lv[4];
  #pragma unroll
  for (int m=0;m<4;m++) lv[m] = *(f32x4*)&alphaL[m*16 + quad*4];
  #pragma unroll
  for (int m=0;m<4;m++){
    #pragma unroll
    for (int reg=0;reg<4;reg++){
      int row = qt*64 + m*16 + quad*4 + reg;
      if (row < 2049)
        Op[(long long)(m*16+quad*4+reg)*384 + w*16 + lm] = fbf(Oacc[m][reg] / lv[m][reg]);
    }
  }
}

// ---------- LayerNorm (fp32 in -> bf16 out), C=384 ----------
__global__ __launch_bounds__(128)
void ln_bf16_kernel(const float* __restrict__ in, const float* __restrict__ g,
                    const float* __restrict__ bt, short* __restrict__ out)
{
  long long row = blockIdx.x;
  const float* p = in + row*384;
  int tid = threadIdx.x;
  float v0=p[tid], v1=p[tid+128], v2=p[tid+256];
  float s = v0+v1+v2;
  float ss = v0*v0+v1*v1+v2*v2;
  __shared__ float r1[2], r2[2];
  s = wsum(s); ss = wsum(ss);
  int wid=tid>>6, lane=tid&63;
  if (lane==0){ r1[wid]=s; r2[wid]=ss; }
  __syncthreads();
  float mean=(r1[0]+r1[1])*(1.f/384.f);
  float var =(r2[0]+r2[1])*(1.f/384.f)-mean*mean;
  float rstd=rsqrtf(var+1e-5f);
  short* o = out + row*384;
  o[tid]     = fbf((v0-mean)*rstd*g[tid]+bt[tid]);
  o[tid+128] = fbf((v1-mean)*rstd*g[tid+128]+bt[tid+128]);
  o[tid+256] = fbf((v2-mean)*rstd*g[tid+256]+bt[tid+256]);
}

// ---------- LN once, write 6 per-view normed copies ----------
__global__ __launch_bounds__(128)
void ln6_kernel(const float* __restrict__ in, const float* __restrict__ g6,
                const float* __restrict__ b6, short* __restrict__ out6)
{
  long long row = blockIdx.x;
  const float* p = in + row*384;
  int tid = threadIdx.x;
  float v0=p[tid], v1=p[tid+128], v2=p[tid+256];
  float s = v0+v1+v2;
  float ss = v0*v0+v1*v1+v2*v2;
  __shared__ float r1[2], r2[2];
  s = wsum(s); ss = wsum(ss);
  int wid=tid>>6, lane=tid&63;
  if (lane==0){ r1[wid]=s; r2[wid]=ss; }
  __syncthreads();
  float mean=(r1[0]+r1[1])*(1.f/384.f);
  float var =(r2[0]+r2[1])*(1.f/384.f)-mean*mean;
  float rstd=rsqrtf(var+1e-5f);
  float n0=(v0-mean)*rstd, n1=(v1-mean)*rstd, n2=(v2-mean)*rstd;
  #pragma unroll
  for (int i=0;i<6;i++){
    const float* g = g6 + i*384;
    const float* bt = b6 + i*384;
    short* o = out6 + (long long)i*8192*384 + row*384;
    o[tid]     = fbf(n0*g[tid]+bt[tid]);
    o[tid+128] = fbf(n1*g[tid+128]+bt[tid+128]);
    o[tid+256] = fbf(n2*g[tid+256]+bt[tid+256]);
  }
}

// ---------- fp32 -> bf16 convert ----------
__global__ void cvt_kernel(const float* __restrict__ in, short* __restrict__ out, long long n4){
  long long i = (long long)blockIdx.x*256 + threadIdx.x;
  if (i<n4){
    float4 f = ((const float4*)in)[i];
    short4 s;
    s.x=fbf(f.x); s.y=fbf(f.y); s.z=fbf(f.z); s.w=fbf(f.w);
    ((short4*)out)[i]=s;
  }
}

// ---------- tiled transpose+convert: fp32 [R,C] -> bf16 [C, ldout] ----------
__global__ __launch_bounds__(256)
void tconv_kernel(const float* __restrict__ in, int ldin, long long sIn, long long sIn2, int zmod,
                  int R, int C, short* __restrict__ out, int ldout, long long sOut)
{
  __shared__ float tile[32][33];
  int z = blockIdx.z;
  const float* ip = in + (long long)(z/zmod)*sIn + (long long)(z%zmod)*sIn2;
  short* op = out + (long long)z*sOut;
  int r0 = blockIdx.x*32;
  int c0 = blockIdx.y*32;
  int tx = threadIdx.x&31, ty = threadIdx.x>>5;
  #pragma unroll
  for (int i=0;i<4;i++){
    int r = r0 + ty + i*8, c = c0 + tx;
    tile[ty+i*8][tx] = (r<R && c<C) ? ip[(long long)r*ldin + c] : 0.f;
  }
  __syncthreads();
  #pragma unroll
  for (int i=0;i<4;i++){
    int oc = c0 + ty + i*8;
    int orr = r0 + tx;
    if (oc<C && orr<ldout) op[(long long)oc*ldout + orr] = fbf(tile[tx][ty+i*8]);
  }
}

// ---------- tiled transpose: bf16 [R,C] -> bf16 [C, ldout] ----------
__global__ __launch_bounds__(256)
void tconv16_kernel(const short* __restrict__ in, int ldin, long long sIn, long long sIn2, int zmod,
                    int R, int C, short* __restrict__ out, int ldout, long long sOut)
{
  __shared__ short tile[32][34];
  int z = blockIdx.z;
  const short* ip = in + (long long)(z/zmod)*sIn + (long long)(z%zmod)*sIn2;
  short* op = out + (long long)z*sOut;
  int r0 = blockIdx.x*32;
  int c0 = blockIdx.y*32;
  int tx = threadIdx.x&31, ty = threadIdx.x>>5;
  #pragma unroll
  for (int i=0;i<4;i++){
    int r = r0 + ty + i*8, c = c0 + tx;
    tile[ty+i*8][tx] = (r<R && c<C) ? ip[(long long)r*ldin + c] : (short)0;
  }
  __syncthreads();
  #pragma unroll
  for (int i=0;i<4;i++){
    int oc = c0 + ty + i*8;
    int orr = r0 + tx;
    if (oc<C && orr<ldout) op[(long long)oc*ldout + orr] = tile[tx][ty+i*8];
  }
}

// ---------- elementwise ----------
__global__ void ew_x2_kernel(float* x1, const float* ffn, const float* ada, long long n){
  long long i=(long long)blockIdx.x*256+threadIdx.x;
  if (i<n) x1[i] = x1[i] + ffn[i] + 0.5f*ada[i];
}
__global__ void copy_pts_kernel(const float* __restrict__ x2, float* __restrict__ pts){
  long long i=(long long)blockIdx.x*256+threadIdx.x;
  if (i < 8192ll*384){
    long long b = i/(2048ll*384);
    long long rem = i%(2048ll*384);
    pts[i] = x2[(b*2049+1)*384 + rem];
  }
}
__global__ void copy_cls_kernel(const float* __restrict__ x2, float* __restrict__ out){
  int i = blockIdx.x*256+threadIdx.x;
  if (i < 4*384){
    int b=i/384, c=i%384;
    out[(long long)b*2049*384 + c] = x2[(long long)b*2049*384 + c];
  }
}

// ---------- segment scatter (z-batched) ----------
__global__ __launch_bounds__(128)
void scatter_seg_kernel(const float* __restrict__ feat, const int* __restrict__ seg,
                        float* __restrict__ fsum, unsigned* __restrict__ fmax,
                        float* __restrict__ cnt,
                        long long zFeat, long long zSeg, long long zSum, long long zCnt)
{
  int n = blockIdx.x, z = blockIdx.y;
  feat += (long long)z*zFeat; seg += (long long)z*zSeg;
  fsum += (long long)z*zSum; fmax += (long long)z*zSum; cnt += (long long)z*zCnt;
  int s = seg[n];
  const float* p = feat + (long long)n*384;
  int tid = threadIdx.x;
  #pragma unroll
  for (int k=0;k<3;k++){
    int c = tid + k*128;
    float v = p[c];
    atomicAdd(&fsum[(long long)s*384+c], v);
    atomicMax(&fmax[(long long)s*384+c], fkey(v));
  }
  if (tid==0) atomicAdd(&cnt[s], 1.0f);
}

// ---------- cell = bn_gelu(max + mean), z-batched ----------
__global__ __launch_bounds__(128)
void cell_kernel(const float* __restrict__ fsum, const unsigned* __restrict__ fmax,
                 const float* __restrict__ cnt,
                 const float* __restrict__ g, const float* __restrict__ bb,
                 const float* __restrict__ m, const float* __restrict__ v,
                 float* __restrict__ out, long long zSum, long long zCnt, long long zP)
{
  int s = blockIdx.x, z = blockIdx.y;
  fsum += (long long)z*zSum; fmax += (long long)z*zSum; cnt += (long long)z*zCnt;
  g += (long long)z*zP; bb += (long long)z*zP; m += (long long)z*zP; v += (long long)z*zP;
  out += (long long)z*zSum;
  float cn = cnt[s];
  float denom = fmaxf(cn, 1.f);
  int tid = threadIdx.x;
  #pragma unroll
  for (int k=0;k<3;k++){
    int c = tid + k*128;
    float mx = (cn>0.f) ? fdec(fmax[(long long)s*384+c]) : 0.f;
    float t = mx + fsum[(long long)s*384+c]/denom;
    t = (t - m[c])*rsqrtf(v[c]+1e-5f)*g[c] + bb[c];
    out[(long long)s*384+c] = geluf(t);
  }
}

// ---------- final cosine-sim weighted combine ----------
__global__ __launch_bounds__(128)
void combine_kernel(const float* __restrict__ pts, const float* __restrict__ cell3,
                    const int* __restrict__ cluster, const float* __restrict__ cell2,
                    const int* __restrict__ gidx, float* __restrict__ out)
{
  int n = blockIdx.x;
  int tid = threadIdx.x;
  __shared__ float sdot[6], ssq[6], sw[6];
  __shared__ int soff[6];
  __shared__ float red[2][2];
  __shared__ float sn3;
  const float* x3 = cell3 + (long long)cluster[n]*384;
  int wid=tid>>6, lane=tid&63;
  float sq=0.f;
  for (int c=tid;c<384;c+=128){ float v=x3[c]; sq+=v*v; }
  sq = wsum(sq);
  if (lane==0) red[0][wid]=sq;
  __syncthreads();
  if (tid==0) sn3 = sqrtf(red[0][0]+red[0][1]);
  __syncthreads();
  for (int i=0;i<6;i++){
    int gi = gidx[(long long)i*8192 + n];
    if (tid==0) soff[i]=gi;
    const float* r = cell2 + ((long long)i*4096 + gi)*384;
    float d=0.f, s2=0.f;
    for (int c=tid;c<384;c+=128){ float a=r[c]; d+=a*x3[c]; s2+=a*a; }
    d = wsum(d); s2 = wsum(s2);
    if (lane==0){ red[0][wid]=d; red[1][wid]=s2; }
    __syncthreads();
    if (tid==0){ sdot[i]=red[0][0]+red[0][1]; ssq[i]=red[1][0]+red[1][1]; }
    __syncthreads();
  }
  if (tid==0){
    float ssumv=0.f; float sims[6];
    for (int i=0;i<6;i++){
      float nrm = sqrtf(ssq[i])*sn3;
      float s = (sdot[i]/fmaxf(nrm,1e-8f) + 1.f)*0.5f;
      sims[i]=s; ssumv+=s;
    }
    for (int i=0;i<6;i++) sw[i]=sims[i]/ssumv;
  }
  __syncthreads();
  int b = n>>11, gp = n&2047;
  float* o = out + ((long long)(b*2049 + 1 + gp))*384;
  for (int c=tid;c<384;c+=128){
    float acc=0.f;
    #pragma unroll
    for (int i=0;i<6;i++){
      const float* r = cell2 + ((long long)i*4096 + soff[i])*384;
      acc += sw[i]*r[c];
    }
    o[c] = pts[(long long)n*384+c] + 0.5f*acc;
  }
}

// ---------- host helpers ----------
static inline void launch_gemm16b(hipStream_t s, const short* A,int lda,long long sA,
  const short* B,int ldb,long long sB, const float* bias, long long sBias,
  const float* res,int ldr,long long sR, void* out,int ldo,long long sO,int outbf16,
  int M,int N,int K,int act,int nz,int KS)
{
  dim3 g((N+XBN-1)/XBN,(M+XBM-1)/XBM,(unsigned)(nz*KS));
  hipLaunchKernelGGL(gemm_bf16_big,g,dim3(256),0,s,
    A,lda,sA,B,ldb,sB,bias,sBias,res,ldr,sR,out,ldo,sO,outbf16,M,N,K,act,KS);
}
static inline void launch_gemm16s(hipStream_t s, const short* A,int lda,long long sA,
  const short* B,int ldb,long long sB, const float* bias, long long sBias,
  const float* res,int ldr,long long sR, void* out,int ldo,long long sO,int outbf16,
  int M,int N,int K,int act,int nz)
{
  dim3 g((N+63)/64,(M+63)/64,(unsigned)nz);
  hipLaunchKernelGGL(gemm_bf16_s,g,dim3(256),0,s,
    A,lda,sA,B,ldb,sB,bias,sBias,res,ldr,sR,out,ldo,sO,outbf16,M,N,K,act);
}
static inline void launch_tconv(hipStream_t s, const float* in,int ldin,long long sIn,long long sIn2,int zmod,
  int R,int C, short* out,int ldout,long long sOut,int nz)
{
  dim3 g((ldout+31)/32,(C+31)/32,(unsigned)nz);
  hipLaunchKernelGGL(tconv_kernel,g,dim3(256),0,s, in,ldin,sIn,sIn2,zmod,R,C,out,ldout,sOut);
}
static inline void launch_tconv16(hipStream_t s, const short* in,int ldin,long long sIn,long long sIn2,int zmod,
  int R,int C, short* out,int ldout,long long sOut,int nz)
{
  dim3 g((ldout+31)/32,(C+31)/32,(unsigned)nz);
  hipLaunchKernelGGL(tconv16_kernel,g,dim3(256),0,s, in,ldin,sIn,sIn2,zmod,R,C,out,ldout,sOut);
}
static inline void launch_cvt(hipStream_t s, const float* in, short* out, long long n){
  long long n4 = n/4;
  hipLaunchKernelGGL(cvt_kernel,dim3((unsigned)((n4+255)/256)),dim3(256),0,s,in,out,n4);
}

extern "C" void kernel_launch(void* const* d_in, const int* in_sizes, int n_in,
                              void* d_out, int out_size, void* d_ws, size_t ws_size,
                              hipStream_t stream)
{
  const float* x       = (const float*)d_in[0];
  const float* norm1_g = (const float*)d_in[2];
  const float* norm1_b = (const float*)d_in[3];
  const float* qkv_w   = (const float*)d_in[4];
  const float* proj_w  = (const float*)d_in[5];
  const float* proj_b  = (const float*)d_in[6];
  const float* norm2_g = (const float*)d_in[7];
  const float* norm2_b = (const float*)d_in[8];
  const float* fc1_w   = (const float*)d_in[9];
  const float* fc1_b   = (const float*)d_in[10];
  const float* fc2_w   = (const float*)d_in[11];
  const float* fc2_b   = (const float*)d_in[12];
  const float* ada1_w  = (const float*)d_in[13];
  const float* ada1_b  = (const float*)d_in[14];
  const float* ada2_w  = (const float*)d_in[15];
  const float* ada2_b  = (const float*)d_in[16];
  const float* bn3_g   = (const float*)d_in[17];
  const float* bn3_b   = (const float*)d_in[18];
  const float* bn3_m   = (const float*)d_in[19];
  const float* bn3_v   = (const float*)d_in[20];
  const float* bn2_g   = (const float*)d_in[21];
  const float* bn2_b   = (const float*)d_in[22];
  const float* bn2_m   = (const float*)d_in[23];
  const float* bn2_v   = (const float*)d_in[24];
  const float* norm3_g = (const float*)d_in[25];
  const float* norm3_b = (const float*)d_in[26];
  const float* a1_qkv_w  = (const float*)d_in[27];
  const float* a1_proj_w = (const float*)d_in[28];
  const float* a1_proj_b = (const float*)d_in[29];
  const void*  maskp     = d_in[30];
  const int*   cluster   = (const int*)d_in[33];
  const int*   fgi       = (const int*)d_in[34];
  float* out = (float*)d_out;

  // ---- workspace ----
  size_t off = 0;
  char* wsb = (char*)d_ws;
  auto alloc = [&](size_t bytes)->void*{
    void* p = wsb + off;
    off += (bytes + 255) & ~(size_t)255;
    return p;
  };
  // persistent
  short*    bufHh = (short*)alloc(8196ll*384*2);
  float*    ptsb  = (float*)alloc(8192ll*384*4);
  float*    cnt   = (float*)alloc(1024*4);
  float*    fsum  = (float*)alloc(1024ll*384*4);
  unsigned* fmaxe = (unsigned*)alloc(1024ll*384*4);
  float*    cell3 = (float*)alloc(1024ll*384*4);
  unsigned char* maskb = (unsigned char*)alloc(6ll*2048*2048);
  float*    gc6   = (float*)alloc(6ll*4096*4);
  short*    qkvT  = (short*)alloc(1152ll*384*2);
  short*    projT = (short*)alloc(384ll*384*2);
  short*    fc1T  = (short*)alloc(1536ll*384*2);
  short*    fc2T  = (short*)alloc(384ll*1536*2);
  short*    ada1T = (short*)alloc(96ll*384*2);
  short*    ada2T = (short*)alloc(384ll*96*2);
  short*    a1qkvT  = (short*)alloc(6ll*1152*384*2);
  short*    a1projT = (short*)alloc(6ll*384*384*2);
  int*      flag  = (int*)alloc(256);
  // arena: A0 [0,75.5M) + A1 [75.5M,151M) + A2 [151M,188.75M)
  char* arena = (char*)alloc(188743680);
  char* A0 = arena;
  char* A1 = arena + 75497472;
  char* A2 = arena + 150994944;
  // phase-1 overlay
  short* bufQh = (short*)(A0 + 0);            // 8196x1152 bf16 (18.9M)
  float* bufO  = (float*)(A0 + 20971520);     // 8196x384 f32 (12.6M)
  short* bufOh = (short*)(A0 + 35651584);     // 8196x384 bf16 (6.3M)
  short* bufAh = (short*)(A0 + 44040192);     // 8196x96 bf16
  float* bufX  = (float*)(A0 + 46137344);     // 8196x384 f32
  float* bufAda= (float*)(A0 + 0);            // ada2 out (aliases bufQh after qkv dead)
  short* Vt_i  = (short*)(A1 + 0);            // 24x64x2112 bf16 (6.5M)
  short* bufTh = (short*)(A1 + 8388608);      // fc1 out 8196x1536 bf16 (25.2M; Vt_i dead by then)
  // view-phase overlay
  short* QK6   = (short*)(A0 + 0);            // 6x8192x768 bf16 (75.5M)
  short* Vt6   = (short*)(A1 + 0);            // 24x384x2048 bf16 (37.7M)
  short* O6    = (short*)(A2 + 0);            // 6x8192x384 bf16 (37.7M)
  short* bufHh6= (short*)(A2 + 0);            // ln6 out (aliases O6; dead before flash)
  // post-flash overlay
  float* bufT6 = (float*)(A0 + 0);            // 6x8192x384 f32 (75.5M, aliases QK6)
  float* gsum6 = (float*)(A1 + 0);            // 6x4096x384 f32 (37.7M)
  unsigned* gmaxe6 = (unsigned*)(A1 + 37748736); // 6x4096x384 u32
  float* cell2 = (float*)(A0 + 0);            // 6x4096x384 f32 (written after bufT6 dead)

  // ---- mask detect + byte conversion ----
  hipMemsetAsync(flag, 0, 4, stream);
  {
    long long nInt = 6ll*2048*2048/4;
    detect_mask_kernel<<<dim3((unsigned)((nInt+255)/256)),dim3(256),0,stream>>>((const int*)maskp, nInt, flag);
    mask_byte_kernel<<<dim3((unsigned)((nInt+255)/256)),dim3(256),0,stream>>>(maskp, maskb, nInt, flag);
  }

  // ---- weight transposes (fp32 [K,N] -> bf16 [N,K]) ----
  launch_tconv(stream, qkv_w, 1152, 0,0,1, 384,1152, qkvT, 384, 0, 1);
  launch_tconv(stream, proj_w, 384, 0,0,1, 384,384,  projT, 384, 0, 1);
  launch_tconv(stream, fc1_w, 1536, 0,0,1, 384,1536, fc1T, 384, 0, 1);
  launch_tconv(stream, fc2_w, 384,  0,0,1, 1536,384, fc2T, 1536, 0, 1);
  launch_tconv(stream, ada1_w, 96,  0,0,1, 384,96,   ada1T, 384, 0, 1);
  launch_tconv(stream, ada2_w, 384, 0,0,1, 96,384,   ada2T, 96, 0, 1);
  launch_tconv(stream, a1_qkv_w, 1152, 384ll*1152,0,1, 384,1152, a1qkvT, 384, 1152ll*384, 6);
  launch_tconv(stream, a1_proj_w, 384, 384ll*384,0,1, 384,384,  a1projT, 384, 384ll*384, 6);

  // ---- phase 1: transformer block ----
  ln_bf16_kernel<<<8196,128,0,stream>>>(x, norm1_g, norm1_b, bufHh);
  launch_gemm16b(stream, bufHh,384,0, qkvT,384,0, nullptr,0, nullptr,0,0,
                 bufQh,1152,0,1, 8196,1152,384, 0, 1,1);
  launch_tconv16(stream, bufQh + 768, 1152, 2049ll*1152, 64, 6, 2049, 64, Vt_i, 2112, 64ll*2112, 24);
  flash_inner<<<dim3(33,24),256,0,stream>>>(bufQh, Vt_i, bufOh);
  launch_gemm16s(stream, bufOh,384,0, projT,384,0, proj_b,0, x,384,0,
                 bufX,384,0,0, 8196,384,384, 0, 1);
  ln_bf16_kernel<<<8196,128,0,stream>>>(bufX, norm2_g, norm2_b, bufHh);
  launch_gemm16b(stream, bufHh,384,0, fc1T,384,0, fc1_b,0, nullptr,0,0,
                 bufTh,1536,0,1, 8196,1536,384, 1, 1,1);
  launch_gemm16s(stream, bufTh,1536,0, fc2T,1536,0, fc2_b,0, nullptr,0,0,
                 bufO,384,0,0, 8196,384,1536, 0, 1);
  launch_cvt(stream, bufO, bufOh, 8196ll*384);
  launch_gemm16s(stream, bufOh,384,0, ada1T,384,0, ada1_b,0, nullptr,0,0,
                 bufAh,96,0,1, 8196,96,384, 2, 1);
  launch_gemm16s(stream, bufAh,96,0, ada2T,96,0, ada2_b,0, nullptr,0,0,
                 bufAda,384,0,0, 8196,384,96, 0, 1);
  ew_x2_kernel<<<dim3((8196*384+255)/256),256,0,stream>>>(bufX, bufO, bufAda, 8196ll*384);
  copy_cls_kernel<<<6,256,0,stream>>>(bufX, out);
  copy_pts_kernel<<<dim3((8192*384+255)/256),256,0,stream>>>(bufX, ptsb);

  // ---- phase 2: cluster pooling -> cell3 ----
  hipMemsetAsync(cnt, 0, 1024*4, stream);
  hipMemsetAsync(fsum, 0, 1024ll*384*4, stream);
  hipMemsetAsync(fmaxe, 0, 1024ll*384*4, stream);
  scatter_seg_kernel<<<dim3(8192,1),128,0,stream>>>(ptsb, cluster, fsum, fmaxe, cnt, 0,0,0,0);
  cell_kernel<<<dim3(1024,1),128,0,stream>>>(fsum, fmaxe, cnt, bn3_g,bn3_b,bn3_m,bn3_v, cell3, 0,0,0);

  // ---- phase 3a: batched view projections ----
  ln6_kernel<<<8192,128,0,stream>>>(ptsb, norm3_g, norm3_b, bufHh6);
  launch_gemm16b(stream, bufHh6,384,8192ll*384, a1qkvT,384,1152ll*384,
                 nullptr,0, nullptr,0,0, QK6,768,8192ll*768,1, 8192,768,384, 0, 6,1);
  launch_gemm16s(stream, bufHh6,384,8192ll*384, a1qkvT + 768ll*384,384,1152ll*384,
                 nullptr,0, nullptr,0,0, Vt6,2048,4ll*384*2048,2, 8192,384,384, 0, 6);

  // ---- phase 3b: fused flash attention for all 24 (v,b) ----
  flash_view<<<dim3(32,4,6),256,0,stream>>>(QK6, Vt6, maskb, O6);

  // ---- phase 3c: batched proj + grid pooling ----
  launch_gemm16s(stream, O6,384,8192ll*384, a1projT,384,384ll*384,
                 a1_proj_b,384, ptsb,384,0,
                 bufT6,384,8192ll*384,0, 8192,384,384, 0, 6);
  hipMemsetAsync(gc6, 0, 6ll*4096*4, stream);
  hipMemsetAsync(gsum6, 0, 6ll*4096*384*4, stream);
  hipMemsetAsync(gmaxe6, 0, 6ll*4096*384*4, stream);
  scatter_seg_kernel<<<dim3(8192,6),128,0,stream>>>(bufT6, fgi, gsum6, gmaxe6, gc6,
      8192ll*384, 8192, 4096ll*384, 4096);
  cell_kernel<<<dim3(4096,6),128,0,stream>>>(gsum6, gmaxe6, gc6,
      bn2_g, bn2_b, bn2_m, bn2_v, cell2, 4096ll*384, 4096, 384);

  // ---- phase 4: combine ----
  combine_kernel<<<8192,128,0,stream>>>(ptsb, cell3, cluster, cell2, fgi, out);
}

// Round 8
// 1589.188 us; speedup vs baseline: 1.6924x; 1.0373x over previous
//
#include <hip/hip_runtime.h>
#include <math.h>

typedef short bf16x8 __attribute__((ext_vector_type(8)));
typedef float f32x4 __attribute__((ext_vector_type(4)));

#define GLL16(g, l) \
  __builtin_amdgcn_global_load_lds((__attribute__((address_space(1))) const unsigned int*)(g), \
                                   (__attribute__((address_space(3))) unsigned int*)(l), 16, 0, 0)

// ---------- helpers ----------
__device__ __forceinline__ float wsum(float v){
  #pragma unroll
  for (int o=32;o;o>>=1) v += __shfl_xor(v,o);
  return v;
}
__device__ __forceinline__ float geluf(float x){
  return 0.5f*x*(1.0f+erff(x*0.7071067811865475f));
}
__device__ __forceinline__ short fbf(float f){
  unsigned u = __float_as_uint(f);
  unsigned r = (u + 0x7fffu + ((u>>16)&1u)) >> 16;
  return (short)r;
}
__device__ __forceinline__ float bff(short s){
  return __uint_as_float(((unsigned)(unsigned short)s)<<16);
}
__device__ __forceinline__ unsigned fkey(float f){
  unsigned b=__float_as_uint(f);
  return (b&0x80000000u)? ~b : (b|0x80000000u);
}
__device__ __forceinline__ float fdec(unsigned k){
  unsigned b=(k&0x80000000u)? (k&0x7fffffffu) : ~k;
  return __uint_as_float(b);
}

// ---------- mask dtype detection + byte conversion ----------
__global__ void detect_mask_kernel(const int* __restrict__ m, long long n, int* flag){
  long long i = (long long)blockIdx.x*256 + threadIdx.x;
  bool bad = (i<n) && (m[i]!=0 && m[i]!=1);
  if (__any(bad)) { if ((threadIdx.x&63)==0) atomicOr(flag,1); }
}
__global__ void mask_byte_kernel(const void* __restrict__ m, unsigned char* __restrict__ mb,
                                 long long n4, const int* __restrict__ flag){
  long long i = (long long)blockIdx.x*256 + threadIdx.x;
  if (i>=n4) return;
  int mode = *flag;
  uchar4 o;
  if (mode){ o = ((const uchar4*)m)[i]; o.x=o.x!=0; o.y=o.y!=0; o.z=o.z!=0; o.w=o.w!=0; }
  else { int4 v = ((const int4*)m)[i];
         o.x=(unsigned char)(v.x!=0); o.y=(unsigned char)(v.y!=0);
         o.z=(unsigned char)(v.z!=0); o.w=(unsigned char)(v.w!=0); }
  ((uchar4*)mb)[i]=o;
}

__device__ __forceinline__ float epi(float v, const float* bias, int col, int act){
  if (bias) v += bias[col];
  if (act==1) v = geluf(v);
  else if (act==2) v = v*(1.f/(1.f+__expf(-1.702f*v)));
  return v;
}

// ---------- bf16 MFMA GEMM, 128x128 tile ----------
#define XBM 128
#define XBN 128
#define XBK 32
__global__ __launch_bounds__(256)
void gemm_bf16_big(const short* __restrict__ A, int lda, long long sA,
                   const short* __restrict__ B, int ldb, long long sB,
                   const float* __restrict__ bias, long long sBias,
                   const float* __restrict__ res, int ldr, long long sR,
                   void* __restrict__ out, int ldo, long long sO, int outbf16,
                   int M, int N, int K, int act, int KS)
{
  __shared__ short As[XBM*XBK];
  __shared__ short Bs[XBN*XBK];
  int zz = blockIdx.z;
  int z = zz / KS, ks = zz - z*KS;
  A += (long long)z*sA; B += (long long)z*sB;
  if (res) res += (long long)z*sR;
  if (bias) bias += (long long)z*sBias;
  float* outF = (float*)out + (long long)z*sO;
  short* outH = (short*)out + (long long)z*sO;

  int tid = threadIdx.x;
  int rowBase = blockIdx.y*XBM;
  int colBase = blockIdx.x*XBN;

  int Kc = ((K + KS*XBK - 1)/(KS*XBK))*XBK;
  int kbeg = ks*Kc;
  int kend = min(K, kbeg+Kc);
  if (kbeg >= kend) return;

  int w = tid>>6;
  int lane = tid&63;
  int lm = lane&15, quad = lane>>4;
  int waveM = w>>1, waveN = w&1;

  int arow0 = min(rowBase + w*32 + lm,      M-1);
  int arow1 = min(rowBase + w*32 + 16 + lm, M-1);
  int brow0 = min(colBase + w*32 + lm,      N-1);
  int brow1 = min(colBase + w*32 + 16 + lm, N-1);
  const short* Ag0 = A + (long long)arow0*lda + quad*8;
  const short* Ag1 = A + (long long)arow1*lda + quad*8;
  const short* Bg0 = B + (long long)brow0*ldb + quad*8;
  const short* Bg1 = B + (long long)brow1*ldb + quad*8;
  short* Al0 = &As[(w*2+0)*512];
  short* Al1 = &As[(w*2+1)*512];
  short* Bl0 = &Bs[(w*2+0)*512];
  short* Bl1 = &Bs[(w*2+1)*512];

  f32x4 acc[4][4] = {};

  for (int k0=kbeg; k0<kend; k0+=XBK){
    GLL16(Ag0 + k0, Al0);
    GLL16(Ag1 + k0, Al1);
    GLL16(Bg0 + k0, Bl0);
    GLL16(Bg1 + k0, Bl1);
    __syncthreads();
    bf16x8 af[4], bfr[4];
    #pragma unroll
    for (int tm=0;tm<4;tm++) af[tm]  = *(bf16x8*)&As[(waveM*4+tm)*512 + quad*128 + lm*8];
    #pragma unroll
    for (int tn=0;tn<4;tn++) bfr[tn] = *(bf16x8*)&Bs[(waveN*4+tn)*512 + quad*128 + lm*8];
    #pragma unroll
    for (int tm=0;tm<4;tm++)
      #pragma unroll
      for (int tn=0;tn<4;tn++)
        acc[tm][tn] = __builtin_amdgcn_mfma_f32_16x16x32_bf16(af[tm], bfr[tn], acc[tm][tn], 0,0,0);
    __syncthreads();
  }

  #pragma unroll
  for (int tm=0;tm<4;tm++){
    #pragma unroll
    for (int tn=0;tn<4;tn++){
      int col = colBase + waveN*64 + tn*16 + lm;
      if (col>=N) continue;
      #pragma unroll
      for (int reg=0;reg<4;reg++){
        int row = rowBase + waveM*64 + tm*16 + quad*4 + reg;
        if (row>=M) continue;
        float v = acc[tm][tn][reg];
        if (KS>1){ atomicAdd(&outF[(long long)row*ldo+col], v); continue; }
        v = epi(v, bias, col, act);
        if (res) v += res[(long long)row*ldr+col];
        if (outbf16) outH[(long long)row*ldo+col] = fbf(v);
        else         outF[(long long)row*ldo+col] = v;
      }
    }
  }
}

// ---------- bf16 MFMA GEMM, 64x64 tile ----------
// outbf16==2: transposed V store: out + (b*384+col)*2048 + (row&2047), b=row>>11
__global__ __launch_bounds__(256)
void gemm_bf16_s(const short* __restrict__ A, int lda, long long sA,
                 const short* __restrict__ B, int ldb, long long sB,
                 const float* __restrict__ bias, long long sBias,
                 const float* __restrict__ res, int ldr, long long sR,
                 void* __restrict__ out, int ldo, long long sO, int outbf16,
                 int M, int N, int K, int act)
{
  __shared__ short As[64*32];
  __shared__ short Bs[64*32];
  int z = blockIdx.z;
  A += (long long)z*sA; B += (long long)z*sB;
  if (res) res += (long long)z*sR;
  if (bias) bias += (long long)z*sBias;
  float* outF = (float*)out + (long long)z*sO;
  short* outH = (short*)out + (long long)z*sO;

  int tid = threadIdx.x;
  int rowBase = blockIdx.y*64;
  int colBase = blockIdx.x*64;

  int w = tid>>6;
  int lane = tid&63;
  int lm = lane&15, quad = lane>>4;
  int wm = w>>1, wn = w&1;

  int arow = min(rowBase + w*16 + lm, M-1);
  int brow = min(colBase + w*16 + lm, N-1);
  const short* Ag = A + (long long)arow*lda + quad*8;
  const short* Bg = B + (long long)brow*ldb + quad*8;
  short* Al = &As[w*512];
  short* Bl = &Bs[w*512];

  f32x4 acc[2][2] = {};

  for (int k0=0; k0<K; k0+=32){
    GLL16(Ag + k0, Al);
    GLL16(Bg + k0, Bl);
    __syncthreads();
    bf16x8 af[2], bfr[2];
    #pragma unroll
    for (int tm=0;tm<2;tm++) af[tm]  = *(bf16x8*)&As[(wm*2+tm)*512 + quad*128 + lm*8];
    #pragma unroll
    for (int tn=0;tn<2;tn++) bfr[tn] = *(bf16x8*)&Bs[(wn*2+tn)*512 + quad*128 + lm*8];
    #pragma unroll
    for (int tm=0;tm<2;tm++)
      #pragma unroll
      for (int tn=0;tn<2;tn++)
        acc[tm][tn] = __builtin_amdgcn_mfma_f32_16x16x32_bf16(af[tm], bfr[tn], acc[tm][tn], 0,0,0);
    __syncthreads();
  }

  #pragma unroll
  for (int tm=0;tm<2;tm++){
    #pragma unroll
    for (int tn=0;tn<2;tn++){
      int col = colBase + wn*32 + tn*16 + lm;
      if (col>=N) continue;
      #pragma unroll
      for (int reg=0;reg<4;reg++){
        int row = rowBase + wm*32 + tm*16 + quad*4 + reg;
        if (row>=M) continue;
        float v = epi(acc[tm][tn][reg], bias, col, act);
        if (res) v += res[(long long)row*ldr+col];
        if (outbf16==2){
          int bb = row>>11;
          outH[((long long)bb*384 + col)*2048 + (row&2047)] = fbf(v);
        }
        else if (outbf16) outH[(long long)row*ldo+col] = fbf(v);
        else              outF[(long long)row*ldo+col] = v;
      }
    }
  }
}

// ---------- flash-fused view attention v4: 2 barriers/kt, V in regs, P stride 68 ----------
// QK6: [6][8192][768] bf16 (Q 0..384, K 384..768); Vt6: [24][384][2048] bf16
// maskb: [6][2048][2048] u8; O6: [6][8192][384] bf16
// LDS: K 48KB [0,49152) + P [64][68]bf16 [49152,57856) + alpha f32[64] [57856,58112)
__global__ __launch_bounds__(256,2)
void flash_view(const short* __restrict__ QK6, const short* __restrict__ Vt6,
                const unsigned char* __restrict__ maskb, short* __restrict__ O6)
{
  __shared__ char lds[58112];
  const float scale = 0.05103103630798288f;
  int qt=blockIdx.x, b=blockIdx.y, v=blockIdx.z;
  int tid=threadIdx.x, w=tid>>6, lane=tid&63, lm=lane&15, quad=lane>>4;

  const short* Qp = QK6 + ((long long)v*8192 + b*2048 + qt*64)*768;
  const short* Kp = QK6 + ((long long)v*8192 + b*2048)*768 + 384;
  const short* Vp = Vt6 + (long long)(v*4+b)*384*2048;
  const unsigned char* Mp = maskb + (long long)v*2048*2048 + (long long)qt*64*2048;
  short* Op = O6 + ((long long)v*8192 + b*2048 + qt*64)*384;

  short* P = (short*)(lds + 49152);
  float* alphaL = (float*)(lds + 57856);

  // Q A-frags direct global->reg (wave w owns q-rows w*16..w*16+16)
  bf16x8 af[12];
  #pragma unroll
  for (int c=0;c<12;c++)
    af[c] = *(const bf16x8*)(Qp + (long long)(w*16+lm)*768 + c*32 + quad*8);

  float m_i[4], l_i[4];
  #pragma unroll
  for (int r=0;r<4;r++){ m_i[r]=-3.0e38f; l_i[r]=0.f; }
  f32x4 Oacc[4][6] = {};

  for (int kt=0; kt<32; kt++){
    // ---- stage K (64x384): wave w stages rows w*16..+16
    #pragma unroll
    for (int c=0;c<12;c++)
      GLL16(Kp + (long long)(kt*64 + w*16 + lm)*768 + c*32 + quad*8, (short*)(lds + w*12288 + c*1024));
    __syncthreads();  // (a) K visible (vmcnt drained)
    // ---- mask prefetch (independent; covered by S MFMAs)
    unsigned char mreg[4][4];
    #pragma unroll
    for (int ct=0;ct<4;ct++)
      #pragma unroll
      for (int r=0;r<4;r++)
        mreg[ct][r] = Mp[(long long)(w*16+quad*4+r)*2048 + kt*64 + ct*16 + lm];
    // ---- S: Q(16x384) @ K(64x384)^T
    f32x4 S[4];
    #pragma unroll
    for (int i=0;i<4;i++) S[i] = (f32x4){0.f,0.f,0.f,0.f};
    #pragma unroll
    for (int kc=0;kc<12;kc++){
      #pragma unroll
      for (int ct=0;ct<4;ct++){
        bf16x8 bf = *(bf16x8*)(lds + ct*12288 + kc*1024 + quad*256 + lm*16);
        S[ct] = __builtin_amdgcn_mfma_f32_16x16x32_bf16(af[kc], bf, S[ct], 0,0,0);
      }
    }
    // ---- mask + scale
    #pragma unroll
    for (int ct=0;ct<4;ct++){
      #pragma unroll
      for (int r=0;r<4;r++)
        S[ct][r] = mreg[ct][r] ? S[ct][r]*scale : -3.0e38f;
    }
    // ---- online softmax for wave's 16 q-rows
    float alpha[4], mnew[4];
    #pragma unroll
    for (int r=0;r<4;r++){
      float rm = S[0][r];
      #pragma unroll
      for (int ct=1;ct<4;ct++) rm = fmaxf(rm, S[ct][r]);
      #pragma unroll
      for (int o=1;o<16;o<<=1) rm = fmaxf(rm, __shfl_xor(rm, o));
      mnew[r] = fmaxf(m_i[r], rm);
      alpha[r] = __expf(m_i[r]-mnew[r]);
      m_i[r] = mnew[r];
    }
    float rs[4] = {0.f,0.f,0.f,0.f};
    #pragma unroll
    for (int ct=0;ct<4;ct++){
      #pragma unroll
      for (int r=0;r<4;r++){
        float sv = S[ct][r];
        float p = (sv > -1.0e37f) ? __expf(sv - mnew[r]) : 0.f;
        rs[r] += p;
        P[(w*16+quad*4+r)*68 + ct*16 + lm] = fbf(p);
      }
    }
    #pragma unroll
    for (int r=0;r<4;r++){
      #pragma unroll
      for (int o=1;o<16;o<<=1) rs[r] += __shfl_xor(rs[r], o);
      l_i[r] = l_i[r]*alpha[r] + rs[r];
    }
    if (lm==0){
      #pragma unroll
      for (int r=0;r<4;r++) alphaL[w*16+quad*4+r] = alpha[r];
    }
    // ---- V prefetch to regs (latency hidden inside barrier (b) drain/wait)
    bf16x8 Vreg[6][2];
    #pragma unroll
    for (int j=0;j<6;j++)
      #pragma unroll
      for (int kk=0;kk<2;kk++)
        Vreg[j][kk] = *(const bf16x8*)(Vp + (long long)((w*6+j)*16+lm)*2048 + kt*64 + kk*32 + quad*8);
    __syncthreads();  // (b) P/alpha visible; V landed
    // ---- rescale Oacc
    f32x4 am[4];
    #pragma unroll
    for (int m=0;m<4;m++) am[m] = *(f32x4*)&alphaL[m*16 + quad*4];
    #pragma unroll
    for (int m=0;m<4;m++)
      #pragma unroll
      for (int tn=0;tn<6;tn++)
        Oacc[m][tn] *= am[m];
    // ---- PV: P(64x64, LDS) @ V(64x384, regs) — wave's 6 tn for all rows
    #pragma unroll
    for (int kk=0;kk<2;kk++){
      bf16x8 ap[4];
      #pragma unroll
      for (int m=0;m<4;m++) ap[m] = *(bf16x8*)&P[(m*16+lm)*68 + kk*32 + quad*8];
      #pragma unroll
      for (int tn=0;tn<6;tn++){
        #pragma unroll
        for (int m=0;m<4;m++)
          Oacc[m][tn] = __builtin_amdgcn_mfma_f32_16x16x32_bf16(ap[m], Vreg[tn][kk], Oacc[m][tn], 0,0,0);
      }
    }
    // next iteration's (a) protects P/alpha reads; PV never reads K
  }

  __syncthreads();
  if (lm==0){
    #pragma unroll
    for (int r=0;r<4;r++) alphaL[w*16+quad*4+r] = l_i[r];
  }
  __syncthreads();
  f32x4 lv[4];
  #pragma unroll
  for (int m=0;m<4;m++) lv[m] = *(f32x4*)&alphaL[m*16 + quad*4];
  #pragma unroll
  for (int m=0;m<4;m++){
    #pragma unroll
    for (int tn=0;tn<6;tn++){
      #pragma unroll
      for (int reg=0;reg<4;reg++){
        Op[(long long)(m*16+quad*4+reg)*384 + (w*6+tn)*16 + lm] = fbf(Oacc[m][tn][reg] / lv[m][reg]);
      }
    }
  }
}

// ---------- flash-fused inner attention v2: d=64, S=2049, 2 barriers/kt ----------
// QKV = bufQh [4][2049][1152]; Vt = Vt_i [24][64][2112] (V^T, zero-padded)
// O = bufOh [4*2049][384]  (bf16)
// LDS: K 8KB [0,8192) + P [64][68] [8192,16896) + alpha f32[64] [16896,17152)
__global__ __launch_bounds__(256,4)
void flash_inner(const short* __restrict__ QKV, const short* __restrict__ Vt,
                 short* __restrict__ O)
{
  __shared__ char lds[17152];
  int qt=blockIdx.x;            // 0..32
  int bh=blockIdx.y;            // 0..23
  int b=bh/6, h=bh-b*6;
  int tid=threadIdx.x, w=tid>>6, lane=tid&63, lm=lane&15, quad=lane>>4;

  const short* Qb = QKV + (long long)b*2049*1152 + h*64;
  const short* Kb = Qb + 384;
  const short* Vtp = Vt + (long long)bh*64*2112;
  short* Op = O + ((long long)b*2049 + qt*64)*384 + h*64;

  short* P = (short*)(lds + 8192);
  float* alphaL = (float*)(lds + 16896);

  int qr = min(qt*64 + w*16 + lm, 2048);
  bf16x8 af[2];
  #pragma unroll
  for (int c=0;c<2;c++)
    af[c] = *(const bf16x8*)(Qb + (long long)qr*1152 + c*32 + quad*8);

  float m_i[4], l_i[4];
  #pragma unroll
  for (int r=0;r<4;r++){ m_i[r]=-3.0e38f; l_i[r]=0.f; }
  f32x4 Oacc[4] = {};

  for (int kt=0; kt<33; kt++){
    int kr = min(kt*64 + w*16 + lm, 2048);
    #pragma unroll
    for (int c=0;c<2;c++)
      GLL16(Kb + (long long)kr*1152 + c*32 + quad*8, (short*)(lds + w*2048 + c*1024));
    __syncthreads();  // (a)
    f32x4 S[4];
    #pragma unroll
    for (int i=0;i<4;i++) S[i] = (f32x4){0.f,0.f,0.f,0.f};
    #pragma unroll
    for (int kc=0;kc<2;kc++){
      #pragma unroll
      for (int ct=0;ct<4;ct++){
        bf16x8 bf = *(bf16x8*)(lds + ct*2048 + kc*1024 + quad*256 + lm*16);
        S[ct] = __builtin_amdgcn_mfma_f32_16x16x32_bf16(af[kc], bf, S[ct], 0,0,0);
      }
    }
    #pragma unroll
    for (int ct=0;ct<4;ct++){
      int scol = kt*64 + ct*16 + lm;
      bool ok = scol <= 2048;
      #pragma unroll
      for (int r=0;r<4;r++) S[ct][r] = ok ? S[ct][r]*0.125f : -3.0e38f;
    }
    float alpha[4], mnew[4];
    #pragma unroll
    for (int r=0;r<4;r++){
      float rm = S[0][r];
      #pragma unroll
      for (int ct=1;ct<4;ct++) rm = fmaxf(rm, S[ct][r]);
      #pragma unroll
      for (int o=1;o<16;o<<=1) rm = fmaxf(rm, __shfl_xor(rm, o));
      mnew[r] = fmaxf(m_i[r], rm);
      alpha[r] = __expf(m_i[r]-mnew[r]);
      m_i[r] = mnew[r];
    }
    float rs[4] = {0.f,0.f,0.f,0.f};
    #pragma unroll
    for (int ct=0;ct<4;ct++){
      #pragma unroll
      for (int r=0;r<4;r++){
        float sv = S[ct][r];
        float p = (sv > -1.0e37f) ? __expf(sv - mnew[r]) : 0.f;
        rs[r] += p;
        P[(w*16+quad*4+r)*68 + ct*16 + lm] = fbf(p);
      }
    }
    #pragma unroll
    for (int r=0;r<4;r++){
      #pragma unroll
      for (int o=1;o<16;o<<=1) rs[r] += __shfl_xor(rs[r], o);
      l_i[r] = l_i[r]*alpha[r] + rs[r];
    }
    if (lm==0){
      #pragma unroll
      for (int r=0;r<4;r++) alphaL[w*16+quad*4+r] = alpha[r];
    }
    // V prefetch (wave's own d-slice tn=w)
    bf16x8 Vreg[2];
    #pragma unroll
    for (int kk=0;kk<2;kk++)
      Vreg[kk] = *(const bf16x8*)(Vtp + (long long)(w*16+lm)*2112 + kt*64 + kk*32 + quad*8);
    __syncthreads();  // (b)
    f32x4 am[4];
    #pragma unroll
    for (int m=0;m<4;m++) am[m] = *(f32x4*)&alphaL[m*16 + quad*4];
    #pragma unroll
    for (int m=0;m<4;m++) Oacc[m] *= am[m];
    #pragma unroll
    for (int kk=0;kk<2;kk++){
      bf16x8 ap[4];
      #pragma unroll
      for (int m=0;m<4;m++) ap[m] = *(bf16x8*)&P[(m*16+lm)*68 + kk*32 + quad*8];
      #pragma unroll
      for (int m=0;m<4;m++)
        Oacc[m] = __builtin_amdgcn_mfma_f32_16x16x32_bf16(ap[m], Vreg[kk], Oacc[m], 0,0,0);
    }
  }

  __syncthreads();
  if (lm==0){
    #pragma unroll
    for (int r=0;r<4;r++) alphaL[w*16+quad*4+r] = l_i[r];
  }
  __syncthreads();
  f32x4 lv[4];
  #pragma unroll
  for (int m=0;m<4;m++) lv[m] = *(f32x4*)&alphaL[m*16 + quad*4];
  #pragma unroll
  for (int m=0;m<4;m++){
    #pragma unroll
    for (int reg=0;reg<4;reg++){
      int row = qt*64 + m*16 + quad*4 + reg;
      if (row < 2049)
        Op[(long long)(m*16+quad*4+reg)*384 + w*16 + lm] = fbf(Oacc[m][reg] / lv[m][reg]);
    }
  }
}

// ---------- LayerNorm (fp32 in -> bf16 out), C=384 ----------
__global__ __launch_bounds__(128)
void ln_bf16_kernel(const float* __restrict__ in, const float* __restrict__ g,
                    const float* __restrict__ bt, short* __restrict__ out)
{
  long long row = blockIdx.x;
  const float* p = in + row*384;
  int tid = threadIdx.x;
  float v0=p[tid], v1=p[tid+128], v2=p[tid+256];
  float s = v0+v1+v2;
  float ss = v0*v0+v1*v1+v2*v2;
  __shared__ float r1[2], r2[2];
  s = wsum(s); ss = wsum(ss);
  int wid=tid>>6, lane=tid&63;
  if (lane==0){ r1[wid]=s; r2[wid]=ss; }
  __syncthreads();
  float mean=(r1[0]+r1[1])*(1.f/384.f);
  float var =(r2[0]+r2[1])*(1.f/384.f)-mean*mean;
  float rstd=rsqrtf(var+1e-5f);
  short* o = out + row*384;
  o[tid]     = fbf((v0-mean)*rstd*g[tid]+bt[tid]);
  o[tid+128] = fbf((v1-mean)*rstd*g[tid+128]+bt[tid+128]);
  o[tid+256] = fbf((v2-mean)*rstd*g[tid+256]+bt[tid+256]);
}

// ---------- LN once, write 6 per-view normed copies ----------
__global__ __launch_bounds__(128)
void ln6_kernel(const float* __restrict__ in, const float* __restrict__ g6,
                const float* __restrict__ b6, short* __restrict__ out6)
{
  long long row = blockIdx.x;
  const float* p = in + row*384;
  int tid = threadIdx.x;
  float v0=p[tid], v1=p[tid+128], v2=p[tid+256];
  float s = v0+v1+v2;
  float ss = v0*v0+v1*v1+v2*v2;
  __shared__ float r1[2], r2[2];
  s = wsum(s); ss = wsum(ss);
  int wid=tid>>6, lane=tid&63;
  if (lane==0){ r1[wid]=s; r2[wid]=ss; }
  __syncthreads();
  float mean=(r1[0]+r1[1])*(1.f/384.f);
  float var =(r2[0]+r2[1])*(1.f/384.f)-mean*mean;
  float rstd=rsqrtf(var+1e-5f);
  float n0=(v0-mean)*rstd, n1=(v1-mean)*rstd, n2=(v2-mean)*rstd;
  #pragma unroll
  for (int i=0;i<6;i++){
    const float* g = g6 + i*384;
    const float* bt = b6 + i*384;
    short* o = out6 + (long long)i*8192*384 + row*384;
    o[tid]     = fbf(n0*g[tid]+bt[tid]);
    o[tid+128] = fbf(n1*g[tid+128]+bt[tid+128]);
    o[tid+256] = fbf(n2*g[tid+256]+bt[tid+256]);
  }
}

// ---------- fp32 -> bf16 convert ----------
__global__ void cvt_kernel(const float* __restrict__ in, short* __restrict__ out, long long n4){
  long long i = (long long)blockIdx.x*256 + threadIdx.x;
  if (i<n4){
    float4 f = ((const float4*)in)[i];
    short4 s;
    s.x=fbf(f.x); s.y=fbf(f.y); s.z=fbf(f.z); s.w=fbf(f.w);
    ((short4*)out)[i]=s;
  }
}

// ---------- tiled transpose+convert: fp32 [R,C] -> bf16 [C, ldout] ----------
__global__ __launch_bounds__(256)
void tconv_kernel(const float* __restrict__ in, int ldin, long long sIn, long long sIn2, int zmod,
                  int R, int C, short* __restrict__ out, int ldout, long long sOut)
{
  __shared__ float tile[32][33];
  int z = blockIdx.z;
  const float* ip = in + (long long)(z/zmod)*sIn + (long long)(z%zmod)*sIn2;
  short* op = out + (long long)z*sOut;
  int r0 = blockIdx.x*32;
  int c0 = blockIdx.y*32;
  int tx = threadIdx.x&31, ty = threadIdx.x>>5;
  #pragma unroll
  for (int i=0;i<4;i++){
    int r = r0 + ty + i*8, c = c0 + tx;
    tile[ty+i*8][tx] = (r<R && c<C) ? ip[(long long)r*ldin + c] : 0.f;
  }
  __syncthreads();
  #pragma unroll
  for (int i=0;i<4;i++){
    int oc = c0 + ty + i*8;
    int orr = r0 + tx;
    if (oc<C && orr<ldout) op[(long long)oc*ldout + orr] = fbf(tile[tx][ty+i*8]);
  }
}

// ---------- tiled transpose: bf16 [R,C] -> bf16 [C, ldout] ----------
__global__ __launch_bounds__(256)
void tconv16_kernel(const short* __restrict__ in, int ldin, long long sIn, long long sIn2, int zmod,
                    int R, int C, short* __restrict__ out, int ldout, long long sOut)
{
  __shared__ short tile[32][34];
  int z = blockIdx.z;
  const short* ip = in + (long long)(z/zmod)*sIn + (long long)(z%zmod)*sIn2;
  short* op = out + (long long)z*sOut;
  int r0 = blockIdx.x*32;
  int c0 = blockIdx.y*32;
  int tx = threadIdx.x&31, ty = threadIdx.x>>5;
  #pragma unroll
  for (int i=0;i<4;i++){
    int r = r0 + ty + i*8, c = c0 + tx;
    tile[ty+i*8][tx] = (r<R && c<C) ? ip[(long long)r*ldin + c] : (short)0;
  }
  __syncthreads();
  #pragma unroll
  for (int i=0;i<4;i++){
    int oc = c0 + ty + i*8;
    int orr = r0 + tx;
    if (oc<C && orr<ldout) op[(long long)oc*ldout + orr] = tile[tx][ty+i*8];
  }
}

// ---------- elementwise ----------
__global__ void ew_x2_kernel(float* x1, const float* ffn, const float* ada, long long n){
  long long i=(long long)blockIdx.x*256+threadIdx.x;
  if (i<n) x1[i] = x1[i] + ffn[i] + 0.5f*ada[i];
}
__global__ void copy_pts_kernel(const float* __restrict__ x2, float* __restrict__ pts){
  long long i=(long long)blockIdx.x*256+threadIdx.x;
  if (i < 8192ll*384){
    long long b = i/(2048ll*384);
    long long rem = i%(2048ll*384);
    pts[i] = x2[(b*2049+1)*384 + rem];
  }
}
__global__ void copy_cls_kernel(const float* __restrict__ x2, float* __restrict__ out){
  int i = blockIdx.x*256+threadIdx.x;
  if (i < 4*384){
    int b=i/384, c=i%384;
    out[(long long)b*2049*384 + c] = x2[(long long)b*2049*384 + c];
  }
}

// ---------- segment scatter (z-batched) ----------
__global__ __launch_bounds__(128)
void scatter_seg_kernel(const float* __restrict__ feat, const int* __restrict__ seg,
                        float* __restrict__ fsum, unsigned* __restrict__ fmax,
                        float* __restrict__ cnt,
                        long long zFeat, long long zSeg, long long zSum, long long zCnt)
{
  int n = blockIdx.x, z = blockIdx.y;
  feat += (long long)z*zFeat; seg += (long long)z*zSeg;
  fsum += (long long)z*zSum; fmax += (long long)z*zSum; cnt += (long long)z*zCnt;
  int s = seg[n];
  const float* p = feat + (long long)n*384;
  int tid = threadIdx.x;
  #pragma unroll
  for (int k=0;k<3;k++){
    int c = tid + k*128;
    float v = p[c];
    atomicAdd(&fsum[(long long)s*384+c], v);
    atomicMax(&fmax[(long long)s*384+c], fkey(v));
  }
  if (tid==0) atomicAdd(&cnt[s], 1.0f);
}

// ---------- cell = bn_gelu(max + mean), z-batched ----------
__global__ __launch_bounds__(128)
void cell_kernel(const float* __restrict__ fsum, const unsigned* __restrict__ fmax,
                 const float* __restrict__ cnt,
                 const float* __restrict__ g, const float* __restrict__ bb,
                 const float* __restrict__ m, const float* __restrict__ v,
                 float* __restrict__ out, long long zSum, long long zCnt, long long zP)
{
  int s = blockIdx.x, z = blockIdx.y;
  fsum += (long long)z*zSum; fmax += (long long)z*zSum; cnt += (long long)z*zCnt;
  g += (long long)z*zP; bb += (long long)z*zP; m += (long long)z*zP; v += (long long)z*zP;
  out += (long long)z*zSum;
  float cn = cnt[s];
  float denom = fmaxf(cn, 1.f);
  int tid = threadIdx.x;
  #pragma unroll
  for (int k=0;k<3;k++){
    int c = tid + k*128;
    float mx = (cn>0.f) ? fdec(fmax[(long long)s*384+c]) : 0.f;
    float t = mx + fsum[(long long)s*384+c]/denom;
    t = (t - m[c])*rsqrtf(v[c]+1e-5f)*g[c] + bb[c];
    out[(long long)s*384+c] = geluf(t);
  }
}

// ---------- final cosine-sim weighted combine ----------
__global__ __launch_bounds__(128)
void combine_kernel(const float* __restrict__ pts, const float* __restrict__ cell3,
                    const int* __restrict__ cluster, const float* __restrict__ cell2,
                    const int* __restrict__ gidx, float* __restrict__ out)
{
  int n = blockIdx.x;
  int tid = threadIdx.x;
  __shared__ float sdot[6], ssq[6], sw[6];
  __shared__ int soff[6];
  __shared__ float red[2][2];
  __shared__ float sn3;
  const float* x3 = cell3 + (long long)cluster[n]*384;
  int wid=tid>>6, lane=tid&63;
  float sq=0.f;
  for (int c=tid;c<384;c+=128){ float v=x3[c]; sq+=v*v; }
  sq = wsum(sq);
  if (lane==0) red[0][wid]=sq;
  __syncthreads();
  if (tid==0) sn3 = sqrtf(red[0][0]+red[0][1]);
  __syncthreads();
  for (int i=0;i<6;i++){
    int gi = gidx[(long long)i*8192 + n];
    if (tid==0) soff[i]=gi;
    const float* r = cell2 + ((long long)i*4096 + gi)*384;
    float d=0.f, s2=0.f;
    for (int c=tid;c<384;c+=128){ float a=r[c]; d+=a*x3[c]; s2+=a*a; }
    d = wsum(d); s2 = wsum(s2);
    if (lane==0){ red[0][wid]=d; red[1][wid]=s2; }
    __syncthreads();
    if (tid==0){ sdot[i]=red[0][0]+red[0][1]; ssq[i]=red[1][0]+red[1][1]; }
    __syncthreads();
  }
  if (tid==0){
    float ssumv=0.f; float sims[6];
    for (int i=0;i<6;i++){
      float nrm = sqrtf(ssq[i])*sn3;
      float s = (sdot[i]/fmaxf(nrm,1e-8f) + 1.f)*0.5f;
      sims[i]=s; ssumv+=s;
    }
    for (int i=0;i<6;i++) sw[i]=sims[i]/ssumv;
  }
  __syncthreads();
  int b = n>>11, gp = n&2047;
  float* o = out + ((long long)(b*2049 + 1 + gp))*384;
  for (int c=tid;c<384;c+=128){
    float acc=0.f;
    #pragma unroll
    for (int i=0;i<6;i++){
      const float* r = cell2 + ((long long)i*4096 + soff[i])*384;
      acc += sw[i]*r[c];
    }
    o[c] = pts[(long long)n*384+c] + 0.5f*acc;
  }
}

// ---------- host helpers ----------
static inline void launch_gemm16b(hipStream_t s, const short* A,int lda,long long sA,
  const short* B,int ldb,long long sB, const float* bias, long long sBias,
  const float* res,int ldr,long long sR, void* out,int ldo,long long sO,int outbf16,
  int M,int N,int K,int act,int nz,int KS)
{
  dim3 g((N+XBN-1)/XBN,(M+XBM-1)/XBM,(unsigned)(nz*KS));
  hipLaunchKernelGGL(gemm_bf16_big,g,dim3(256),0,s,
    A,lda,sA,B,ldb,sB,bias,sBias,res,ldr,sR,out,ldo,sO,outbf16,M,N,K,act,KS);
}
static inline void launch_gemm16s(hipStream_t s, const short* A,int lda,long long sA,
  const short* B,int ldb,long long sB, const float* bias, long long sBias,
  const float* res,int ldr,long long sR, void* out,int ldo,long long sO,int outbf16,
  int M,int N,int K,int act,int nz)
{
  dim3 g((N+63)/64,(M+63)/64,(unsigned)nz);
  hipLaunchKernelGGL(gemm_bf16_s,g,dim3(256),0,s,
    A,lda,sA,B,ldb,sB,bias,sBias,res,ldr,sR,out,ldo,sO,outbf16,M,N,K,act);
}
static inline void launch_tconv(hipStream_t s, const float* in,int ldin,long long sIn,long long sIn2,int zmod,
  int R,int C, short* out,int ldout,long long sOut,int nz)
{
  dim3 g((ldout+31)/32,(C+31)/32,(unsigned)nz);
  hipLaunchKernelGGL(tconv_kernel,g,dim3(256),0,s, in,ldin,sIn,sIn2,zmod,R,C,out,ldout,sOut);
}
static inline void launch_tconv16(hipStream_t s, const short* in,int ldin,long long sIn,long long sIn2,int zmod,
  int R,int C, short* out,int ldout,long long sOut,int nz)
{
  dim3 g((ldout+31)/32,(C+31)/32,(unsigned)nz);
  hipLaunchKernelGGL(tconv16_kernel,g,dim3(256),0,s, in,ldin,sIn,sIn2,zmod,R,C,out,ldout,sOut);
}
static inline void launch_cvt(hipStream_t s, const float* in, short* out, long long n){
  long long n4 = n/4;
  hipLaunchKernelGGL(cvt_kernel,dim3((unsigned)((n4+255)/256)),dim3(256),0,s,in,out,n4);
}

extern "C" void kernel_launch(void* const* d_in, const int* in_sizes, int n_in,
                              void* d_out, int out_size, void* d_ws, size_t ws_size,
                              hipStream_t stream)
{
  const float* x       = (const float*)d_in[0];
  const float* norm1_g = (const float*)d_in[2];
  const float* norm1_b = (const float*)d_in[3];
  const float* qkv_w   = (const float*)d_in[4];
  const float* proj_w  = (const float*)d_in[5];
  const float* proj_b  = (const float*)d_in[6];
  const float* norm2_g = (const float*)d_in[7];
  const float* norm2_b = (const float*)d_in[8];
  const float* fc1_w   = (const float*)d_in[9];
  const float* fc1_b   = (const float*)d_in[10];
  const float* fc2_w   = (const float*)d_in[11];
  const float* fc2_b   = (const float*)d_in[12];
  const float* ada1_w  = (const float*)d_in[13];
  const float* ada1_b  = (const float*)d_in[14];
  const float* ada2_w  = (const float*)d_in[15];
  const float* ada2_b  = (const float*)d_in[16];
  const float* bn3_g   = (const float*)d_in[17];
  const float* bn3_b   = (const float*)d_in[18];
  const float* bn3_m   = (const float*)d_in[19];
  const float* bn3_v   = (const float*)d_in[20];
  const float* bn2_g   = (const float*)d_in[21];
  const float* bn2_b   = (const float*)d_in[22];
  const float* bn2_m   = (const float*)d_in[23];
  const float* bn2_v   = (const float*)d_in[24];
  const float* norm3_g = (const float*)d_in[25];
  const float* norm3_b = (const float*)d_in[26];
  const float* a1_qkv_w  = (const float*)d_in[27];
  const float* a1_proj_w = (const float*)d_in[28];
  const float* a1_proj_b = (const float*)d_in[29];
  const void*  maskp     = d_in[30];
  const int*   cluster   = (const int*)d_in[33];
  const int*   fgi       = (const int*)d_in[34];
  float* out = (float*)d_out;

  // ---- workspace ----
  size_t off = 0;
  char* wsb = (char*)d_ws;
  auto alloc = [&](size_t bytes)->void*{
    void* p = wsb + off;
    off += (bytes + 255) & ~(size_t)255;
    return p;
  };
  // persistent
  short*    bufHh = (short*)alloc(8196ll*384*2);
  float*    ptsb  = (float*)alloc(8192ll*384*4);
  float*    cnt   = (float*)alloc(1024*4);
  float*    fsum  = (float*)alloc(1024ll*384*4);
  unsigned* fmaxe = (unsigned*)alloc(1024ll*384*4);
  float*    cell3 = (float*)alloc(1024ll*384*4);
  unsigned char* maskb = (unsigned char*)alloc(6ll*2048*2048);
  float*    gc6   = (float*)alloc(6ll*4096*4);
  short*    qkvT  = (short*)alloc(1152ll*384*2);
  short*    projT = (short*)alloc(384ll*384*2);
  short*    fc1T  = (short*)alloc(1536ll*384*2);
  short*    fc2T  = (short*)alloc(384ll*1536*2);
  short*    ada1T = (short*)alloc(96ll*384*2);
  short*    ada2T = (short*)alloc(384ll*96*2);
  short*    a1qkvT  = (short*)alloc(6ll*1152*384*2);
  short*    a1projT = (short*)alloc(6ll*384*384*2);
  int*      flag  = (int*)alloc(256);
  // arena: A0 [0,75.5M) + A1 [75.5M,151M) + A2 [151M,188.75M)
  char* arena = (char*)alloc(188743680);
  char* A0 = arena;
  char* A1 = arena + 75497472;
  char* A2 = arena + 150994944;
  // phase-1 overlay
  short* bufQh = (short*)(A0 + 0);            // 8196x1152 bf16 (18.9M)
  float* bufO  = (float*)(A0 + 20971520);     // 8196x384 f32 (12.6M)
  short* bufOh = (short*)(A0 + 35651584);     // 8196x384 bf16 (6.3M)
  short* bufAh = (short*)(A0 + 44040192);     // 8196x96 bf16
  float* bufX  = (float*)(A0 + 46137344);     // 8196x384 f32
  float* bufAda= (float*)(A0 + 0);            // ada2 out (aliases bufQh after qkv dead)
  short* Vt_i  = (short*)(A1 + 0);            // 24x64x2112 bf16 (6.5M)
  short* bufTh = (short*)(A1 + 8388608);      // fc1 out 8196x1536 bf16 (25.2M; Vt_i dead by then)
  // view-phase overlay
  short* QK6   = (short*)(A0 + 0);            // 6x8192x768 bf16 (75.5M)
  short* Vt6   = (short*)(A1 + 0);            // 24x384x2048 bf16 (37.7M)
  short* O6    = (short*)(A2 + 0);            // 6x8192x384 bf16 (37.7M)
  short* bufHh6= (short*)(A2 + 0);            // ln6 out (aliases O6; dead before flash)
  // post-flash overlay
  float* bufT6 = (float*)(A0 + 0);            // 6x8192x384 f32 (75.5M, aliases QK6)
  float* gsum6 = (float*)(A1 + 0);            // 6x4096x384 f32 (37.7M)
  unsigned* gmaxe6 = (unsigned*)(A1 + 37748736); // 6x4096x384 u32
  float* cell2 = (float*)(A0 + 0);            // 6x4096x384 f32 (written after bufT6 dead)

  // ---- mask detect + byte conversion ----
  hipMemsetAsync(flag, 0, 4, stream);
  {
    long long nInt = 6ll*2048*2048/4;
    detect_mask_kernel<<<dim3((unsigned)((nInt+255)/256)),dim3(256),0,stream>>>((const int*)maskp, nInt, flag);
    mask_byte_kernel<<<dim3((unsigned)((nInt+255)/256)),dim3(256),0,stream>>>(maskp, maskb, nInt, flag);
  }

  // ---- weight transposes (fp32 [K,N] -> bf16 [N,K]) ----
  launch_tconv(stream, qkv_w, 1152, 0,0,1, 384,1152, qkvT, 384, 0, 1);
  launch_tconv(stream, proj_w, 384, 0,0,1, 384,384,  projT, 384, 0, 1);
  launch_tconv(stream, fc1_w, 1536, 0,0,1, 384,1536, fc1T, 384, 0, 1);
  launch_tconv(stream, fc2_w, 384,  0,0,1, 1536,384, fc2T, 1536, 0, 1);
  launch_tconv(stream, ada1_w, 96,  0,0,1, 384,96,   ada1T, 384, 0, 1);
  launch_tconv(stream, ada2_w, 384, 0,0,1, 96,384,   ada2T, 96, 0, 1);
  launch_tconv(stream, a1_qkv_w, 1152, 384ll*1152,0,1, 384,1152, a1qkvT, 384, 1152ll*384, 6);
  launch_tconv(stream, a1_proj_w, 384, 384ll*384,0,1, 384,384,  a1projT, 384, 384ll*384, 6);

  // ---- phase 1: transformer block ----
  ln_bf16_kernel<<<8196,128,0,stream>>>(x, norm1_g, norm1_b, bufHh);
  launch_gemm16b(stream, bufHh,384,0, qkvT,384,0, nullptr,0, nullptr,0,0,
                 bufQh,1152,0,1, 8196,1152,384, 0, 1,1);
  launch_tconv16(stream, bufQh + 768, 1152, 2049ll*1152, 64, 6, 2049, 64, Vt_i, 2112, 64ll*2112, 24);
  flash_inner<<<dim3(33,24),256,0,stream>>>(bufQh, Vt_i, bufOh);
  launch_gemm16s(stream, bufOh,384,0, projT,384,0, proj_b,0, x,384,0,
                 bufX,384,0,0, 8196,384,384, 0, 1);
  ln_bf16_kernel<<<8196,128,0,stream>>>(bufX, norm2_g, norm2_b, bufHh);
  launch_gemm16b(stream, bufHh,384,0, fc1T,384,0, fc1_b,0, nullptr,0,0,
                 bufTh,1536,0,1, 8196,1536,384, 1, 1,1);
  launch_gemm16s(stream, bufTh,1536,0, fc2T,1536,0, fc2_b,0, nullptr,0,0,
                 bufO,384,0,0, 8196,384,1536, 0, 1);
  launch_cvt(stream, bufO, bufOh, 8196ll*384);
  launch_gemm16s(stream, bufOh,384,0, ada1T,384,0, ada1_b,0, nullptr,0,0,
                 bufAh,96,0,1, 8196,96,384, 2, 1);
  launch_gemm16s(stream, bufAh,96,0, ada2T,96,0, ada2_b,0, nullptr,0,0,
                 bufAda,384,0,0, 8196,384,96, 0, 1);
  ew_x2_kernel<<<dim3((8196*384+255)/256),256,0,stream>>>(bufX, bufO, bufAda, 8196ll*384);
  copy_cls_kernel<<<6,256,0,stream>>>(bufX, out);
  copy_pts_kernel<<<dim3((8192*384+255)/256),256,0,stream>>>(bufX, ptsb);

  // ---- phase 2: cluster pooling -> cell3 ----
  hipMemsetAsync(cnt, 0, 1024*4, stream);
  hipMemsetAsync(fsum, 0, 1024ll*384*4, stream);
  hipMemsetAsync(fmaxe, 0, 1024ll*384*4, stream);
  scatter_seg_kernel<<<dim3(8192,1),128,0,stream>>>(ptsb, cluster, fsum, fmaxe, cnt, 0,0,0,0);
  cell_kernel<<<dim3(1024,1),128,0,stream>>>(fsum, fmaxe, cnt, bn3_g,bn3_b,bn3_m,bn3_v, cell3, 0,0,0);

  // ---- phase 3a: batched view projections ----
  ln6_kernel<<<8192,128,0,stream>>>(ptsb, norm3_g, norm3_b, bufHh6);
  launch_gemm16b(stream, bufHh6,384,8192ll*384, a1qkvT,384,1152ll*384,
                 nullptr,0, nullptr,0,0, QK6,768,8192ll*768,1, 8192,768,384, 0, 6,1);
  launch_gemm16s(stream, bufHh6,384,8192ll*384, a1qkvT + 768ll*384,384,1152ll*384,
                 nullptr,0, nullptr,0,0, Vt6,2048,4ll*384*2048,2, 8192,384,384, 0, 6);

  // ---- phase 3b: fused flash attention for all 24 (v,b) ----
  flash_view<<<dim3(32,4,6),256,0,stream>>>(QK6, Vt6, maskb, O6);

  // ---- phase 3c: batched proj + grid pooling ----
  launch_gemm16s(stream, O6,384,8192ll*384, a1projT,384,384ll*384,
                 a1_proj_b,384, ptsb,384,0,
                 bufT6,384,8192ll*384,0, 8192,384,384, 0, 6);
  hipMemsetAsync(gc6, 0, 6ll*4096*4, stream);
  hipMemsetAsync(gsum6, 0, 6ll*4096*384*4, stream);
  hipMemsetAsync(gmaxe6, 0, 6ll*4096*384*4, stream);
  scatter_seg_kernel<<<dim3(8192,6),128,0,stream>>>(bufT6, fgi, gsum6, gmaxe6, gc6,
      8192ll*384, 8192, 4096ll*384, 4096);
  cell_kernel<<<dim3(4096,6),128,0,stream>>>(gsum6, gmaxe6, gc6,
      bn2_g, bn2_b, bn2_m, bn2_v, cell2, 4096ll*384, 4096, 384);

  // ---- phase 4: combine ----
  combine_kernel<<<8192,128,0,stream>>>(ptsb, cell3, cluster, cell2, fgi, out);
}

// Round 9
// 1578.523 us; speedup vs baseline: 1.7038x; 1.0068x over previous
//
#include <hip/hip_runtime.h>
#include <math.h>

typedef short bf16x8 __attribute__((ext_vector_type(8)));
typedef float f32x4 __attribute__((ext_vector_type(4)));

#define GLL16(g, l) \
  __builtin_amdgcn_global_load_lds((__attribute__((address_space(1))) const unsigned int*)(g), \
                                   (__attribute__((address_space(3))) unsigned int*)(l), 16, 0, 0)

// ---------- helpers ----------
__device__ __forceinline__ float wsum(float v){
  #pragma unroll
  for (int o=32;o;o>>=1) v += __shfl_xor(v,o);
  return v;
}
__device__ __forceinline__ float geluf(float x){
  return 0.5f*x*(1.0f+erff(x*0.7071067811865475f));
}
__device__ __forceinline__ short fbf(float f){
  unsigned u = __float_as_uint(f);
  unsigned r = (u + 0x7fffu + ((u>>16)&1u)) >> 16;
  return (short)r;
}
__device__ __forceinline__ float bff(short s){
  return __uint_as_float(((unsigned)(unsigned short)s)<<16);
}
__device__ __forceinline__ unsigned fkey(float f){
  unsigned b=__float_as_uint(f);
  return (b&0x80000000u)? ~b : (b|0x80000000u);
}
__device__ __forceinline__ float fdec(unsigned k){
  unsigned b=(k&0x80000000u)? (k&0x7fffffffu) : ~k;
  return __uint_as_float(b);
}

// ---------- mask dtype detection + byte conversion ----------
__global__ void detect_mask_kernel(const int* __restrict__ m, long long n, int* flag){
  long long i = (long long)blockIdx.x*256 + threadIdx.x;
  bool bad = (i<n) && (m[i]!=0 && m[i]!=1);
  if (__any(bad)) { if ((threadIdx.x&63)==0) atomicOr(flag,1); }
}
__global__ void mask_byte_kernel(const void* __restrict__ m, unsigned char* __restrict__ mb,
                                 long long n4, const int* __restrict__ flag){
  long long i = (long long)blockIdx.x*256 + threadIdx.x;
  if (i>=n4) return;
  int mode = *flag;
  uchar4 o;
  if (mode){ o = ((const uchar4*)m)[i]; o.x=o.x!=0; o.y=o.y!=0; o.z=o.z!=0; o.w=o.w!=0; }
  else { int4 v = ((const int4*)m)[i];
         o.x=(unsigned char)(v.x!=0); o.y=(unsigned char)(v.y!=0);
         o.z=(unsigned char)(v.z!=0); o.w=(unsigned char)(v.w!=0); }
  ((uchar4*)mb)[i]=o;
}

__device__ __forceinline__ float epi(float v, const float* bias, int col, int act){
  if (bias) v += bias[col];
  if (act==1) v = geluf(v);
  else if (act==2) v = v*(1.f/(1.f+__expf(-1.702f*v)));
  return v;
}

// ---------- bf16 MFMA GEMM, 128x128 tile ----------
#define XBM 128
#define XBN 128
#define XBK 32
__global__ __launch_bounds__(256)
void gemm_bf16_big(const short* __restrict__ A, int lda, long long sA,
                   const short* __restrict__ B, int ldb, long long sB,
                   const float* __restrict__ bias, long long sBias,
                   const float* __restrict__ res, int ldr, long long sR,
                   void* __restrict__ out, int ldo, long long sO, int outbf16,
                   int M, int N, int K, int act, int KS)
{
  __shared__ short As[XBM*XBK];
  __shared__ short Bs[XBN*XBK];
  int zz = blockIdx.z;
  int z = zz / KS, ks = zz - z*KS;
  A += (long long)z*sA; B += (long long)z*sB;
  if (res) res += (long long)z*sR;
  if (bias) bias += (long long)z*sBias;
  float* outF = (float*)out + (long long)z*sO;
  short* outH = (short*)out + (long long)z*sO;

  int tid = threadIdx.x;
  int rowBase = blockIdx.y*XBM;
  int colBase = blockIdx.x*XBN;

  int Kc = ((K + KS*XBK - 1)/(KS*XBK))*XBK;
  int kbeg = ks*Kc;
  int kend = min(K, kbeg+Kc);
  if (kbeg >= kend) return;

  int w = tid>>6;
  int lane = tid&63;
  int lm = lane&15, quad = lane>>4;
  int waveM = w>>1, waveN = w&1;

  int arow0 = min(rowBase + w*32 + lm,      M-1);
  int arow1 = min(rowBase + w*32 + 16 + lm, M-1);
  int brow0 = min(colBase + w*32 + lm,      N-1);
  int brow1 = min(colBase + w*32 + 16 + lm, N-1);
  const short* Ag0 = A + (long long)arow0*lda + quad*8;
  const short* Ag1 = A + (long long)arow1*lda + quad*8;
  const short* Bg0 = B + (long long)brow0*ldb + quad*8;
  const short* Bg1 = B + (long long)brow1*ldb + quad*8;
  short* Al0 = &As[(w*2+0)*512];
  short* Al1 = &As[(w*2+1)*512];
  short* Bl0 = &Bs[(w*2+0)*512];
  short* Bl1 = &Bs[(w*2+1)*512];

  f32x4 acc[4][4] = {};

  for (int k0=kbeg; k0<kend; k0+=XBK){
    GLL16(Ag0 + k0, Al0);
    GLL16(Ag1 + k0, Al1);
    GLL16(Bg0 + k0, Bl0);
    GLL16(Bg1 + k0, Bl1);
    __syncthreads();
    bf16x8 af[4], bfr[4];
    #pragma unroll
    for (int tm=0;tm<4;tm++) af[tm]  = *(bf16x8*)&As[(waveM*4+tm)*512 + quad*128 + lm*8];
    #pragma unroll
    for (int tn=0;tn<4;tn++) bfr[tn] = *(bf16x8*)&Bs[(waveN*4+tn)*512 + quad*128 + lm*8];
    #pragma unroll
    for (int tm=0;tm<4;tm++)
      #pragma unroll
      for (int tn=0;tn<4;tn++)
        acc[tm][tn] = __builtin_amdgcn_mfma_f32_16x16x32_bf16(af[tm], bfr[tn], acc[tm][tn], 0,0,0);
    __syncthreads();
  }

  #pragma unroll
  for (int tm=0;tm<4;tm++){
    #pragma unroll
    for (int tn=0;tn<4;tn++){
      int col = colBase + waveN*64 + tn*16 + lm;
      if (col>=N) continue;
      #pragma unroll
      for (int reg=0;reg<4;reg++){
        int row = rowBase + waveM*64 + tm*16 + quad*4 + reg;
        if (row>=M) continue;
        float v = acc[tm][tn][reg];
        if (KS>1){ atomicAdd(&outF[(long long)row*ldo+col], v); continue; }
        v = epi(v, bias, col, act);
        if (res) v += res[(long long)row*ldr+col];
        if (outbf16) outH[(long long)row*ldo+col] = fbf(v);
        else         outF[(long long)row*ldo+col] = v;
      }
    }
  }
}

// ---------- bf16 MFMA GEMM, 64x64 tile ----------
// outbf16==2: transposed V store: out + (b*384+col)*2048 + (row&2047), b=row>>11
__global__ __launch_bounds__(256)
void gemm_bf16_s(const short* __restrict__ A, int lda, long long sA,
                 const short* __restrict__ B, int ldb, long long sB,
                 const float* __restrict__ bias, long long sBias,
                 const float* __restrict__ res, int ldr, long long sR,
                 void* __restrict__ out, int ldo, long long sO, int outbf16,
                 int M, int N, int K, int act)
{
  __shared__ short As[64*32];
  __shared__ short Bs[64*32];
  int z = blockIdx.z;
  A += (long long)z*sA; B += (long long)z*sB;
  if (res) res += (long long)z*sR;
  if (bias) bias += (long long)z*sBias;
  float* outF = (float*)out + (long long)z*sO;
  short* outH = (short*)out + (long long)z*sO;

  int tid = threadIdx.x;
  int rowBase = blockIdx.y*64;
  int colBase = blockIdx.x*64;

  int w = tid>>6;
  int lane = tid&63;
  int lm = lane&15, quad = lane>>4;
  int wm = w>>1, wn = w&1;

  int arow = min(rowBase + w*16 + lm, M-1);
  int brow = min(colBase + w*16 + lm, N-1);
  const short* Ag = A + (long long)arow*lda + quad*8;
  const short* Bg = B + (long long)brow*ldb + quad*8;
  short* Al = &As[w*512];
  short* Bl = &Bs[w*512];

  f32x4 acc[2][2] = {};

  for (int k0=0; k0<K; k0+=32){
    GLL16(Ag + k0, Al);
    GLL16(Bg + k0, Bl);
    __syncthreads();
    bf16x8 af[2], bfr[2];
    #pragma unroll
    for (int tm=0;tm<2;tm++) af[tm]  = *(bf16x8*)&As[(wm*2+tm)*512 + quad*128 + lm*8];
    #pragma unroll
    for (int tn=0;tn<2;tn++) bfr[tn] = *(bf16x8*)&Bs[(wn*2+tn)*512 + quad*128 + lm*8];
    #pragma unroll
    for (int tm=0;tm<2;tm++)
      #pragma unroll
      for (int tn=0;tn<2;tn++)
        acc[tm][tn] = __builtin_amdgcn_mfma_f32_16x16x32_bf16(af[tm], bfr[tn], acc[tm][tn], 0,0,0);
    __syncthreads();
  }

  #pragma unroll
  for (int tm=0;tm<2;tm++){
    #pragma unroll
    for (int tn=0;tn<2;tn++){
      int col = colBase + wn*32 + tn*16 + lm;
      if (col>=N) continue;
      #pragma unroll
      for (int reg=0;reg<4;reg++){
        int row = rowBase + wm*32 + tm*16 + quad*4 + reg;
        if (row>=M) continue;
        float v = epi(acc[tm][tn][reg], bias, col, act);
        if (res) v += res[(long long)row*ldr+col];
        if (outbf16==2){
          int bb = row>>11;
          outH[((long long)bb*384 + col)*2048 + (row&2047)] = fbf(v);
        }
        else if (outbf16) outH[(long long)row*ldo+col] = fbf(v);
        else              outF[(long long)row*ldo+col] = v;
      }
    }
  }
}

// ---------- flash-fused view attention v5: v4 + XCD-aware block swizzle ----------
// grid: 768 blocks 1-D. id%8 = XCD guess; each XCD handles 3 (v,b) pairs.
// QK6: [6][8192][768] bf16 (Q 0..384, K 384..768); Vt6: [24][384][2048] bf16
// maskb: [6][2048][2048] u8; O6: [6][8192][384] bf16
// LDS: K 48KB [0,49152) + P [64][68]bf16 [49152,57856) + alpha f32[64]
__global__ __launch_bounds__(256,2)
void flash_view(const short* __restrict__ QK6, const short* __restrict__ Vt6,
                const unsigned char* __restrict__ maskb, short* __restrict__ O6)
{
  __shared__ char lds[58112];
  const float scale = 0.05103103630798288f;
  // XCD-aware decode: blocks with same id%8 share 3 (v,b) K/V working sets
  int id = blockIdx.x;
  int xcd = id & 7;
  int j = id >> 3;              // 0..95
  int vb = xcd*3 + (j>>5);      // 0..23
  int qt = j & 31;
  int v = vb >> 2, b = vb & 3;
  int tid=threadIdx.x, w=tid>>6, lane=tid&63, lm=lane&15, quad=lane>>4;

  const short* Qp = QK6 + ((long long)v*8192 + b*2048 + qt*64)*768;
  const short* Kp = QK6 + ((long long)v*8192 + b*2048)*768 + 384;
  const short* Vp = Vt6 + (long long)(v*4+b)*384*2048;
  const unsigned char* Mp = maskb + (long long)v*2048*2048 + (long long)qt*64*2048;
  short* Op = O6 + ((long long)v*8192 + b*2048 + qt*64)*384;

  short* P = (short*)(lds + 49152);
  float* alphaL = (float*)(lds + 57856);

  // Q A-frags direct global->reg (wave w owns q-rows w*16..w*16+16)
  bf16x8 af[12];
  #pragma unroll
  for (int c=0;c<12;c++)
    af[c] = *(const bf16x8*)(Qp + (long long)(w*16+lm)*768 + c*32 + quad*8);

  float m_i[4], l_i[4];
  #pragma unroll
  for (int r=0;r<4;r++){ m_i[r]=-3.0e38f; l_i[r]=0.f; }
  f32x4 Oacc[4][6] = {};

  for (int kt=0; kt<32; kt++){
    // ---- stage K (64x384): wave w stages rows w*16..+16
    #pragma unroll
    for (int c=0;c<12;c++)
      GLL16(Kp + (long long)(kt*64 + w*16 + lm)*768 + c*32 + quad*8, (short*)(lds + w*12288 + c*1024));
    __syncthreads();  // (a) K visible
    // ---- mask prefetch (covered by S MFMAs)
    unsigned char mreg[4][4];
    #pragma unroll
    for (int ct=0;ct<4;ct++)
      #pragma unroll
      for (int r=0;r<4;r++)
        mreg[ct][r] = Mp[(long long)(w*16+quad*4+r)*2048 + kt*64 + ct*16 + lm];
    // ---- S: Q(16x384) @ K(64x384)^T
    f32x4 S[4];
    #pragma unroll
    for (int i=0;i<4;i++) S[i] = (f32x4){0.f,0.f,0.f,0.f};
    #pragma unroll
    for (int kc=0;kc<12;kc++){
      #pragma unroll
      for (int ct=0;ct<4;ct++){
        bf16x8 bf = *(bf16x8*)(lds + ct*12288 + kc*1024 + quad*256 + lm*16);
        S[ct] = __builtin_amdgcn_mfma_f32_16x16x32_bf16(af[kc], bf, S[ct], 0,0,0);
      }
    }
    // ---- mask + scale
    #pragma unroll
    for (int ct=0;ct<4;ct++){
      #pragma unroll
      for (int r=0;r<4;r++)
        S[ct][r] = mreg[ct][r] ? S[ct][r]*scale : -3.0e38f;
    }
    // ---- online softmax for wave's 16 q-rows
    float alpha[4], mnew[4];
    #pragma unroll
    for (int r=0;r<4;r++){
      float rm = S[0][r];
      #pragma unroll
      for (int ct=1;ct<4;ct++) rm = fmaxf(rm, S[ct][r]);
      #pragma unroll
      for (int o=1;o<16;o<<=1) rm = fmaxf(rm, __shfl_xor(rm, o));
      mnew[r] = fmaxf(m_i[r], rm);
      alpha[r] = __expf(m_i[r]-mnew[r]);
      m_i[r] = mnew[r];
    }
    float rs[4] = {0.f,0.f,0.f,0.f};
    #pragma unroll
    for (int ct=0;ct<4;ct++){
      #pragma unroll
      for (int r=0;r<4;r++){
        float sv = S[ct][r];
        float p = (sv > -1.0e37f) ? __expf(sv - mnew[r]) : 0.f;
        rs[r] += p;
        P[(w*16+quad*4+r)*68 + ct*16 + lm] = fbf(p);
      }
    }
    #pragma unroll
    for (int r=0;r<4;r++){
      #pragma unroll
      for (int o=1;o<16;o<<=1) rs[r] += __shfl_xor(rs[r], o);
      l_i[r] = l_i[r]*alpha[r] + rs[r];
    }
    if (lm==0){
      #pragma unroll
      for (int r=0;r<4;r++) alphaL[w*16+quad*4+r] = alpha[r];
    }
    // ---- V prefetch to regs (latency hidden inside barrier (b) drain)
    bf16x8 Vreg[6][2];
    #pragma unroll
    for (int jj=0;jj<6;jj++)
      #pragma unroll
      for (int kk=0;kk<2;kk++)
        Vreg[jj][kk] = *(const bf16x8*)(Vp + (long long)((w*6+jj)*16+lm)*2048 + kt*64 + kk*32 + quad*8);
    __syncthreads();  // (b) P/alpha visible; V landed
    // ---- rescale Oacc
    f32x4 am[4];
    #pragma unroll
    for (int m=0;m<4;m++) am[m] = *(f32x4*)&alphaL[m*16 + quad*4];
    #pragma unroll
    for (int m=0;m<4;m++)
      #pragma unroll
      for (int tn=0;tn<6;tn++)
        Oacc[m][tn] *= am[m];
    // ---- PV: P(64x64, LDS) @ V(64x384, regs) — wave's 6 tn for all rows
    #pragma unroll
    for (int kk=0;kk<2;kk++){
      bf16x8 ap[4];
      #pragma unroll
      for (int m=0;m<4;m++) ap[m] = *(bf16x8*)&P[(m*16+lm)*68 + kk*32 + quad*8];
      #pragma unroll
      for (int tn=0;tn<6;tn++){
        #pragma unroll
        for (int m=0;m<4;m++)
          Oacc[m][tn] = __builtin_amdgcn_mfma_f32_16x16x32_bf16(ap[m], Vreg[tn][kk], Oacc[m][tn], 0,0,0);
      }
    }
  }

  __syncthreads();
  if (lm==0){
    #pragma unroll
    for (int r=0;r<4;r++) alphaL[w*16+quad*4+r] = l_i[r];
  }
  __syncthreads();
  f32x4 lv[4];
  #pragma unroll
  for (int m=0;m<4;m++) lv[m] = *(f32x4*)&alphaL[m*16 + quad*4];
  #pragma unroll
  for (int m=0;m<4;m++){
    #pragma unroll
    for (int tn=0;tn<6;tn++){
      #pragma unroll
      for (int reg=0;reg<4;reg++){
        Op[(long long)(m*16+quad*4+reg)*384 + (w*6+tn)*16 + lm] = fbf(Oacc[m][tn][reg] / lv[m][reg]);
      }
    }
  }
}

// ---------- flash-fused inner attention v3: XCD-aware swizzle ----------
// grid 792 blocks 1-D: id%8 = XCD; each XCD handles 3 (b,h) pairs.
// QKV = bufQh [4][2049][1152]; Vt = Vt_i [24][64][2112] (V^T, zero-padded)
// O = bufOh [4*2049][384]  (bf16)
// LDS: K 8KB [0,8192) + P [64][68] [8192,16896) + alpha f32[64] [16896,17152)
__global__ __launch_bounds__(256,4)
void flash_inner(const short* __restrict__ QKV, const short* __restrict__ Vt,
                 short* __restrict__ O)
{
  __shared__ char lds[17152];
  int id = blockIdx.x;
  int xcd = id & 7;
  int j = id >> 3;              // 0..98
  int bh = xcd*3 + j/33;        // 0..23
  int qt = j%33;
  int b=bh/6, h=bh-b*6;
  int tid=threadIdx.x, w=tid>>6, lane=tid&63, lm=lane&15, quad=lane>>4;

  const short* Qb = QKV + (long long)b*2049*1152 + h*64;
  const short* Kb = Qb + 384;
  const short* Vtp = Vt + (long long)bh*64*2112;
  short* Op = O + ((long long)b*2049 + qt*64)*384 + h*64;

  short* P = (short*)(lds + 8192);
  float* alphaL = (float*)(lds + 16896);

  int qr = min(qt*64 + w*16 + lm, 2048);
  bf16x8 af[2];
  #pragma unroll
  for (int c=0;c<2;c++)
    af[c] = *(const bf16x8*)(Qb + (long long)qr*1152 + c*32 + quad*8);

  float m_i[4], l_i[4];
  #pragma unroll
  for (int r=0;r<4;r++){ m_i[r]=-3.0e38f; l_i[r]=0.f; }
  f32x4 Oacc[4] = {};

  for (int kt=0; kt<33; kt++){
    int kr = min(kt*64 + w*16 + lm, 2048);
    #pragma unroll
    for (int c=0;c<2;c++)
      GLL16(Kb + (long long)kr*1152 + c*32 + quad*8, (short*)(lds + w*2048 + c*1024));
    __syncthreads();  // (a)
    f32x4 S[4];
    #pragma unroll
    for (int i=0;i<4;i++) S[i] = (f32x4){0.f,0.f,0.f,0.f};
    #pragma unroll
    for (int kc=0;kc<2;kc++){
      #pragma unroll
      for (int ct=0;ct<4;ct++){
        bf16x8 bf = *(bf16x8*)(lds + ct*2048 + kc*1024 + quad*256 + lm*16);
        S[ct] = __builtin_amdgcn_mfma_f32_16x16x32_bf16(af[kc], bf, S[ct], 0,0,0);
      }
    }
    #pragma unroll
    for (int ct=0;ct<4;ct++){
      int scol = kt*64 + ct*16 + lm;
      bool ok = scol <= 2048;
      #pragma unroll
      for (int r=0;r<4;r++) S[ct][r] = ok ? S[ct][r]*0.125f : -3.0e38f;
    }
    float alpha[4], mnew[4];
    #pragma unroll
    for (int r=0;r<4;r++){
      float rm = S[0][r];
      #pragma unroll
      for (int ct=1;ct<4;ct++) rm = fmaxf(rm, S[ct][r]);
      #pragma unroll
      for (int o=1;o<16;o<<=1) rm = fmaxf(rm, __shfl_xor(rm, o));
      mnew[r] = fmaxf(m_i[r], rm);
      alpha[r] = __expf(m_i[r]-mnew[r]);
      m_i[r] = mnew[r];
    }
    float rs[4] = {0.f,0.f,0.f,0.f};
    #pragma unroll
    for (int ct=0;ct<4;ct++){
      #pragma unroll
      for (int r=0;r<4;r++){
        float sv = S[ct][r];
        float p = (sv > -1.0e37f) ? __expf(sv - mnew[r]) : 0.f;
        rs[r] += p;
        P[(w*16+quad*4+r)*68 + ct*16 + lm] = fbf(p);
      }
    }
    #pragma unroll
    for (int r=0;r<4;r++){
      #pragma unroll
      for (int o=1;o<16;o<<=1) rs[r] += __shfl_xor(rs[r], o);
      l_i[r] = l_i[r]*alpha[r] + rs[r];
    }
    if (lm==0){
      #pragma unroll
      for (int r=0;r<4;r++) alphaL[w*16+quad*4+r] = alpha[r];
    }
    bf16x8 Vreg[2];
    #pragma unroll
    for (int kk=0;kk<2;kk++)
      Vreg[kk] = *(const bf16x8*)(Vtp + (long long)(w*16+lm)*2112 + kt*64 + kk*32 + quad*8);
    __syncthreads();  // (b)
    f32x4 am[4];
    #pragma unroll
    for (int m=0;m<4;m++) am[m] = *(f32x4*)&alphaL[m*16 + quad*4];
    #pragma unroll
    for (int m=0;m<4;m++) Oacc[m] *= am[m];
    #pragma unroll
    for (int kk=0;kk<2;kk++){
      bf16x8 ap[4];
      #pragma unroll
      for (int m=0;m<4;m++) ap[m] = *(bf16x8*)&P[(m*16+lm)*68 + kk*32 + quad*8];
      #pragma unroll
      for (int m=0;m<4;m++)
        Oacc[m] = __builtin_amdgcn_mfma_f32_16x16x32_bf16(ap[m], Vreg[kk], Oacc[m], 0,0,0);
    }
  }

  __syncthreads();
  if (lm==0){
    #pragma unroll
    for (int r=0;r<4;r++) alphaL[w*16+quad*4+r] = l_i[r];
  }
  __syncthreads();
  f32x4 lv[4];
  #pragma unroll
  for (int m=0;m<4;m++) lv[m] = *(f32x4*)&alphaL[m*16 + quad*4];
  #pragma unroll
  for (int m=0;m<4;m++){
    #pragma unroll
    for (int reg=0;reg<4;reg++){
      int row = qt*64 + m*16 + quad*4 + reg;
      if (row < 2049)
        Op[(long long)(m*16+quad*4+reg)*384 + w*16 + lm] = fbf(Oacc[m][reg] / lv[m][reg]);
    }
  }
}

// ---------- LayerNorm (fp32 in -> bf16 out), C=384 ----------
__global__ __launch_bounds__(128)
void ln_bf16_kernel(const float* __restrict__ in, const float* __restrict__ g,
                    const float* __restrict__ bt, short* __restrict__ out)
{
  long long row = blockIdx.x;
  const float* p = in + row*384;
  int tid = threadIdx.x;
  float v0=p[tid], v1=p[tid+128], v2=p[tid+256];
  float s = v0+v1+v2;
  float ss = v0*v0+v1*v1+v2*v2;
  __shared__ float r1[2], r2[2];
  s = wsum(s); ss = wsum(ss);
  int wid=tid>>6, lane=tid&63;
  if (lane==0){ r1[wid]=s; r2[wid]=ss; }
  __syncthreads();
  float mean=(r1[0]+r1[1])*(1.f/384.f);
  float var =(r2[0]+r2[1])*(1.f/384.f)-mean*mean;
  float rstd=rsqrtf(var+1e-5f);
  short* o = out + row*384;
  o[tid]     = fbf((v0-mean)*rstd*g[tid]+bt[tid]);
  o[tid+128] = fbf((v1-mean)*rstd*g[tid+128]+bt[tid+128]);
  o[tid+256] = fbf((v2-mean)*rstd*g[tid+256]+bt[tid+256]);
}

// ---------- LN once, write 6 per-view normed copies ----------
__global__ __launch_bounds__(128)
void ln6_kernel(const float* __restrict__ in, const float* __restrict__ g6,
                const float* __restrict__ b6, short* __restrict__ out6)
{
  long long row = blockIdx.x;
  const float* p = in + row*384;
  int tid = threadIdx.x;
  float v0=p[tid], v1=p[tid+128], v2=p[tid+256];
  float s = v0+v1+v2;
  float ss = v0*v0+v1*v1+v2*v2;
  __shared__ float r1[2], r2[2];
  s = wsum(s); ss = wsum(ss);
  int wid=tid>>6, lane=tid&63;
  if (lane==0){ r1[wid]=s; r2[wid]=ss; }
  __syncthreads();
  float mean=(r1[0]+r1[1])*(1.f/384.f);
  float var =(r2[0]+r2[1])*(1.f/384.f)-mean*mean;
  float rstd=rsqrtf(var+1e-5f);
  float n0=(v0-mean)*rstd, n1=(v1-mean)*rstd, n2=(v2-mean)*rstd;
  #pragma unroll
  for (int i=0;i<6;i++){
    const float* g = g6 + i*384;
    const float* bt = b6 + i*384;
    short* o = out6 + (long long)i*8192*384 + row*384;
    o[tid]     = fbf(n0*g[tid]+bt[tid]);
    o[tid+128] = fbf(n1*g[tid+128]+bt[tid+128]);
    o[tid+256] = fbf(n2*g[tid+256]+bt[tid+256]);
  }
}

// ---------- fp32 -> bf16 convert ----------
__global__ void cvt_kernel(const float* __restrict__ in, short* __restrict__ out, long long n4){
  long long i = (long long)blockIdx.x*256 + threadIdx.x;
  if (i<n4){
    float4 f = ((const float4*)in)[i];
    short4 s;
    s.x=fbf(f.x); s.y=fbf(f.y); s.z=fbf(f.z); s.w=fbf(f.w);
    ((short4*)out)[i]=s;
  }
}

// ---------- tiled transpose+convert: fp32 [R,C] -> bf16 [C, ldout] ----------
__global__ __launch_bounds__(256)
void tconv_kernel(const float* __restrict__ in, int ldin, long long sIn, long long sIn2, int zmod,
                  int R, int C, short* __restrict__ out, int ldout, long long sOut)
{
  __shared__ float tile[32][33];
  int z = blockIdx.z;
  const float* ip = in + (long long)(z/zmod)*sIn + (long long)(z%zmod)*sIn2;
  short* op = out + (long long)z*sOut;
  int r0 = blockIdx.x*32;
  int c0 = blockIdx.y*32;
  int tx = threadIdx.x&31, ty = threadIdx.x>>5;
  #pragma unroll
  for (int i=0;i<4;i++){
    int r = r0 + ty + i*8, c = c0 + tx;
    tile[ty+i*8][tx] = (r<R && c<C) ? ip[(long long)r*ldin + c] : 0.f;
  }
  __syncthreads();
  #pragma unroll
  for (int i=0;i<4;i++){
    int oc = c0 + ty + i*8;
    int orr = r0 + tx;
    if (oc<C && orr<ldout) op[(long long)oc*ldout + orr] = fbf(tile[tx][ty+i*8]);
  }
}

// ---------- tiled transpose: bf16 [R,C] -> bf16 [C, ldout] ----------
__global__ __launch_bounds__(256)
void tconv16_kernel(const short* __restrict__ in, int ldin, long long sIn, long long sIn2, int zmod,
                    int R, int C, short* __restrict__ out, int ldout, long long sOut)
{
  __shared__ short tile[32][34];
  int z = blockIdx.z;
  const short* ip = in + (long long)(z/zmod)*sIn + (long long)(z%zmod)*sIn2;
  short* op = out + (long long)z*sOut;
  int r0 = blockIdx.x*32;
  int c0 = blockIdx.y*32;
  int tx = threadIdx.x&31, ty = threadIdx.x>>5;
  #pragma unroll
  for (int i=0;i<4;i++){
    int r = r0 + ty + i*8, c = c0 + tx;
    tile[ty+i*8][tx] = (r<R && c<C) ? ip[(long long)r*ldin + c] : (short)0;
  }
  __syncthreads();
  #pragma unroll
  for (int i=0;i<4;i++){
    int oc = c0 + ty + i*8;
    int orr = r0 + tx;
    if (oc<C && orr<ldout) op[(long long)oc*ldout + orr] = tile[tx][ty+i*8];
  }
}

// ---------- elementwise ----------
__global__ void ew_x2_kernel(float* x1, const float* ffn, const float* ada, long long n){
  long long i=(long long)blockIdx.x*256+threadIdx.x;
  if (i<n) x1[i] = x1[i] + ffn[i] + 0.5f*ada[i];
}
__global__ void copy_pts_kernel(const float* __restrict__ x2, float* __restrict__ pts){
  long long i=(long long)blockIdx.x*256+threadIdx.x;
  if (i < 8192ll*384){
    long long b = i/(2048ll*384);
    long long rem = i%(2048ll*384);
    pts[i] = x2[(b*2049+1)*384 + rem];
  }
}
__global__ void copy_cls_kernel(const float* __restrict__ x2, float* __restrict__ out){
  int i = blockIdx.x*256+threadIdx.x;
  if (i < 4*384){
    int b=i/384, c=i%384;
    out[(long long)b*2049*384 + c] = x2[(long long)b*2049*384 + c];
  }
}

// ---------- segment scatter (z-batched) ----------
__global__ __launch_bounds__(128)
void scatter_seg_kernel(const float* __restrict__ feat, const int* __restrict__ seg,
                        float* __restrict__ fsum, unsigned* __restrict__ fmax,
                        float* __restrict__ cnt,
                        long long zFeat, long long zSeg, long long zSum, long long zCnt)
{
  int n = blockIdx.x, z = blockIdx.y;
  feat += (long long)z*zFeat; seg += (long long)z*zSeg;
  fsum += (long long)z*zSum; fmax += (long long)z*zSum; cnt += (long long)z*zCnt;
  int s = seg[n];
  const float* p = feat + (long long)n*384;
  int tid = threadIdx.x;
  #pragma unroll
  for (int k=0;k<3;k++){
    int c = tid + k*128;
    float v = p[c];
    atomicAdd(&fsum[(long long)s*384+c], v);
    atomicMax(&fmax[(long long)s*384+c], fkey(v));
  }
  if (tid==0) atomicAdd(&cnt[s], 1.0f);
}

// ---------- cell = bn_gelu(max + mean), z-batched ----------
__global__ __launch_bounds__(128)
void cell_kernel(const float* __restrict__ fsum, const unsigned* __restrict__ fmax,
                 const float* __restrict__ cnt,
                 const float* __restrict__ g, const float* __restrict__ bb,
                 const float* __restrict__ m, const float* __restrict__ v,
                 float* __restrict__ out, long long zSum, long long zCnt, long long zP)
{
  int s = blockIdx.x, z = blockIdx.y;
  fsum += (long long)z*zSum; fmax += (long long)z*zSum; cnt += (long long)z*zCnt;
  g += (long long)z*zP; bb += (long long)z*zP; m += (long long)z*zP; v += (long long)z*zP;
  out += (long long)z*zSum;
  float cn = cnt[s];
  float denom = fmaxf(cn, 1.f);
  int tid = threadIdx.x;
  #pragma unroll
  for (int k=0;k<3;k++){
    int c = tid + k*128;
    float mx = (cn>0.f) ? fdec(fmax[(long long)s*384+c]) : 0.f;
    float t = mx + fsum[(long long)s*384+c]/denom;
    t = (t - m[c])*rsqrtf(v[c]+1e-5f)*g[c] + bb[c];
    out[(long long)s*384+c] = geluf(t);
  }
}

// ---------- final cosine-sim weighted combine ----------
__global__ __launch_bounds__(128)
void combine_kernel(const float* __restrict__ pts, const float* __restrict__ cell3,
                    const int* __restrict__ cluster, const float* __restrict__ cell2,
                    const int* __restrict__ gidx, float* __restrict__ out)
{
  int n = blockIdx.x;
  int tid = threadIdx.x;
  __shared__ float sdot[6], ssq[6], sw[6];
  __shared__ int soff[6];
  __shared__ float red[2][2];
  __shared__ float sn3;
  const float* x3 = cell3 + (long long)cluster[n]*384;
  int wid=tid>>6, lane=tid&63;
  float sq=0.f;
  for (int c=tid;c<384;c+=128){ float v=x3[c]; sq+=v*v; }
  sq = wsum(sq);
  if (lane==0) red[0][wid]=sq;
  __syncthreads();
  if (tid==0) sn3 = sqrtf(red[0][0]+red[0][1]);
  __syncthreads();
  for (int i=0;i<6;i++){
    int gi = gidx[(long long)i*8192 + n];
    if (tid==0) soff[i]=gi;
    const float* r = cell2 + ((long long)i*4096 + gi)*384;
    float d=0.f, s2=0.f;
    for (int c=tid;c<384;c+=128){ float a=r[c]; d+=a*x3[c]; s2+=a*a; }
    d = wsum(d); s2 = wsum(s2);
    if (lane==0){ red[0][wid]=d; red[1][wid]=s2; }
    __syncthreads();
    if (tid==0){ sdot[i]=red[0][0]+red[0][1]; ssq[i]=red[1][0]+red[1][1]; }
    __syncthreads();
  }
  if (tid==0){
    float ssumv=0.f; float sims[6];
    for (int i=0;i<6;i++){
      float nrm = sqrtf(ssq[i])*sn3;
      float s = (sdot[i]/fmaxf(nrm,1e-8f) + 1.f)*0.5f;
      sims[i]=s; ssumv+=s;
    }
    for (int i=0;i<6;i++) sw[i]=sims[i]/ssumv;
  }
  __syncthreads();
  int b = n>>11, gp = n&2047;
  float* o = out + ((long long)(b*2049 + 1 + gp))*384;
  for (int c=tid;c<384;c+=128){
    float acc=0.f;
    #pragma unroll
    for (int i=0;i<6;i++){
      const float* r = cell2 + ((long long)i*4096 + soff[i])*384;
      acc += sw[i]*r[c];
    }
    o[c] = pts[(long long)n*384+c] + 0.5f*acc;
  }
}

// ---------- host helpers ----------
static inline void launch_gemm16b(hipStream_t s, const short* A,int lda,long long sA,
  const short* B,int ldb,long long sB, const float* bias, long long sBias,
  const float* res,int ldr,long long sR, void* out,int ldo,long long sO,int outbf16,
  int M,int N,int K,int act,int nz,int KS)
{
  dim3 g((N+XBN-1)/XBN,(M+XBM-1)/XBM,(unsigned)(nz*KS));
  hipLaunchKernelGGL(gemm_bf16_big,g,dim3(256),0,s,
    A,lda,sA,B,ldb,sB,bias,sBias,res,ldr,sR,out,ldo,sO,outbf16,M,N,K,act,KS);
}
static inline void launch_gemm16s(hipStream_t s, const short* A,int lda,long long sA,
  const short* B,int ldb,long long sB, const float* bias, long long sBias,
  const float* res,int ldr,long long sR, void* out,int ldo,long long sO,int outbf16,
  int M,int N,int K,int act,int nz)
{
  dim3 g((N+63)/64,(M+63)/64,(unsigned)nz);
  hipLaunchKernelGGL(gemm_bf16_s,g,dim3(256),0,s,
    A,lda,sA,B,ldb,sB,bias,sBias,res,ldr,sR,out,ldo,sO,outbf16,M,N,K,act);
}
static inline void launch_tconv(hipStream_t s, const float* in,int ldin,long long sIn,long long sIn2,int zmod,
  int R,int C, short* out,int ldout,long long sOut,int nz)
{
  dim3 g((ldout+31)/32,(C+31)/32,(unsigned)nz);
  hipLaunchKernelGGL(tconv_kernel,g,dim3(256),0,s, in,ldin,sIn,sIn2,zmod,R,C,out,ldout,sOut);
}
static inline void launch_tconv16(hipStream_t s, const short* in,int ldin,long long sIn,long long sIn2,int zmod,
  int R,int C, short* out,int ldout,long long sOut,int nz)
{
  dim3 g((ldout+31)/32,(C+31)/32,(unsigned)nz);
  hipLaunchKernelGGL(tconv16_kernel,g,dim3(256),0,s, in,ldin,sIn,sIn2,zmod,R,C,out,ldout,sOut);
}
static inline void launch_cvt(hipStream_t s, const float* in, short* out, long long n){
  long long n4 = n/4;
  hipLaunchKernelGGL(cvt_kernel,dim3((unsigned)((n4+255)/256)),dim3(256),0,s,in,out,n4);
}

extern "C" void kernel_launch(void* const* d_in, const int* in_sizes, int n_in,
                              void* d_out, int out_size, void* d_ws, size_t ws_size,
                              hipStream_t stream)
{
  const float* x       = (const float*)d_in[0];
  const float* norm1_g = (const float*)d_in[2];
  const float* norm1_b = (const float*)d_in[3];
  const float* qkv_w   = (const float*)d_in[4];
  const float* proj_w  = (const float*)d_in[5];
  const float* proj_b  = (const float*)d_in[6];
  const float* norm2_g = (const float*)d_in[7];
  const float* norm2_b = (const float*)d_in[8];
  const float* fc1_w   = (const float*)d_in[9];
  const float* fc1_b   = (const float*)d_in[10];
  const float* fc2_w   = (const float*)d_in[11];
  const float* fc2_b   = (const float*)d_in[12];
  const float* ada1_w  = (const float*)d_in[13];
  const float* ada1_b  = (const float*)d_in[14];
  const float* ada2_w  = (const float*)d_in[15];
  const float* ada2_b  = (const float*)d_in[16];
  const float* bn3_g   = (const float*)d_in[17];
  const float* bn3_b   = (const float*)d_in[18];
  const float* bn3_m   = (const float*)d_in[19];
  const float* bn3_v   = (const float*)d_in[20];
  const float* bn2_g   = (const float*)d_in[21];
  const float* bn2_b   = (const float*)d_in[22];
  const float* bn2_m   = (const float*)d_in[23];
  const float* bn2_v   = (const float*)d_in[24];
  const float* norm3_g = (const float*)d_in[25];
  const float* norm3_b = (const float*)d_in[26];
  const float* a1_qkv_w  = (const float*)d_in[27];
  const float* a1_proj_w = (const float*)d_in[28];
  const float* a1_proj_b = (const float*)d_in[29];
  const void*  maskp     = d_in[30];
  const int*   cluster   = (const int*)d_in[33];
  const int*   fgi       = (const int*)d_in[34];
  float* out = (float*)d_out;

  // ---- workspace ----
  size_t off = 0;
  char* wsb = (char*)d_ws;
  auto alloc = [&](size_t bytes)->void*{
    void* p = wsb + off;
    off += (bytes + 255) & ~(size_t)255;
    return p;
  };
  // persistent
  short*    bufHh = (short*)alloc(8196ll*384*2);
  float*    ptsb  = (float*)alloc(8192ll*384*4);
  float*    cnt   = (float*)alloc(1024*4);
  float*    fsum  = (float*)alloc(1024ll*384*4);
  unsigned* fmaxe = (unsigned*)alloc(1024ll*384*4);
  float*    cell3 = (float*)alloc(1024ll*384*4);
  unsigned char* maskb = (unsigned char*)alloc(6ll*2048*2048);
  float*    gc6   = (float*)alloc(6ll*4096*4);
  short*    qkvT  = (short*)alloc(1152ll*384*2);
  short*    projT = (short*)alloc(384ll*384*2);
  short*    fc1T  = (short*)alloc(1536ll*384*2);
  short*    fc2T  = (short*)alloc(384ll*1536*2);
  short*    ada1T = (short*)alloc(96ll*384*2);
  short*    ada2T = (short*)alloc(384ll*96*2);
  short*    a1qkvT  = (short*)alloc(6ll*1152*384*2);
  short*    a1projT = (short*)alloc(6ll*384*384*2);
  int*      flag  = (int*)alloc(256);
  // arena: A0 [0,75.5M) + A1 [75.5M,151M) + A2 [151M,188.75M)
  char* arena = (char*)alloc(188743680);
  char* A0 = arena;
  char* A1 = arena + 75497472;
  char* A2 = arena + 150994944;
  // phase-1 overlay
  short* bufQh = (short*)(A0 + 0);            // 8196x1152 bf16 (18.9M)
  float* bufO  = (float*)(A0 + 20971520);     // 8196x384 f32 (12.6M)
  short* bufOh = (short*)(A0 + 35651584);     // 8196x384 bf16 (6.3M)
  short* bufAh = (short*)(A0 + 44040192);     // 8196x96 bf16
  float* bufX  = (float*)(A0 + 46137344);     // 8196x384 f32
  float* bufAda= (float*)(A0 + 0);            // ada2 out (aliases bufQh after qkv dead)
  short* Vt_i  = (short*)(A1 + 0);            // 24x64x2112 bf16 (6.5M)
  short* bufTh = (short*)(A1 + 8388608);      // fc1 out 8196x1536 bf16 (25.2M; Vt_i dead by then)
  // view-phase overlay
  short* QK6   = (short*)(A0 + 0);            // 6x8192x768 bf16 (75.5M)
  short* Vt6   = (short*)(A1 + 0);            // 24x384x2048 bf16 (37.7M)
  short* O6    = (short*)(A2 + 0);            // 6x8192x384 bf16 (37.7M)
  short* bufHh6= (short*)(A2 + 0);            // ln6 out (aliases O6; dead before flash)
  // post-flash overlay
  float* bufT6 = (float*)(A0 + 0);            // 6x8192x384 f32 (75.5M, aliases QK6)
  float* gsum6 = (float*)(A1 + 0);            // 6x4096x384 f32 (37.7M)
  unsigned* gmaxe6 = (unsigned*)(A1 + 37748736); // 6x4096x384 u32
  float* cell2 = (float*)(A0 + 0);            // 6x4096x384 f32 (written after bufT6 dead)

  // ---- mask detect + byte conversion ----
  hipMemsetAsync(flag, 0, 4, stream);
  {
    long long nInt = 6ll*2048*2048/4;
    detect_mask_kernel<<<dim3((unsigned)((nInt+255)/256)),dim3(256),0,stream>>>((const int*)maskp, nInt, flag);
    mask_byte_kernel<<<dim3((unsigned)((nInt+255)/256)),dim3(256),0,stream>>>(maskp, maskb, nInt, flag);
  }

  // ---- weight transposes (fp32 [K,N] -> bf16 [N,K]) ----
  launch_tconv(stream, qkv_w, 1152, 0,0,1, 384,1152, qkvT, 384, 0, 1);
  launch_tconv(stream, proj_w, 384, 0,0,1, 384,384,  projT, 384, 0, 1);
  launch_tconv(stream, fc1_w, 1536, 0,0,1, 384,1536, fc1T, 384, 0, 1);
  launch_tconv(stream, fc2_w, 384,  0,0,1, 1536,384, fc2T, 1536, 0, 1);
  launch_tconv(stream, ada1_w, 96,  0,0,1, 384,96,   ada1T, 384, 0, 1);
  launch_tconv(stream, ada2_w, 384, 0,0,1, 96,384,   ada2T, 96, 0, 1);
  launch_tconv(stream, a1_qkv_w, 1152, 384ll*1152,0,1, 384,1152, a1qkvT, 384, 1152ll*384, 6);
  launch_tconv(stream, a1_proj_w, 384, 384ll*384,0,1, 384,384,  a1projT, 384, 384ll*384, 6);

  // ---- phase 1: transformer block ----
  ln_bf16_kernel<<<8196,128,0,stream>>>(x, norm1_g, norm1_b, bufHh);
  launch_gemm16b(stream, bufHh,384,0, qkvT,384,0, nullptr,0, nullptr,0,0,
                 bufQh,1152,0,1, 8196,1152,384, 0, 1,1);
  launch_tconv16(stream, bufQh + 768, 1152, 2049ll*1152, 64, 6, 2049, 64, Vt_i, 2112, 64ll*2112, 24);
  flash_inner<<<dim3(792),256,0,stream>>>(bufQh, Vt_i, bufOh);
  launch_gemm16s(stream, bufOh,384,0, projT,384,0, proj_b,0, x,384,0,
                 bufX,384,0,0, 8196,384,384, 0, 1);
  ln_bf16_kernel<<<8196,128,0,stream>>>(bufX, norm2_g, norm2_b, bufHh);
  launch_gemm16b(stream, bufHh,384,0, fc1T,384,0, fc1_b,0, nullptr,0,0,
                 bufTh,1536,0,1, 8196,1536,384, 1, 1,1);
  launch_gemm16s(stream, bufTh,1536,0, fc2T,1536,0, fc2_b,0, nullptr,0,0,
                 bufO,384,0,0, 8196,384,1536, 0, 1);
  launch_cvt(stream, bufO, bufOh, 8196ll*384);
  launch_gemm16s(stream, bufOh,384,0, ada1T,384,0, ada1_b,0, nullptr,0,0,
                 bufAh,96,0,1, 8196,96,384, 2, 1);
  launch_gemm16s(stream, bufAh,96,0, ada2T,96,0, ada2_b,0, nullptr,0,0,
                 bufAda,384,0,0, 8196,384,96, 0, 1);
  ew_x2_kernel<<<dim3((8196*384+255)/256),256,0,stream>>>(bufX, bufO, bufAda, 8196ll*384);
  copy_cls_kernel<<<6,256,0,stream>>>(bufX, out);
  copy_pts_kernel<<<dim3((8192*384+255)/256),256,0,stream>>>(bufX, ptsb);

  // ---- phase 2: cluster pooling -> cell3 ----
  hipMemsetAsync(cnt, 0, 1024*4, stream);
  hipMemsetAsync(fsum, 0, 1024ll*384*4, stream);
  hipMemsetAsync(fmaxe, 0, 1024ll*384*4, stream);
  scatter_seg_kernel<<<dim3(8192,1),128,0,stream>>>(ptsb, cluster, fsum, fmaxe, cnt, 0,0,0,0);
  cell_kernel<<<dim3(1024,1),128,0,stream>>>(fsum, fmaxe, cnt, bn3_g,bn3_b,bn3_m,bn3_v, cell3, 0,0,0);

  // ---- phase 3a: batched view projections ----
  ln6_kernel<<<8192,128,0,stream>>>(ptsb, norm3_g, norm3_b, bufHh6);
  launch_gemm16b(stream, bufHh6,384,8192ll*384, a1qkvT,384,1152ll*384,
                 nullptr,0, nullptr,0,0, QK6,768,8192ll*768,1, 8192,768,384, 0, 6,1);
  launch_gemm16s(stream, bufHh6,384,8192ll*384, a1qkvT + 768ll*384,384,1152ll*384,
                 nullptr,0, nullptr,0,0, Vt6,2048,4ll*384*2048,2, 8192,384,384, 0, 6);

  // ---- phase 3b: fused flash attention for all 24 (v,b), XCD-swizzled ----
  flash_view<<<dim3(768),256,0,stream>>>(QK6, Vt6, maskb, O6);

  // ---- phase 3c: batched proj + grid pooling ----
  launch_gemm16s(stream, O6,384,8192ll*384, a1projT,384,384ll*384,
                 a1_proj_b,384, ptsb,384,0,
                 bufT6,384,8192ll*384,0, 8192,384,384, 0, 6);
  hipMemsetAsync(gc6, 0, 6ll*4096*4, stream);
  hipMemsetAsync(gsum6, 0, 6ll*4096*384*4, stream);
  hipMemsetAsync(gmaxe6, 0, 6ll*4096*384*4, stream);
  scatter_seg_kernel<<<dim3(8192,6),128,0,stream>>>(bufT6, fgi, gsum6, gmaxe6, gc6,
      8192ll*384, 8192, 4096ll*384, 4096);
  cell_kernel<<<dim3(4096,6),128,0,stream>>>(gsum6, gmaxe6, gc6,
      bn2_g, bn2_b, bn2_m, bn2_v, cell2, 4096ll*384, 4096, 384);

  // ---- phase 4: combine ----
  combine_kernel<<<8192,128,0,stream>>>(ptsb, cell3, cluster, cell2, fgi, out);
}